// Round 1
// baseline (5238.350 us; speedup 1.0000x reference)
//
#include <hip/hip_runtime.h>
#include <math.h>

#define HW 16384
constexpr int C_ = 96;
constexpr int E_ = 192, DI_ = 384, NS_ = 16, R_ = 12, K_ = 4, NBLK_ = 8, GW_ = 48;
constexpr int L_ = 1024, CXP_ = 44; // R + 2*NS

__device__ __forceinline__ float lrelu_(float x){ return x >= 0.f ? x : 0.2f*x; }
__device__ __forceinline__ float sigmoid_(float x){ return 1.f/(1.f+expf(-x)); }
__device__ __forceinline__ float silu_(float x){ return x/(1.f+expf(-x)); }
__device__ __forceinline__ float softplus_(float x){ return fmaxf(x,0.f)+log1pf(expf(-fabsf(x))); }

// ---------------- generic tiled transpose: out[b][c][r] = in[b][r*in_stride + c]
__global__ void k_transpose(const float* __restrict__ in, float* __restrict__ out,
                            int rows, int cols, int in_stride){
  __shared__ float t[32][33];
  const float* ib = in + (size_t)blockIdx.z*rows*in_stride;
  float* ob = out + (size_t)blockIdx.z*rows*cols;
  int r0 = blockIdx.y*32, c0 = blockIdx.x*32;
  int tx = threadIdx.x, ty = threadIdx.y;
  for (int i=0;i<32;i+=8){
    int r = r0+ty+i, c = c0+tx;
    if (r<rows && c<cols) t[ty+i][tx] = ib[(size_t)r*in_stride+c];
  }
  __syncthreads();
  for (int i=0;i<32;i+=8){
    int c = c0+ty+i, r = r0+tx;
    if (r<rows && c<cols) ob[(size_t)c*rows+r] = t[tx][ty+i];
  }
}

// ---------------- bn1 + per-channel mean/max stats
__global__ void k_bn1(const float* __restrict__ x, const float* g, const float* b,
                      const float* m, const float* v,
                      float* __restrict__ h, float* __restrict__ stats){
  int c = blockIdx.x, tid = threadIdx.x;
  float sc = g[c]*rsqrtf(v[c]+1e-5f), sh = b[c]-m[c]*sc;
  const float* xc = x + (size_t)c*HW;
  float* hc = h + (size_t)c*HW;
  float s = 0.f, mx = -1e30f;
  for (int i=tid;i<HW;i+=256){
    float val = fmaf(xc[i], sc, sh);
    hc[i] = val; s += val; mx = fmaxf(mx, val);
  }
  for (int o=32;o;o>>=1){ s += __shfl_xor(s,o); mx = fmaxf(mx, __shfl_xor(mx,o)); }
  __shared__ float ss[4], sm[4];
  int wid = tid>>6, lane = tid&63;
  if (!lane){ ss[wid]=s; sm[wid]=mx; }
  __syncthreads();
  if (!tid){
    stats[c] = (ss[0]+ss[1]+ss[2]+ss[3])*(1.f/HW);
    stats[96+c] = fmaxf(fmaxf(sm[0],sm[1]),fmaxf(sm[2],sm[3]));
  }
}

// ---------------- channel-attention MLP (1 block)
__global__ void k_attn(const float* __restrict__ stats, const float* __restrict__ w1,
                       const float* __restrict__ w2, float* __restrict__ attn){
  __shared__ float hid[12];
  int tid = threadIdx.x;
  if (tid < 12){
    int j = tid%6, which = tid/6;
    const float* vv = stats + which*96;
    float a = 0.f;
    for (int c=0;c<96;c++) a += vv[c]*w1[j*96+c];
    hid[tid] = fmaxf(a, 0.f);
  }
  __syncthreads();
  if (tid < 96){
    float a = 0.f;
    for (int j=0;j<6;j++) a += (hid[j]+hid[6+j])*w2[tid*6+j];
    attn[tid] = sigmoid_(a);
  }
}

// ---------------- patchify h -> xp[l][1536]
__global__ void k_patchify(const float* __restrict__ h, float* __restrict__ xp){
  int idx = blockIdx.x*256 + threadIdx.x;
  int l = idx/1536, kk = idx%1536;
  int c = kk>>4, i = (kk>>2)&3, j = kk&3;
  int hp = l>>5, wp = l&31;
  xp[idx] = h[((size_t)c<<14) + (size_t)(hp*4+i)*128 + (wp*4+j)];
}

// ---------------- generic GEMM: out[l][n] = (res?) + Sum_k act[l][k]*wt[k][n] + (bias?)
__global__ __launch_bounds__(256) void k_gemm(const float* __restrict__ act,
                      const float* __restrict__ wt, const float* __restrict__ bias,
                      const float* __restrict__ res, float* __restrict__ out,
                      int K, int N){
  __shared__ float la[4*1536];
  int n = blockIdx.y*256 + threadIdx.x;
  int m0 = blockIdx.x*4;
  for (int i=threadIdx.x; i<4*K; i+=256)
    la[i] = act[(size_t)(m0 + i/K)*K + (i%K)];
  __syncthreads();
  if (n >= N) return;
  float a0=0,a1=0,a2=0,a3=0;
  const float* l0=la, *l1=la+K, *l2=la+2*K, *l3=la+3*K;
  const float* wp = wt + n;
  for (int k=0;k<K;k++){
    float w = wp[(size_t)k*N];
    a0 = fmaf(l0[k],w,a0); a1 = fmaf(l1[k],w,a1);
    a2 = fmaf(l2[k],w,a2); a3 = fmaf(l3[k],w,a3);
  }
  float bb = bias ? bias[n] : 0.f;
  size_t o = (size_t)m0*N + n;
  float r0 = res? res[o]:0.f, r1 = res? res[o+N]:0.f, r2 = res? res[o+2*N]:0.f, r3 = res? res[o+3*N]:0.f;
  out[o]     = a0+bb+r0;
  out[o+N]   = a1+bb+r1;
  out[o+2*N] = a2+bb+r2;
  out[o+3*N] = a3+bb+r3;
}

// ---------------- layernorm over E_=192, one wave per row
__global__ void k_ln(const float* __restrict__ x, const float* __restrict__ g,
                     const float* __restrict__ b, float* __restrict__ out){
  int l = blockIdx.x*4 + (threadIdx.x>>6);
  int lane = threadIdx.x&63;
  const float* xr = x + (size_t)l*E_;
  float v0 = xr[lane], v1 = xr[lane+64], v2 = xr[lane+128];
  float s = v0+v1+v2, sq = v0*v0+v1*v1+v2*v2;
  for (int o=32;o;o>>=1){ s += __shfl_xor(s,o); sq += __shfl_xor(sq,o); }
  float mu = s*(1.f/192.f);
  float rs = rsqrtf(sq*(1.f/192.f) - mu*mu + 1e-5f);
  float* orow = out + (size_t)l*E_;
  orow[lane]     = (v0-mu)*rs*g[lane]     + b[lane];
  orow[lane+64]  = (v1-mu)*rs*g[lane+64]  + b[lane+64];
  orow[lane+128] = (v2-mu)*rs*g[lane+128] + b[lane+128];
}

// ---------------- depthwise 3x3 conv (SAME) + bias + silu; in/out [d][l], l=h*32+w
__global__ void k_dwconv(const float* __restrict__ xc, const float* __restrict__ w,
                         const float* __restrict__ bias, float* __restrict__ out){
  int d = blockIdx.x;
  const float* in = xc + (size_t)d*L_;
  float wk[9];
  #pragma unroll
  for (int i=0;i<9;i++) wk[i] = w[d*9+i];
  float bb = bias[d];
  for (int p=threadIdx.x; p<L_; p+=256){
    int hh = p>>5, ww = p&31;
    float acc = bb;
    #pragma unroll
    for (int di=0;di<3;di++){
      int y = hh+di-1;
      if ((unsigned)y >= 32u) continue;
      #pragma unroll
      for (int dj=0;dj<3;dj++){
        int xx = ww+dj-1;
        if ((unsigned)xx >= 32u) continue;
        acc = fmaf(in[y*32+xx], wk[di*3+dj], acc);
      }
    }
    out[(size_t)d*L_+p] = silu_(acc);
  }
}

// ---------------- build xs_t[k][t][d] (4 scan orders) from xcs[d][l]
__global__ void k_build_xst(const float* __restrict__ xcs, float* __restrict__ xst){
  __shared__ float t[32][33];
  int d0 = blockIdx.y*32;
  int h0 = blockIdx.x;          // l tile = h0*32 .. h0*32+31
  int l0 = h0*32;
  int tx = threadIdx.x, ty = threadIdx.y;
  for (int i=0;i<32;i+=8)
    t[ty+i][tx] = xcs[(size_t)(d0+ty+i)*L_ + l0+tx];
  __syncthreads();
  int d = d0+tx;
  for (int i=0;i<32;i+=8){
    int wq = ty+i;
    int l = l0+wq;
    float val = t[tx][wq];
    int t1 = wq*32 + h0;
    xst[(size_t)l*DI_ + d] = val;
    xst[(size_t)(L_ + t1)*DI_ + d] = val;
    xst[(size_t)(2*L_ + (1023-l))*DI_ + d] = val;
    xst[(size_t)(3*L_ + (1023-t1))*DI_ + d] = val;
  }
}

// ---------------- x_dbl[k][c][l] = Sum_d xs[k][d][l] * xw[k][c][d]
// iterate in source (read) order so xcs reads are coalesced; scatter writes for k=1,3
__global__ __launch_bounds__(256) void k_xdbl(const float* __restrict__ xcs,
                       const float* __restrict__ xw, float* __restrict__ xdbl){
  int k = blockIdx.z;
  int s = blockIdx.x*256 + threadIdx.x;   // source position in xcs row
  int Ts = ((s&31)<<5) | (s>>5);
  int lw;
  if (k==0) lw = s;
  else if (k==1) lw = Ts;
  else if (k==2) lw = 1023-s;
  else lw = 1023-Ts;
  int c0 = blockIdx.y*4;
  const float* w0 = xw + ((size_t)k*CXP_ + c0)*DI_;
  float a0=0,a1=0,a2=0,a3=0;
  const float* src = xcs + s;
  for (int d=0; d<DI_; d++){
    float v = src[(size_t)d*L_];
    a0 = fmaf(v, w0[d],        a0);
    a1 = fmaf(v, w0[DI_+d],    a1);
    a2 = fmaf(v, w0[2*DI_+d],  a2);
    a3 = fmaf(v, w0[3*DI_+d],  a3);
  }
  size_t base = ((size_t)k*CXP_ + c0)*L_ + lw;
  xdbl[base]       = a0;
  xdbl[base+L_]    = a1;
  xdbl[base+2*L_]  = a2;
  xdbl[base+3*L_]  = a3;
}

// ---------------- dt projection + softplus -> dts_t[k][l][d]
__global__ void k_dt(const float* __restrict__ xdbl, const float* __restrict__ dtw,
                     const float* __restrict__ dtb, float* __restrict__ dts_t){
  int k = blockIdx.y, l = blockIdx.x, d = threadIdx.x;
  float acc = dtb[(size_t)k*DI_ + d];
  const float* w = dtw + ((size_t)k*DI_ + d)*R_;
  const float* xr = xdbl + (size_t)k*CXP_*L_ + l;
  #pragma unroll
  for (int r=0;r<R_;r++) acc = fmaf(xr[(size_t)r*L_], w[r], acc);
  dts_t[((size_t)k*L_ + l)*DI_ + d] = softplus_(acc);
}

// ---------------- repack B,C -> bc[k][t][32]
__global__ void k_bc(const float* __restrict__ xdbl, float* __restrict__ bc){
  int idx = blockIdx.x*256 + threadIdx.x;
  int k = idx>>10, t = idx&1023;
  const float* src = xdbl + ((size_t)k*CXP_ + R_)*L_ + t;
  float* dst = bc + ((size_t)k*L_ + t)*32;
  #pragma unroll
  for (int c=0;c<32;c++) dst[c] = src[(size_t)c*L_];
}

// ---------------- selective scan: thread per (k,d,n)
__global__ __launch_bounds__(256) void k_scan(const float* __restrict__ xst,
                      const float* __restrict__ dts_t, const float* __restrict__ bc,
                      const float* __restrict__ Alog, float* __restrict__ yst){
  int k = blockIdx.y;
  int d = blockIdx.x*16 + (threadIdx.x>>4);
  int n = threadIdx.x&15;
  float A = -expf(Alog[((size_t)k*DI_ + d)*NS_ + n]);
  float aL2 = A * 1.4426950408889634f;
  const float* xp_ = xst   + (size_t)k*L_*DI_ + d;
  const float* dtp = dts_t + (size_t)k*L_*DI_ + d;
  const float* bcp = bc    + (size_t)k*L_*32;
  float* yp = yst + (size_t)k*L_*DI_ + d;
  float h = 0.f;
  #pragma unroll 2
  for (int t=0;t<L_;t++){
    float dt = dtp[(size_t)t*DI_];
    float xv = xp_[(size_t)t*DI_];
    float Bn = bcp[t*32+n], Cn = bcp[t*32+16+n];
    float e = exp2f(aL2*dt);
    h = fmaf(e, h, dt*xv*Bn);
    float p = h*Cn;
    p += __shfl_xor(p,1); p += __shfl_xor(p,2);
    p += __shfl_xor(p,4); p += __shfl_xor(p,8);
    if (n==0) yp[(size_t)t*DI_] = p;
  }
}

// ---------------- merge 4 directions + Dskip + LN + silu(z) gate
__global__ void k_merge(const float* __restrict__ yst, const float* __restrict__ xst,
                        const float* __restrict__ Dsk, const float* __restrict__ mw,
                        const float* __restrict__ ong, const float* __restrict__ onb,
                        const float* __restrict__ xz, float* __restrict__ out){
  int l = blockIdx.x, d = threadIdx.x;
  int T = ((l&31)<<5) | (l>>5);
  int tt[4] = { l, T, 1023-l, 1023-T };
  float v = 0.f;
  #pragma unroll
  for (int k=0;k<4;k++){
    size_t idx = (size_t)(k*L_ + tt[k])*DI_ + d;
    v += mw[k]*(yst[idx] + xst[idx]*Dsk[k*DI_+d]);
  }
  float s = v, sq = v*v;
  for (int o=32;o;o>>=1){ s += __shfl_xor(s,o); sq += __shfl_xor(sq,o); }
  __shared__ float rs_[6], rq_[6];
  int lane = d&63, wid = d>>6;
  if (!lane){ rs_[wid]=s; rq_[wid]=sq; }
  __syncthreads();
  float ts=0.f, tq=0.f;
  #pragma unroll
  for (int i=0;i<6;i++){ ts += rs_[i]; tq += rq_[i]; }
  float mu = ts*(1.f/DI_);
  float rstd = rsqrtf(tq*(1.f/DI_) - mu*mu + 1e-5f);
  float y = (v-mu)*rstd*ong[d] + onb[d];
  float z = xz[(size_t)l*768 + DI_ + d];
  out[(size_t)l*DI_ + d] = y * silu_(z);
}

// ---------------- un-patchify + residual + attention + bn2
__global__ void k_sum(const float* __restrict__ x, const float* __restrict__ h,
                      const float* __restrict__ attn, const float* __restrict__ xu,
                      const float* g2, const float* b2, const float* m2, const float* v2,
                      float* __restrict__ xsum, float* __restrict__ h2){
  int idx = blockIdx.x*256 + threadIdx.x;
  int c = idx>>14, p = idx&16383;
  int hh = p>>7, ww = p&127;
  int l = (hh>>2)*32 + (ww>>2);
  int o = (c<<4) + ((hh&3)<<2) + (ww&3);
  float s = x[idx] + h[idx]*attn[c] + xu[(size_t)l*1536 + o];
  xsum[idx] = s;
  h2[idx] = (s - m2[c])*rsqrtf(v2[c]+1e-5f)*g2[c] + b2[c];
}

// ---------------- scpa: dual 1x1 conv + lrelu
__global__ void k_1x1ab(const float* __restrict__ h2, const float* __restrict__ wa,
                        const float* __restrict__ wb, float* __restrict__ a, float* __restrict__ b){
  int o = blockIdx.x;
  int p = blockIdx.y*256 + threadIdx.x;
  float aa=0.f, ab=0.f;
  for (int c=0;c<96;c++){
    float v = h2[(size_t)c*HW + p];
    aa = fmaf(v, wa[o*96+c], aa);
    ab = fmaf(v, wb[o*96+c], ab);
  }
  a[(size_t)o*HW+p] = lrelu_(aa);
  b[(size_t)o*HW+p] = lrelu_(ab);
}

// ---------------- scpa: 1x1 conv + bias + sigmoid (gate)
__global__ void k_1x1g(const float* __restrict__ b, const float* __restrict__ w,
                       const float* __restrict__ bias, float* __restrict__ g){
  int o = blockIdx.x;
  int p = blockIdx.y*256 + threadIdx.x;
  float acc = bias[o];
  for (int c=0;c<48;c++) acc = fmaf(b[(size_t)c*HW+p], w[o*48+c], acc);
  g[(size_t)o*HW+p] = sigmoid_(acc);
}

// ---------------- scpa: 3x3 conv 48->48, epilogue mode 0=lrelu, 1=mul aux
__global__ void k_conv3(const float* __restrict__ in, const float* __restrict__ w,
                        const float* __restrict__ aux, float* __restrict__ out, int mode){
  int oc = blockIdx.x;
  int p = blockIdx.y*256 + threadIdx.x;
  int hh = p>>7, ww = p&127;
  float acc = 0.f;
  for (int ic=0; ic<48; ic++){
    const float* ip = in + (size_t)ic*HW;
    const float* wp = w + ((size_t)oc*48+ic)*9;
    #pragma unroll
    for (int di=0;di<3;di++){
      int y = hh+di-1;
      if ((unsigned)y >= 128u) continue;
      #pragma unroll
      for (int dj=0;dj<3;dj++){
        int xx = ww+dj-1;
        if ((unsigned)xx >= 128u) continue;
        acc = fmaf(ip[y*128+xx], wp[di*3+dj], acc);
      }
    }
  }
  out[(size_t)oc*HW+p] = (mode==0) ? lrelu_(acc) : acc*aux[(size_t)oc*HW+p];
}

// ---------------- final 1x1 conv + both residuals
__global__ void k_c3(const float* __restrict__ ab, const float* __restrict__ w,
                     const float* __restrict__ h2, const float* __restrict__ xsum,
                     float* __restrict__ out){
  int c = blockIdx.x;
  int p = blockIdx.y*256 + threadIdx.x;
  float acc = 0.f;
  for (int j=0;j<96;j++) acc = fmaf(ab[(size_t)j*HW+p], w[c*96+j], acc);
  out[(size_t)c*HW+p] = acc + h2[(size_t)c*HW+p] + xsum[(size_t)c*HW+p];
}

extern "C" void kernel_launch(void* const* d_in, const int* in_sizes, int n_in,
                              void* d_out, int out_size, void* d_ws, size_t ws_size,
                              hipStream_t stream){
  (void)in_sizes; (void)n_in; (void)out_size; (void)ws_size;
  const float* x    = (const float*)d_in[0];
  const float* bn1g = (const float*)d_in[1];
  const float* bn1b = (const float*)d_in[2];
  const float* bn1m = (const float*)d_in[3];
  const float* bn1v = (const float*)d_in[4];
  const float* caw1 = (const float*)d_in[5];
  const float* caw2 = (const float*)d_in[6];
  const float* peW  = (const float*)d_in[7];
  const float* peb  = (const float*)d_in[8];
  const float* puW  = (const float*)d_in[9];
  const float* pub  = (const float*)d_in[10];
  const float* lng  = (const float*)d_in[11];
  const float* lnb  = (const float*)d_in[12];
  const float* inW  = (const float*)d_in[13];
  const float* convw= (const float*)d_in[14];
  const float* convb= (const float*)d_in[15];
  const float* xprojw=(const float*)d_in[16];
  const float* dtw  = (const float*)d_in[17];
  const float* dtb  = (const float*)d_in[18];
  const float* Alog = (const float*)d_in[19];
  const float* Dsk  = (const float*)d_in[20];
  const float* ong  = (const float*)d_in[21];
  const float* onb  = (const float*)d_in[22];
  const float* outW = (const float*)d_in[23];
  const float* mw   = (const float*)d_in[24];
  const float* bn2g = (const float*)d_in[25];
  const float* bn2b = (const float*)d_in[26];
  const float* bn2m = (const float*)d_in[27];
  const float* bn2v = (const float*)d_in[28];
  const float* c1a  = (const float*)d_in[29];
  const float* c1b  = (const float*)d_in[30];
  const float* k1w  = (const float*)d_in[31];
  const float* k2w  = (const float*)d_in[32];
  const float* k2b  = (const float*)d_in[33];
  const float* k3w  = (const float*)d_in[34];
  const float* k4w  = (const float*)d_in[35];
  const float* c3w  = (const float*)d_in[36];
  float* out = (float*)d_out;

  float* ws = (float*)d_ws;
  size_t off = 0;
  auto alloc = [&](size_t n){ float* p = ws + off; off += n; return p; };
  float* peWT  = alloc((size_t)1536*192);
  float* puWT  = alloc((size_t)192*1536);
  float* inWT  = alloc((size_t)8*192*768);
  float* outWT = alloc((size_t)8*384*192);
  float* bufH  = alloc((size_t)96*HW);
  float* stats = alloc(256);
  float* attn  = alloc(128);
  float* bufP  = alloc((size_t)1024*1536);   // xp, later xu
  float* x2a   = alloc((size_t)1024*192);
  float* x2b   = alloc((size_t)1024*192);
  float* bufLN = alloc((size_t)1024*192);
  float* bufXZ = alloc((size_t)1024*768);
  float* bufXC = alloc((size_t)384*1024);
  float* bufXCS= alloc((size_t)384*1024);
  float* bufXST= alloc((size_t)4*1024*384);  // later ab (96ch)
  float* xdbl  = alloc((size_t)4*44*1024);
  float* dts   = alloc((size_t)4*1024*384);  // later scpa a|b
  float* bc    = alloc((size_t)4*1024*32);
  float* yst   = alloc((size_t)4*1024*384);  // later scpa g|t
  float* bufY  = alloc((size_t)1024*384);
  float* xsum  = alloc((size_t)96*HW);
  float* h2    = alloc((size_t)96*HW);

  dim3 tb(32,8);
  // weight transposes
  k_transpose<<<dim3(48,6,1), tb, 0, stream>>>(peW, peWT, 192, 1536, 1536);
  k_transpose<<<dim3(6,48,1), tb, 0, stream>>>(puW, puWT, 1536, 192, 192);
  k_transpose<<<dim3(6,24,8), tb, 0, stream>>>(inW, inWT, 768, 192, 192);
  k_transpose<<<dim3(12,6,8), tb, 0, stream>>>(outW, outWT, 192, 384, 384);

  k_bn1<<<96,256,0,stream>>>(x, bn1g, bn1b, bn1m, bn1v, bufH, stats);
  k_attn<<<1,128,0,stream>>>(stats, caw1, caw2, attn);
  k_patchify<<<(1024*1536)/256,256,0,stream>>>(bufH, bufP);
  k_gemm<<<dim3(256,1),256,0,stream>>>(bufP, peWT, peb, nullptr, x2a, 1536, 192);

  float* cur = x2a; float* nxt = x2b;
  for (int b=0;b<8;b++){
    k_ln<<<256,256,0,stream>>>(cur, lng+(size_t)b*192, lnb+(size_t)b*192, bufLN);
    k_gemm<<<dim3(256,3),256,0,stream>>>(bufLN, inWT+(size_t)b*192*768, nullptr, nullptr, bufXZ, 192, 768);
    k_transpose<<<dim3(12,32,1),tb,0,stream>>>(bufXZ, bufXC, 1024, 384, 768);
    k_dwconv<<<384,256,0,stream>>>(bufXC, convw+(size_t)b*384*9, convb+(size_t)b*384, bufXCS);
    k_build_xst<<<dim3(32,12),tb,0,stream>>>(bufXCS, bufXST);
    k_xdbl<<<dim3(4,11,4),256,0,stream>>>(bufXCS, xprojw+(size_t)b*4*44*384, xdbl);
    k_dt<<<dim3(1024,4),384,0,stream>>>(xdbl, dtw+(size_t)b*4*384*12, dtb+(size_t)b*4*384, dts);
    k_bc<<<16,256,0,stream>>>(xdbl, bc);
    k_scan<<<dim3(24,4),256,0,stream>>>(bufXST, dts, bc, Alog+(size_t)b*4*384*16, yst);
    k_merge<<<1024,384,0,stream>>>(yst, bufXST, Dsk+(size_t)b*4*384, mw+(size_t)b*4,
                                   ong+(size_t)b*384, onb+(size_t)b*384, bufXZ, bufY);
    k_gemm<<<dim3(256,1),256,0,stream>>>(bufY, outWT+(size_t)b*384*192, nullptr, cur, nxt, 384, 192);
    float* t = cur; cur = nxt; nxt = t;
  }

  k_gemm<<<dim3(256,6),256,0,stream>>>(cur, puWT, pub, nullptr, bufP, 192, 1536);
  k_sum<<<(96*HW)/256,256,0,stream>>>(x, bufH, attn, bufP, bn2g, bn2b, bn2m, bn2v, xsum, h2);

  float* bufA = dts;
  float* bufB = dts + (size_t)48*HW;
  float* bufG = yst;
  float* bufT = yst + (size_t)48*HW;
  float* ab   = bufXST;
  k_1x1ab<<<dim3(48,64),256,0,stream>>>(h2, c1a, c1b, bufA, bufB);
  k_1x1g<<<dim3(48,64),256,0,stream>>>(bufB, k2w, k2b, bufG);
  k_conv3<<<dim3(48,64),256,0,stream>>>(bufA, k1w, nullptr, ab, 0);
  k_conv3<<<dim3(48,64),256,0,stream>>>(bufB, k3w, bufG, bufT, 1);
  k_conv3<<<dim3(48,64),256,0,stream>>>(bufT, k4w, nullptr, ab+(size_t)48*HW, 0);
  k_c3<<<dim3(96,64),256,0,stream>>>(ab, c3w, h2, xsum, out);
}

// Round 2
// 1863.451 us; speedup vs baseline: 2.8111x; 2.8111x over previous
//
#include <hip/hip_runtime.h>
#include <math.h>

#define HW 16384
constexpr int C_ = 96;
constexpr int E_ = 192, DI_ = 384, NS_ = 16, R_ = 12, K_ = 4, NBLK_ = 8, GW_ = 48;
constexpr int L_ = 1024, CXP_ = 44; // R + 2*NS
constexpr int TC_ = 64;             // scan chunk length
constexpr int NCH_ = L_ / TC_;      // 16 chunks

__device__ __forceinline__ float lrelu_(float x){ return x >= 0.f ? x : 0.2f*x; }
__device__ __forceinline__ float sigmoid_(float x){ return 1.f/(1.f+expf(-x)); }
__device__ __forceinline__ float silu_(float x){ return x/(1.f+expf(-x)); }
__device__ __forceinline__ float softplus_(float x){ return fmaxf(x,0.f)+log1pf(expf(-fabsf(x))); }

// ---------------- generic tiled transpose: out[b][c][r] = in[b][r*in_stride + c]
__global__ void k_transpose(const float* __restrict__ in, float* __restrict__ out,
                            int rows, int cols, int in_stride){
  __shared__ float t[32][33];
  const float* ib = in + (size_t)blockIdx.z*rows*in_stride;
  float* ob = out + (size_t)blockIdx.z*rows*cols;
  int r0 = blockIdx.y*32, c0 = blockIdx.x*32;
  int tx = threadIdx.x, ty = threadIdx.y;
  for (int i=0;i<32;i+=8){
    int r = r0+ty+i, c = c0+tx;
    if (r<rows && c<cols) t[ty+i][tx] = ib[(size_t)r*in_stride+c];
  }
  __syncthreads();
  for (int i=0;i<32;i+=8){
    int c = c0+ty+i, r = r0+tx;
    if (r<rows && c<cols) ob[(size_t)c*rows+r] = t[tx][ty+i];
  }
}

// ---------------- bn1 + per-channel mean/max stats
__global__ void k_bn1(const float* __restrict__ x, const float* g, const float* b,
                      const float* m, const float* v,
                      float* __restrict__ h, float* __restrict__ stats){
  int c = blockIdx.x, tid = threadIdx.x;
  float sc = g[c]*rsqrtf(v[c]+1e-5f), sh = b[c]-m[c]*sc;
  const float* xc = x + (size_t)c*HW;
  float* hc = h + (size_t)c*HW;
  float s = 0.f, mx = -1e30f;
  for (int i=tid;i<HW;i+=256){
    float val = fmaf(xc[i], sc, sh);
    hc[i] = val; s += val; mx = fmaxf(mx, val);
  }
  for (int o=32;o;o>>=1){ s += __shfl_xor(s,o); mx = fmaxf(mx, __shfl_xor(mx,o)); }
  __shared__ float ss[4], sm[4];
  int wid = tid>>6, lane = tid&63;
  if (!lane){ ss[wid]=s; sm[wid]=mx; }
  __syncthreads();
  if (!tid){
    stats[c] = (ss[0]+ss[1]+ss[2]+ss[3])*(1.f/HW);
    stats[96+c] = fmaxf(fmaxf(sm[0],sm[1]),fmaxf(sm[2],sm[3]));
  }
}

// ---------------- channel-attention MLP (1 block)
__global__ void k_attn(const float* __restrict__ stats, const float* __restrict__ w1,
                       const float* __restrict__ w2, float* __restrict__ attn){
  __shared__ float hid[12];
  int tid = threadIdx.x;
  if (tid < 12){
    int j = tid%6, which = tid/6;
    const float* vv = stats + which*96;
    float a = 0.f;
    for (int c=0;c<96;c++) a += vv[c]*w1[j*96+c];
    hid[tid] = fmaxf(a, 0.f);
  }
  __syncthreads();
  if (tid < 96){
    float a = 0.f;
    for (int j=0;j<6;j++) a += (hid[j]+hid[6+j])*w2[tid*6+j];
    attn[tid] = sigmoid_(a);
  }
}

// ---------------- patchify h -> xp[l][1536]
__global__ void k_patchify(const float* __restrict__ h, float* __restrict__ xp){
  int idx = blockIdx.x*256 + threadIdx.x;
  int l = idx/1536, kk = idx%1536;
  int c = kk>>4, i = (kk>>2)&3, j = kk&3;
  int hp = l>>5, wp = l&31;
  xp[idx] = h[((size_t)c<<14) + (size_t)(hp*4+i)*128 + (wp*4+j)];
}

// ---------------- generic GEMM: out[l][n] = (res?) + Sum_k act[l][k]*wt[k][n] + (bias?)
__global__ __launch_bounds__(256) void k_gemm(const float* __restrict__ act,
                      const float* __restrict__ wt, const float* __restrict__ bias,
                      const float* __restrict__ res, float* __restrict__ out,
                      int K, int N){
  __shared__ float la[4*1536];
  int n = blockIdx.y*256 + threadIdx.x;
  int m0 = blockIdx.x*4;
  for (int i=threadIdx.x; i<4*K; i+=256)
    la[i] = act[(size_t)(m0 + i/K)*K + (i%K)];
  __syncthreads();
  if (n >= N) return;
  float a0=0,a1=0,a2=0,a3=0;
  const float* l0=la, *l1=la+K, *l2=la+2*K, *l3=la+3*K;
  const float* wp = wt + n;
  for (int k=0;k<K;k++){
    float w = wp[(size_t)k*N];
    a0 = fmaf(l0[k],w,a0); a1 = fmaf(l1[k],w,a1);
    a2 = fmaf(l2[k],w,a2); a3 = fmaf(l3[k],w,a3);
  }
  float bb = bias ? bias[n] : 0.f;
  size_t o = (size_t)m0*N + n;
  float r0 = res? res[o]:0.f, r1 = res? res[o+N]:0.f, r2 = res? res[o+2*N]:0.f, r3 = res? res[o+3*N]:0.f;
  out[o]     = a0+bb+r0;
  out[o+N]   = a1+bb+r1;
  out[o+2*N] = a2+bb+r2;
  out[o+3*N] = a3+bb+r3;
}

// ---------------- layernorm over E_=192, one wave per row
__global__ void k_ln(const float* __restrict__ x, const float* __restrict__ g,
                     const float* __restrict__ b, float* __restrict__ out){
  int l = blockIdx.x*4 + (threadIdx.x>>6);
  int lane = threadIdx.x&63;
  const float* xr = x + (size_t)l*E_;
  float v0 = xr[lane], v1 = xr[lane+64], v2 = xr[lane+128];
  float s = v0+v1+v2, sq = v0*v0+v1*v1+v2*v2;
  for (int o=32;o;o>>=1){ s += __shfl_xor(s,o); sq += __shfl_xor(sq,o); }
  float mu = s*(1.f/192.f);
  float rs = rsqrtf(sq*(1.f/192.f) - mu*mu + 1e-5f);
  float* orow = out + (size_t)l*E_;
  orow[lane]     = (v0-mu)*rs*g[lane]     + b[lane];
  orow[lane+64]  = (v1-mu)*rs*g[lane+64]  + b[lane+64];
  orow[lane+128] = (v2-mu)*rs*g[lane+128] + b[lane+128];
}

// ---------------- depthwise 3x3 conv (SAME) + bias + silu; in/out [d][l], l=h*32+w
__global__ void k_dwconv(const float* __restrict__ xc, const float* __restrict__ w,
                         const float* __restrict__ bias, float* __restrict__ out){
  int d = blockIdx.x;
  const float* in = xc + (size_t)d*L_;
  float wk[9];
  #pragma unroll
  for (int i=0;i<9;i++) wk[i] = w[d*9+i];
  float bb = bias[d];
  for (int p=threadIdx.x; p<L_; p+=256){
    int hh = p>>5, ww = p&31;
    float acc = bb;
    #pragma unroll
    for (int di=0;di<3;di++){
      int y = hh+di-1;
      if ((unsigned)y >= 32u) continue;
      #pragma unroll
      for (int dj=0;dj<3;dj++){
        int xx = ww+dj-1;
        if ((unsigned)xx >= 32u) continue;
        acc = fmaf(in[y*32+xx], wk[di*3+dj], acc);
      }
    }
    out[(size_t)d*L_+p] = silu_(acc);
  }
}

// ---------------- build xs_t[k][t][d] (4 scan orders) from xcs[d][l]
__global__ void k_build_xst(const float* __restrict__ xcs, float* __restrict__ xst){
  __shared__ float t[32][33];
  int d0 = blockIdx.y*32;
  int h0 = blockIdx.x;          // l tile = h0*32 .. h0*32+31
  int l0 = h0*32;
  int tx = threadIdx.x, ty = threadIdx.y;
  for (int i=0;i<32;i+=8)
    t[ty+i][tx] = xcs[(size_t)(d0+ty+i)*L_ + l0+tx];
  __syncthreads();
  int d = d0+tx;
  for (int i=0;i<32;i+=8){
    int wq = ty+i;
    int l = l0+wq;
    float val = t[tx][wq];
    int t1 = wq*32 + h0;
    xst[(size_t)l*DI_ + d] = val;
    xst[(size_t)(L_ + t1)*DI_ + d] = val;
    xst[(size_t)(2*L_ + (1023-l))*DI_ + d] = val;
    xst[(size_t)(3*L_ + (1023-t1))*DI_ + d] = val;
  }
}

// ---------------- x_dbl[k][c][l] = Sum_d xs[k][d][l] * xw[k][c][d]
__global__ __launch_bounds__(256) void k_xdbl(const float* __restrict__ xcs,
                       const float* __restrict__ xw, float* __restrict__ xdbl){
  int k = blockIdx.z;
  int s = blockIdx.x*256 + threadIdx.x;   // source position in xcs row
  int Ts = ((s&31)<<5) | (s>>5);
  int lw;
  if (k==0) lw = s;
  else if (k==1) lw = Ts;
  else if (k==2) lw = 1023-s;
  else lw = 1023-Ts;
  int c0 = blockIdx.y*4;
  const float* w0 = xw + ((size_t)k*CXP_ + c0)*DI_;
  float a0=0,a1=0,a2=0,a3=0;
  const float* src = xcs + s;
  for (int d=0; d<DI_; d++){
    float v = src[(size_t)d*L_];
    a0 = fmaf(v, w0[d],        a0);
    a1 = fmaf(v, w0[DI_+d],    a1);
    a2 = fmaf(v, w0[2*DI_+d],  a2);
    a3 = fmaf(v, w0[3*DI_+d],  a3);
  }
  size_t base = ((size_t)k*CXP_ + c0)*L_ + lw;
  xdbl[base]       = a0;
  xdbl[base+L_]    = a1;
  xdbl[base+2*L_]  = a2;
  xdbl[base+3*L_]  = a3;
}

// ---------------- dt projection + softplus -> dts_t[k][l][d]
__global__ void k_dt(const float* __restrict__ xdbl, const float* __restrict__ dtw,
                     const float* __restrict__ dtb, float* __restrict__ dts_t){
  int k = blockIdx.y, l = blockIdx.x, d = threadIdx.x;
  float acc = dtb[(size_t)k*DI_ + d];
  const float* w = dtw + ((size_t)k*DI_ + d)*R_;
  const float* xr = xdbl + (size_t)k*CXP_*L_ + l;
  #pragma unroll
  for (int r=0;r<R_;r++) acc = fmaf(xr[(size_t)r*L_], w[r], acc);
  dts_t[((size_t)k*L_ + l)*DI_ + d] = softplus_(acc);
}

// ---------------- repack B,C -> bc[k][t][32]
__global__ void k_bc(const float* __restrict__ xdbl, float* __restrict__ bc){
  int idx = blockIdx.x*256 + threadIdx.x;
  int k = idx>>10, t = idx&1023;
  const float* src = xdbl + ((size_t)k*CXP_ + R_)*L_ + t;
  float* dst = bc + ((size_t)k*L_ + t)*32;
  #pragma unroll
  for (int c=0;c<32;c++) dst[c] = src[(size_t)c*L_];
}

// ---------------- chunked selective scan, phase A: per-chunk aggregates
// grid (NCH_, DI_/16, K_), 256 thr; thread = (n, dsub): n=tid&15, d=by*16+(tid>>4)
__global__ __launch_bounds__(256) void k_scanA(const float* __restrict__ xst,
                      const float* __restrict__ dts_t, const float* __restrict__ bc,
                      const float* __restrict__ Alog,
                      float* __restrict__ Ech, float* __restrict__ Hch){
  int k = blockIdx.z;
  int d = blockIdx.y*16 + (threadIdx.x>>4);
  int n = threadIdx.x&15;
  int ch = blockIdx.x;
  float A = -expf(Alog[((size_t)k*DI_ + d)*NS_ + n]);
  float aL2 = A * 1.4426950408889634f;
  int t0 = ch*TC_;
  const float* dtp = dts_t + ((size_t)k*L_ + t0)*DI_ + d;
  const float* xp_ = xst   + ((size_t)k*L_ + t0)*DI_ + d;
  const float* bcp = bc    + ((size_t)k*L_ + t0)*32;
  float h = 0.f, Ep = 1.f;
  #pragma unroll 4
  for (int t=0;t<TC_;t++){
    float dt = dtp[(size_t)t*DI_];
    float xv = xp_[(size_t)t*DI_];
    float Bn = bcp[t*32+n];
    float e = exp2f(aL2*dt);
    h = fmaf(e, h, dt*xv*Bn);
    Ep *= e;
  }
  size_t idx = (((size_t)k*NCH_ + ch)*DI_ + d)*NS_ + n;
  Ech[idx] = Ep; Hch[idx] = h;
}

// ---------------- phase B: fold chunk aggregates -> carry-in per chunk
__global__ void k_scanB(const float* __restrict__ Ech, const float* __restrict__ Hch,
                        float* __restrict__ carry){
  int idx = blockIdx.x*256 + threadIdx.x;     // (k, d*16+n) flattened
  int k = idx / (DI_*NS_);
  int dn = idx % (DI_*NS_);
  float h = 0.f;
  #pragma unroll
  for (int c=0;c<NCH_;c++){
    size_t o = ((size_t)(k*NCH_+c)*DI_*NS_) + dn;
    carry[o] = h;
    h = fmaf(Ech[o], h, Hch[o]);
  }
}

// ---------------- phase C: recompute with carry-in, emit y
__global__ __launch_bounds__(256) void k_scanC(const float* __restrict__ xst,
                      const float* __restrict__ dts_t, const float* __restrict__ bc,
                      const float* __restrict__ Alog, const float* __restrict__ carry,
                      float* __restrict__ yst){
  int k = blockIdx.z;
  int d = blockIdx.y*16 + (threadIdx.x>>4);
  int n = threadIdx.x&15;
  int ch = blockIdx.x;
  float A = -expf(Alog[((size_t)k*DI_ + d)*NS_ + n]);
  float aL2 = A * 1.4426950408889634f;
  int t0 = ch*TC_;
  const float* dtp = dts_t + ((size_t)k*L_ + t0)*DI_ + d;
  const float* xp_ = xst   + ((size_t)k*L_ + t0)*DI_ + d;
  const float* bcp = bc    + ((size_t)k*L_ + t0)*32;
  float* yp = yst + ((size_t)k*L_ + t0)*DI_ + d;
  float h = carry[(((size_t)k*NCH_ + ch)*DI_ + d)*NS_ + n];
  #pragma unroll 4
  for (int t=0;t<TC_;t++){
    float dt = dtp[(size_t)t*DI_];
    float xv = xp_[(size_t)t*DI_];
    float Bn = bcp[t*32+n], Cn = bcp[t*32+16+n];
    float e = exp2f(aL2*dt);
    h = fmaf(e, h, dt*xv*Bn);
    float p = h*Cn;
    p += __shfl_xor(p,1); p += __shfl_xor(p,2);
    p += __shfl_xor(p,4); p += __shfl_xor(p,8);
    if (n==0) yp[(size_t)t*DI_] = p;
  }
}

// ---------------- merge 4 directions + Dskip + LN + silu(z) gate
__global__ void k_merge(const float* __restrict__ yst, const float* __restrict__ xst,
                        const float* __restrict__ Dsk, const float* __restrict__ mw,
                        const float* __restrict__ ong, const float* __restrict__ onb,
                        const float* __restrict__ xz, float* __restrict__ out){
  int l = blockIdx.x, d = threadIdx.x;
  int T = ((l&31)<<5) | (l>>5);
  int tt[4] = { l, T, 1023-l, 1023-T };
  float v = 0.f;
  #pragma unroll
  for (int k=0;k<4;k++){
    size_t idx = (size_t)(k*L_ + tt[k])*DI_ + d;
    v += mw[k]*(yst[idx] + xst[idx]*Dsk[k*DI_+d]);
  }
  float s = v, sq = v*v;
  for (int o=32;o;o>>=1){ s += __shfl_xor(s,o); sq += __shfl_xor(sq,o); }
  __shared__ float rs_[6], rq_[6];
  int lane = d&63, wid = d>>6;
  if (!lane){ rs_[wid]=s; rq_[wid]=sq; }
  __syncthreads();
  float ts=0.f, tq=0.f;
  #pragma unroll
  for (int i=0;i<6;i++){ ts += rs_[i]; tq += rq_[i]; }
  float mu = ts*(1.f/DI_);
  float rstd = rsqrtf(tq*(1.f/DI_) - mu*mu + 1e-5f);
  float y = (v-mu)*rstd*ong[d] + onb[d];
  float z = xz[(size_t)l*768 + DI_ + d];
  out[(size_t)l*DI_ + d] = y * silu_(z);
}

// ---------------- un-patchify + residual + attention + bn2
__global__ void k_sum(const float* __restrict__ x, const float* __restrict__ h,
                      const float* __restrict__ attn, const float* __restrict__ xu,
                      const float* g2, const float* b2, const float* m2, const float* v2,
                      float* __restrict__ xsum, float* __restrict__ h2){
  int idx = blockIdx.x*256 + threadIdx.x;
  int c = idx>>14, p = idx&16383;
  int hh = p>>7, ww = p&127;
  int l = (hh>>2)*32 + (ww>>2);
  int o = (c<<4) + ((hh&3)<<2) + (ww&3);
  float s = x[idx] + h[idx]*attn[c] + xu[(size_t)l*1536 + o];
  xsum[idx] = s;
  h2[idx] = (s - m2[c])*rsqrtf(v2[c]+1e-5f)*g2[c] + b2[c];
}

// ---------------- scpa: dual 1x1 conv + lrelu
__global__ void k_1x1ab(const float* __restrict__ h2, const float* __restrict__ wa,
                        const float* __restrict__ wb, float* __restrict__ a, float* __restrict__ b){
  int o = blockIdx.x;
  int p = blockIdx.y*256 + threadIdx.x;
  float aa=0.f, ab=0.f;
  for (int c=0;c<96;c++){
    float v = h2[(size_t)c*HW + p];
    aa = fmaf(v, wa[o*96+c], aa);
    ab = fmaf(v, wb[o*96+c], ab);
  }
  a[(size_t)o*HW+p] = lrelu_(aa);
  b[(size_t)o*HW+p] = lrelu_(ab);
}

// ---------------- scpa: 1x1 conv + bias + sigmoid (gate)
__global__ void k_1x1g(const float* __restrict__ b, const float* __restrict__ w,
                       const float* __restrict__ bias, float* __restrict__ g){
  int o = blockIdx.x;
  int p = blockIdx.y*256 + threadIdx.x;
  float acc = bias[o];
  for (int c=0;c<48;c++) acc = fmaf(b[(size_t)c*HW+p], w[o*48+c], acc);
  g[(size_t)o*HW+p] = sigmoid_(acc);
}

// ---------------- scpa: 3x3 conv 48->48, epilogue mode 0=lrelu, 1=mul aux
__global__ void k_conv3(const float* __restrict__ in, const float* __restrict__ w,
                        const float* __restrict__ aux, float* __restrict__ out, int mode){
  int oc = blockIdx.x;
  int p = blockIdx.y*256 + threadIdx.x;
  int hh = p>>7, ww = p&127;
  float acc = 0.f;
  for (int ic=0; ic<48; ic++){
    const float* ip = in + (size_t)ic*HW;
    const float* wp = w + ((size_t)oc*48+ic)*9;
    #pragma unroll
    for (int di=0;di<3;di++){
      int y = hh+di-1;
      if ((unsigned)y >= 128u) continue;
      #pragma unroll
      for (int dj=0;dj<3;dj++){
        int xx = ww+dj-1;
        if ((unsigned)xx >= 128u) continue;
        acc = fmaf(ip[y*128+xx], wp[di*3+dj], acc);
      }
    }
  }
  out[(size_t)oc*HW+p] = (mode==0) ? lrelu_(acc) : acc*aux[(size_t)oc*HW+p];
}

// ---------------- final 1x1 conv + both residuals
__global__ void k_c3(const float* __restrict__ ab, const float* __restrict__ w,
                     const float* __restrict__ h2, const float* __restrict__ xsum,
                     float* __restrict__ out){
  int c = blockIdx.x;
  int p = blockIdx.y*256 + threadIdx.x;
  float acc = 0.f;
  for (int j=0;j<96;j++) acc = fmaf(ab[(size_t)j*HW+p], w[c*96+j], acc);
  out[(size_t)c*HW+p] = acc + h2[(size_t)c*HW+p] + xsum[(size_t)c*HW+p];
}

extern "C" void kernel_launch(void* const* d_in, const int* in_sizes, int n_in,
                              void* d_out, int out_size, void* d_ws, size_t ws_size,
                              hipStream_t stream){
  (void)in_sizes; (void)n_in; (void)out_size; (void)ws_size;
  const float* x    = (const float*)d_in[0];
  const float* bn1g = (const float*)d_in[1];
  const float* bn1b = (const float*)d_in[2];
  const float* bn1m = (const float*)d_in[3];
  const float* bn1v = (const float*)d_in[4];
  const float* caw1 = (const float*)d_in[5];
  const float* caw2 = (const float*)d_in[6];
  const float* peW  = (const float*)d_in[7];
  const float* peb  = (const float*)d_in[8];
  const float* puW  = (const float*)d_in[9];
  const float* pub  = (const float*)d_in[10];
  const float* lng  = (const float*)d_in[11];
  const float* lnb  = (const float*)d_in[12];
  const float* inW  = (const float*)d_in[13];
  const float* convw= (const float*)d_in[14];
  const float* convb= (const float*)d_in[15];
  const float* xprojw=(const float*)d_in[16];
  const float* dtw  = (const float*)d_in[17];
  const float* dtb  = (const float*)d_in[18];
  const float* Alog = (const float*)d_in[19];
  const float* Dsk  = (const float*)d_in[20];
  const float* ong  = (const float*)d_in[21];
  const float* onb  = (const float*)d_in[22];
  const float* outW = (const float*)d_in[23];
  const float* mw   = (const float*)d_in[24];
  const float* bn2g = (const float*)d_in[25];
  const float* bn2b = (const float*)d_in[26];
  const float* bn2m = (const float*)d_in[27];
  const float* bn2v = (const float*)d_in[28];
  const float* c1a  = (const float*)d_in[29];
  const float* c1b  = (const float*)d_in[30];
  const float* k1w  = (const float*)d_in[31];
  const float* k2w  = (const float*)d_in[32];
  const float* k2b  = (const float*)d_in[33];
  const float* k3w  = (const float*)d_in[34];
  const float* k4w  = (const float*)d_in[35];
  const float* c3w  = (const float*)d_in[36];
  float* out = (float*)d_out;

  float* ws = (float*)d_ws;
  size_t off = 0;
  auto alloc = [&](size_t n){ float* p = ws + off; off += n; return p; };
  float* peWT  = alloc((size_t)1536*192);
  float* puWT  = alloc((size_t)192*1536);
  float* inWT  = alloc((size_t)8*192*768);
  float* outWT = alloc((size_t)8*384*192);
  float* bufH  = alloc((size_t)96*HW);
  float* stats = alloc(256);
  float* attn  = alloc(128);
  float* bufP  = alloc((size_t)1024*1536);   // xp, later xu
  float* x2a   = alloc((size_t)1024*192);
  float* x2b   = alloc((size_t)1024*192);
  float* bufLN = alloc((size_t)1024*192);
  float* bufXZ = alloc((size_t)1024*768);
  float* bufXC = alloc((size_t)384*1024);
  float* bufXCS= alloc((size_t)384*1024);
  float* bufXST= alloc((size_t)4*1024*384);  // later ab (96ch)
  float* xdbl  = alloc((size_t)4*44*1024);
  float* dts   = alloc((size_t)4*1024*384);  // later scpa a|b
  float* bc    = alloc((size_t)4*1024*32);
  float* yst   = alloc((size_t)4*1024*384);  // later scpa g|t
  float* bufY  = alloc((size_t)1024*384);
  float* xsum  = alloc((size_t)96*HW);
  float* h2    = alloc((size_t)96*HW);
  float* Ech   = alloc((size_t)K_*NCH_*DI_*NS_);
  float* Hch   = alloc((size_t)K_*NCH_*DI_*NS_);
  float* carry = alloc((size_t)K_*NCH_*DI_*NS_);

  dim3 tb(32,8);
  // weight transposes
  k_transpose<<<dim3(48,6,1), tb, 0, stream>>>(peW, peWT, 192, 1536, 1536);
  k_transpose<<<dim3(6,48,1), tb, 0, stream>>>(puW, puWT, 1536, 192, 192);
  k_transpose<<<dim3(6,24,8), tb, 0, stream>>>(inW, inWT, 768, 192, 192);
  k_transpose<<<dim3(12,6,8), tb, 0, stream>>>(outW, outWT, 192, 384, 384);

  k_bn1<<<96,256,0,stream>>>(x, bn1g, bn1b, bn1m, bn1v, bufH, stats);
  k_attn<<<1,128,0,stream>>>(stats, caw1, caw2, attn);
  k_patchify<<<(1024*1536)/256,256,0,stream>>>(bufH, bufP);
  k_gemm<<<dim3(256,1),256,0,stream>>>(bufP, peWT, peb, nullptr, x2a, 1536, 192);

  float* cur = x2a; float* nxt = x2b;
  for (int b=0;b<8;b++){
    k_ln<<<256,256,0,stream>>>(cur, lng+(size_t)b*192, lnb+(size_t)b*192, bufLN);
    k_gemm<<<dim3(256,3),256,0,stream>>>(bufLN, inWT+(size_t)b*192*768, nullptr, nullptr, bufXZ, 192, 768);
    k_transpose<<<dim3(12,32,1),tb,0,stream>>>(bufXZ, bufXC, 1024, 384, 768);
    k_dwconv<<<384,256,0,stream>>>(bufXC, convw+(size_t)b*384*9, convb+(size_t)b*384, bufXCS);
    k_build_xst<<<dim3(32,12),tb,0,stream>>>(bufXCS, bufXST);
    k_xdbl<<<dim3(4,11,4),256,0,stream>>>(bufXCS, xprojw+(size_t)b*4*44*384, xdbl);
    k_dt<<<dim3(1024,4),384,0,stream>>>(xdbl, dtw+(size_t)b*4*384*12, dtb+(size_t)b*4*384, dts);
    k_bc<<<16,256,0,stream>>>(xdbl, bc);
    const float* Ab = Alog + (size_t)b*4*384*16;
    k_scanA<<<dim3(NCH_,DI_/16,4),256,0,stream>>>(bufXST, dts, bc, Ab, Ech, Hch);
    k_scanB<<<(K_*DI_*NS_)/256,256,0,stream>>>(Ech, Hch, carry);
    k_scanC<<<dim3(NCH_,DI_/16,4),256,0,stream>>>(bufXST, dts, bc, Ab, carry, yst);
    k_merge<<<1024,384,0,stream>>>(yst, bufXST, Dsk+(size_t)b*4*384, mw+(size_t)b*4,
                                   ong+(size_t)b*384, onb+(size_t)b*384, bufXZ, bufY);
    k_gemm<<<dim3(256,1),256,0,stream>>>(bufY, outWT+(size_t)b*384*192, nullptr, cur, nxt, 384, 192);
    float* t = cur; cur = nxt; nxt = t;
  }

  k_gemm<<<dim3(256,6),256,0,stream>>>(cur, puWT, pub, nullptr, bufP, 192, 1536);
  k_sum<<<(96*HW)/256,256,0,stream>>>(x, bufH, attn, bufP, bn2g, bn2b, bn2m, bn2v, xsum, h2);

  float* bufA = dts;
  float* bufB = dts + (size_t)48*HW;
  float* bufG = yst;
  float* bufT = yst + (size_t)48*HW;
  float* ab   = bufXST;
  k_1x1ab<<<dim3(48,64),256,0,stream>>>(h2, c1a, c1b, bufA, bufB);
  k_1x1g<<<dim3(48,64),256,0,stream>>>(bufB, k2w, k2b, bufG);
  k_conv3<<<dim3(48,64),256,0,stream>>>(bufA, k1w, nullptr, ab, 0);
  k_conv3<<<dim3(48,64),256,0,stream>>>(bufB, k3w, bufG, bufT, 1);
  k_conv3<<<dim3(48,64),256,0,stream>>>(bufT, k4w, nullptr, ab+(size_t)48*HW, 0);
  k_c3<<<dim3(96,64),256,0,stream>>>(ab, c3w, h2, xsum, out);
}

// Round 3
// 1580.704 us; speedup vs baseline: 3.3139x; 1.1789x over previous
//
#include <hip/hip_runtime.h>
#include <math.h>

#define HW 16384
constexpr int C_ = 96;
constexpr int E_ = 192, DI_ = 384, NS_ = 16, R_ = 12, K_ = 4, NBLK_ = 8, GW_ = 48;
constexpr int L_ = 1024, CXP_ = 44; // R + 2*NS
constexpr int TC_ = 64;             // scan chunk length
constexpr int NCH_ = L_ / TC_;      // 16 chunks

__device__ __forceinline__ float lrelu_(float x){ return x >= 0.f ? x : 0.2f*x; }
__device__ __forceinline__ float sigmoid_(float x){ return 1.f/(1.f+expf(-x)); }
__device__ __forceinline__ float silu_(float x){ return x/(1.f+expf(-x)); }
__device__ __forceinline__ float softplus_(float x){ return fmaxf(x,0.f)+log1pf(expf(-fabsf(x))); }

// ---------------- generic tiled transpose: out[b][c][r] = in[b][r*in_stride + c]
__global__ void k_transpose(const float* __restrict__ in, float* __restrict__ out,
                            int rows, int cols, int in_stride){
  __shared__ float t[32][33];
  const float* ib = in + (size_t)blockIdx.z*rows*in_stride;
  float* ob = out + (size_t)blockIdx.z*rows*cols;
  int r0 = blockIdx.y*32, c0 = blockIdx.x*32;
  int tx = threadIdx.x, ty = threadIdx.y;
  for (int i=0;i<32;i+=8){
    int r = r0+ty+i, c = c0+tx;
    if (r<rows && c<cols) t[ty+i][tx] = ib[(size_t)r*in_stride+c];
  }
  __syncthreads();
  for (int i=0;i<32;i+=8){
    int c = c0+ty+i, r = r0+tx;
    if (r<rows && c<cols) ob[(size_t)c*rows+r] = t[tx][ty+i];
  }
}

// ---------------- bn1 + per-channel mean/max stats
__global__ void k_bn1(const float* __restrict__ x, const float* g, const float* b,
                      const float* m, const float* v,
                      float* __restrict__ h, float* __restrict__ stats){
  int c = blockIdx.x, tid = threadIdx.x;
  float sc = g[c]*rsqrtf(v[c]+1e-5f), sh = b[c]-m[c]*sc;
  const float* xc = x + (size_t)c*HW;
  float* hc = h + (size_t)c*HW;
  float s = 0.f, mx = -1e30f;
  for (int i=tid;i<HW;i+=256){
    float val = fmaf(xc[i], sc, sh);
    hc[i] = val; s += val; mx = fmaxf(mx, val);
  }
  for (int o=32;o;o>>=1){ s += __shfl_xor(s,o); mx = fmaxf(mx, __shfl_xor(mx,o)); }
  __shared__ float ss[4], sm[4];
  int wid = tid>>6, lane = tid&63;
  if (!lane){ ss[wid]=s; sm[wid]=mx; }
  __syncthreads();
  if (!tid){
    stats[c] = (ss[0]+ss[1]+ss[2]+ss[3])*(1.f/HW);
    stats[96+c] = fmaxf(fmaxf(sm[0],sm[1]),fmaxf(sm[2],sm[3]));
  }
}

// ---------------- channel-attention MLP (1 block)
__global__ void k_attn(const float* __restrict__ stats, const float* __restrict__ w1,
                       const float* __restrict__ w2, float* __restrict__ attn){
  __shared__ float hid[12];
  int tid = threadIdx.x;
  if (tid < 12){
    int j = tid%6, which = tid/6;
    const float* vv = stats + which*96;
    float a = 0.f;
    for (int c=0;c<96;c++) a += vv[c]*w1[j*96+c];
    hid[tid] = fmaxf(a, 0.f);
  }
  __syncthreads();
  if (tid < 96){
    float a = 0.f;
    for (int j=0;j<6;j++) a += (hid[j]+hid[6+j])*w2[tid*6+j];
    attn[tid] = sigmoid_(a);
  }
}

// ---------------- patchify h -> xp[l][1536]
__global__ void k_patchify(const float* __restrict__ h, float* __restrict__ xp){
  int idx = blockIdx.x*256 + threadIdx.x;
  int l = idx/1536, kk = idx%1536;
  int c = kk>>4, i = (kk>>2)&3, j = kk&3;
  int hp = l>>5, wp = l&31;
  xp[idx] = h[((size_t)c<<14) + (size_t)(hp*4+i)*128 + (wp*4+j)];
}

// ---------------- generic GEMM: out[l][n] = (res?) + Sum_k act[l][k]*wt[k][n] + (bias?)
__global__ __launch_bounds__(256) void k_gemm(const float* __restrict__ act,
                      const float* __restrict__ wt, const float* __restrict__ bias,
                      const float* __restrict__ res, float* __restrict__ out,
                      int K, int N){
  __shared__ float la[4*1536];
  int n = blockIdx.y*256 + threadIdx.x;
  int m0 = blockIdx.x*4;
  for (int i=threadIdx.x; i<4*K; i+=256)
    la[i] = act[(size_t)(m0 + i/K)*K + (i%K)];
  __syncthreads();
  if (n >= N) return;
  float a0=0,a1=0,a2=0,a3=0;
  const float* l0=la, *l1=la+K, *l2=la+2*K, *l3=la+3*K;
  const float* wp = wt + n;
  for (int k=0;k<K;k++){
    float w = wp[(size_t)k*N];
    a0 = fmaf(l0[k],w,a0); a1 = fmaf(l1[k],w,a1);
    a2 = fmaf(l2[k],w,a2); a3 = fmaf(l3[k],w,a3);
  }
  float bb = bias ? bias[n] : 0.f;
  size_t o = (size_t)m0*N + n;
  float r0 = res? res[o]:0.f, r1 = res? res[o+N]:0.f, r2 = res? res[o+2*N]:0.f, r3 = res? res[o+3*N]:0.f;
  out[o]     = a0+bb+r0;
  out[o+N]   = a1+bb+r1;
  out[o+2*N] = a2+bb+r2;
  out[o+3*N] = a3+bb+r3;
}

// ---------------- layernorm over E_=192, one wave per row
__global__ void k_ln(const float* __restrict__ x, const float* __restrict__ g,
                     const float* __restrict__ b, float* __restrict__ out){
  int l = blockIdx.x*4 + (threadIdx.x>>6);
  int lane = threadIdx.x&63;
  const float* xr = x + (size_t)l*E_;
  float v0 = xr[lane], v1 = xr[lane+64], v2 = xr[lane+128];
  float s = v0+v1+v2, sq = v0*v0+v1*v1+v2*v2;
  for (int o=32;o;o>>=1){ s += __shfl_xor(s,o); sq += __shfl_xor(sq,o); }
  float mu = s*(1.f/192.f);
  float rs = rsqrtf(sq*(1.f/192.f) - mu*mu + 1e-5f);
  float* orow = out + (size_t)l*E_;
  orow[lane]     = (v0-mu)*rs*g[lane]     + b[lane];
  orow[lane+64]  = (v1-mu)*rs*g[lane+64]  + b[lane+64];
  orow[lane+128] = (v2-mu)*rs*g[lane+128] + b[lane+128];
}

// ---------------- depthwise 3x3 conv (SAME) + bias + silu; in/out [d][l], l=h*32+w
__global__ void k_dwconv(const float* __restrict__ xc, const float* __restrict__ w,
                         const float* __restrict__ bias, float* __restrict__ out){
  int d = blockIdx.x;
  const float* in = xc + (size_t)d*L_;
  float wk[9];
  #pragma unroll
  for (int i=0;i<9;i++) wk[i] = w[d*9+i];
  float bb = bias[d];
  for (int p=threadIdx.x; p<L_; p+=256){
    int hh = p>>5, ww = p&31;
    float acc = bb;
    #pragma unroll
    for (int di=0;di<3;di++){
      int y = hh+di-1;
      if ((unsigned)y >= 32u) continue;
      #pragma unroll
      for (int dj=0;dj<3;dj++){
        int xx = ww+dj-1;
        if ((unsigned)xx >= 32u) continue;
        acc = fmaf(in[y*32+xx], wk[di*3+dj], acc);
      }
    }
    out[(size_t)d*L_+p] = silu_(acc);
  }
}

// ---------------- build xs_t[k][t][d] (4 scan orders) from xcs[d][l]
__global__ void k_build_xst(const float* __restrict__ xcs, float* __restrict__ xst){
  __shared__ float t[32][33];
  int d0 = blockIdx.y*32;
  int h0 = blockIdx.x;          // l tile = h0*32 .. h0*32+31
  int l0 = h0*32;
  int tx = threadIdx.x, ty = threadIdx.y;
  for (int i=0;i<32;i+=8)
    t[ty+i][tx] = xcs[(size_t)(d0+ty+i)*L_ + l0+tx];
  __syncthreads();
  int d = d0+tx;
  for (int i=0;i<32;i+=8){
    int wq = ty+i;
    int l = l0+wq;
    float val = t[tx][wq];
    int t1 = wq*32 + h0;
    xst[(size_t)l*DI_ + d] = val;
    xst[(size_t)(L_ + t1)*DI_ + d] = val;
    xst[(size_t)(2*L_ + (1023-l))*DI_ + d] = val;
    xst[(size_t)(3*L_ + (1023-t1))*DI_ + d] = val;
  }
}

// ---------------- x_dbl[k][c][l] = Sum_d xs[k][d][l] * xw[k][c][d]
__global__ __launch_bounds__(256) void k_xdbl(const float* __restrict__ xcs,
                       const float* __restrict__ xw, float* __restrict__ xdbl){
  int k = blockIdx.z;
  int s = blockIdx.x*256 + threadIdx.x;   // source position in xcs row
  int Ts = ((s&31)<<5) | (s>>5);
  int lw;
  if (k==0) lw = s;
  else if (k==1) lw = Ts;
  else if (k==2) lw = 1023-s;
  else lw = 1023-Ts;
  int c0 = blockIdx.y*4;
  const float* w0 = xw + ((size_t)k*CXP_ + c0)*DI_;
  float a0=0,a1=0,a2=0,a3=0;
  const float* src = xcs + s;
  for (int d=0; d<DI_; d++){
    float v = src[(size_t)d*L_];
    a0 = fmaf(v, w0[d],        a0);
    a1 = fmaf(v, w0[DI_+d],    a1);
    a2 = fmaf(v, w0[2*DI_+d],  a2);
    a3 = fmaf(v, w0[3*DI_+d],  a3);
  }
  size_t base = ((size_t)k*CXP_ + c0)*L_ + lw;
  xdbl[base]       = a0;
  xdbl[base+L_]    = a1;
  xdbl[base+2*L_]  = a2;
  xdbl[base+3*L_]  = a3;
}

// ---------------- dt projection + softplus -> dts_t[k][l][d]
__global__ void k_dt(const float* __restrict__ xdbl, const float* __restrict__ dtw,
                     const float* __restrict__ dtb, float* __restrict__ dts_t){
  int k = blockIdx.y, l = blockIdx.x, d = threadIdx.x;
  float acc = dtb[(size_t)k*DI_ + d];
  const float* w = dtw + ((size_t)k*DI_ + d)*R_;
  const float* xr = xdbl + (size_t)k*CXP_*L_ + l;
  #pragma unroll
  for (int r=0;r<R_;r++) acc = fmaf(xr[(size_t)r*L_], w[r], acc);
  dts_t[((size_t)k*L_ + l)*DI_ + d] = softplus_(acc);
}

// ---------------- repack B,C -> bc[k][t][32]
__global__ void k_bc(const float* __restrict__ xdbl, float* __restrict__ bc){
  int idx = blockIdx.x*256 + threadIdx.x;
  int k = idx>>10, t = idx&1023;
  const float* src = xdbl + ((size_t)k*CXP_ + R_)*L_ + t;
  float* dst = bc + ((size_t)k*L_ + t)*32;
  #pragma unroll
  for (int c=0;c<32;c++) dst[c] = src[(size_t)c*L_];
}

// ---------------- chunked selective scan, phase A: per-chunk aggregates
__global__ __launch_bounds__(256) void k_scanA(const float* __restrict__ xst,
                      const float* __restrict__ dts_t, const float* __restrict__ bc,
                      const float* __restrict__ Alog,
                      float* __restrict__ Ech, float* __restrict__ Hch){
  int k = blockIdx.z;
  int d = blockIdx.y*16 + (threadIdx.x>>4);
  int n = threadIdx.x&15;
  int ch = blockIdx.x;
  float A = -expf(Alog[((size_t)k*DI_ + d)*NS_ + n]);
  float aL2 = A * 1.4426950408889634f;
  int t0 = ch*TC_;
  const float* dtp = dts_t + ((size_t)k*L_ + t0)*DI_ + d;
  const float* xp_ = xst   + ((size_t)k*L_ + t0)*DI_ + d;
  const float* bcp = bc    + ((size_t)k*L_ + t0)*32;
  float h = 0.f, Ep = 1.f;
  #pragma unroll 4
  for (int t=0;t<TC_;t++){
    float dt = dtp[(size_t)t*DI_];
    float xv = xp_[(size_t)t*DI_];
    float Bn = bcp[t*32+n];
    float e = exp2f(aL2*dt);
    h = fmaf(e, h, dt*xv*Bn);
    Ep *= e;
  }
  size_t idx = (((size_t)k*NCH_ + ch)*DI_ + d)*NS_ + n;
  Ech[idx] = Ep; Hch[idx] = h;
}

// ---------------- phase B: fold chunk aggregates -> carry-in per chunk
__global__ void k_scanB(const float* __restrict__ Ech, const float* __restrict__ Hch,
                        float* __restrict__ carry){
  int idx = blockIdx.x*256 + threadIdx.x;     // (k, d*16+n) flattened
  int k = idx / (DI_*NS_);
  int dn = idx % (DI_*NS_);
  float h = 0.f;
  #pragma unroll
  for (int c=0;c<NCH_;c++){
    size_t o = ((size_t)(k*NCH_+c)*DI_*NS_) + dn;
    carry[o] = h;
    h = fmaf(Ech[o], h, Hch[o]);
  }
}

// ---------------- phase C: recompute with carry-in, emit y
__global__ __launch_bounds__(256) void k_scanC(const float* __restrict__ xst,
                      const float* __restrict__ dts_t, const float* __restrict__ bc,
                      const float* __restrict__ Alog, const float* __restrict__ carry,
                      float* __restrict__ yst){
  int k = blockIdx.z;
  int d = blockIdx.y*16 + (threadIdx.x>>4);
  int n = threadIdx.x&15;
  int ch = blockIdx.x;
  float A = -expf(Alog[((size_t)k*DI_ + d)*NS_ + n]);
  float aL2 = A * 1.4426950408889634f;
  int t0 = ch*TC_;
  const float* dtp = dts_t + ((size_t)k*L_ + t0)*DI_ + d;
  const float* xp_ = xst   + ((size_t)k*L_ + t0)*DI_ + d;
  const float* bcp = bc    + ((size_t)k*L_ + t0)*32;
  float* yp = yst + ((size_t)k*L_ + t0)*DI_ + d;
  float h = carry[(((size_t)k*NCH_ + ch)*DI_ + d)*NS_ + n];
  #pragma unroll 4
  for (int t=0;t<TC_;t++){
    float dt = dtp[(size_t)t*DI_];
    float xv = xp_[(size_t)t*DI_];
    float Bn = bcp[t*32+n], Cn = bcp[t*32+16+n];
    float e = exp2f(aL2*dt);
    h = fmaf(e, h, dt*xv*Bn);
    float p = h*Cn;
    p += __shfl_xor(p,1); p += __shfl_xor(p,2);
    p += __shfl_xor(p,4); p += __shfl_xor(p,8);
    if (n==0) yp[(size_t)t*DI_] = p;
  }
}

// ---------------- merge 4 directions + Dskip + LN + silu(z) gate
__global__ void k_merge(const float* __restrict__ yst, const float* __restrict__ xst,
                        const float* __restrict__ Dsk, const float* __restrict__ mw,
                        const float* __restrict__ ong, const float* __restrict__ onb,
                        const float* __restrict__ xz, float* __restrict__ out){
  int l = blockIdx.x, d = threadIdx.x;
  int T = ((l&31)<<5) | (l>>5);
  int tt[4] = { l, T, 1023-l, 1023-T };
  float v = 0.f;
  #pragma unroll
  for (int k=0;k<4;k++){
    size_t idx = (size_t)(k*L_ + tt[k])*DI_ + d;
    v += mw[k]*(yst[idx] + xst[idx]*Dsk[k*DI_+d]);
  }
  float s = v, sq = v*v;
  for (int o=32;o;o>>=1){ s += __shfl_xor(s,o); sq += __shfl_xor(sq,o); }
  __shared__ float rs_[6], rq_[6];
  int lane = d&63, wid = d>>6;
  if (!lane){ rs_[wid]=s; rq_[wid]=sq; }
  __syncthreads();
  float ts=0.f, tq=0.f;
  #pragma unroll
  for (int i=0;i<6;i++){ ts += rs_[i]; tq += rq_[i]; }
  float mu = ts*(1.f/DI_);
  float rstd = rsqrtf(tq*(1.f/DI_) - mu*mu + 1e-5f);
  float y = (v-mu)*rstd*ong[d] + onb[d];
  float z = xz[(size_t)l*768 + DI_ + d];
  out[(size_t)l*DI_ + d] = y * silu_(z);
}

// ---------------- un-patchify + residual + attention + bn2
__global__ void k_sum(const float* __restrict__ x, const float* __restrict__ h,
                      const float* __restrict__ attn, const float* __restrict__ xu,
                      const float* g2, const float* b2, const float* m2, const float* v2,
                      float* __restrict__ xsum, float* __restrict__ h2){
  int idx = blockIdx.x*256 + threadIdx.x;
  int c = idx>>14, p = idx&16383;
  int hh = p>>7, ww = p&127;
  int l = (hh>>2)*32 + (ww>>2);
  int o = (c<<4) + ((hh&3)<<2) + (ww&3);
  float s = x[idx] + h[idx]*attn[c] + xu[(size_t)l*1536 + o];
  xsum[idx] = s;
  h2[idx] = (s - m2[c])*rsqrtf(v2[c]+1e-5f)*g2[c] + b2[c];
}

// ---------------- scpa: dual 1x1 conv + lrelu; 12 a-oc + 12 b-oc per block
// grid (4, 64); ocg = blockIdx.x
__global__ __launch_bounds__(256) void k_1x1ab(const float* __restrict__ h2,
                        const float* __restrict__ wa, const float* __restrict__ wb,
                        float* __restrict__ a, float* __restrict__ b){
  __shared__ float lw[96*24];          // [c][o24]: 12 a then 12 b
  int ocg = blockIdx.x;
  for (int i=threadIdx.x; i<96*24; i+=256){
    int o = i%24, c = i/24;
    lw[i] = (o<12) ? wa[(ocg*12 + o)*96 + c] : wb[(ocg*12 + (o-12))*96 + c];
  }
  __syncthreads();
  int p = blockIdx.y*256 + threadIdx.x;
  float acc[24];
  #pragma unroll
  for (int o=0;o<24;o++) acc[o]=0.f;
  for (int c=0;c<96;c++){
    float v = h2[(size_t)c*HW + p];
    const float* w = lw + c*24;
    #pragma unroll
    for (int o=0;o<24;o++) acc[o] = fmaf(v, w[o], acc[o]);
  }
  #pragma unroll
  for (int o=0;o<12;o++){
    a[(size_t)(ocg*12+o)*HW + p] = lrelu_(acc[o]);
    b[(size_t)(ocg*12+o)*HW + p] = lrelu_(acc[12+o]);
  }
}

// ---------------- scpa: 1x1 conv + bias + sigmoid (gate); 12 oc per block
__global__ __launch_bounds__(256) void k_1x1g(const float* __restrict__ b,
                       const float* __restrict__ w, const float* __restrict__ bias,
                       float* __restrict__ g){
  __shared__ float lw[48*12];
  int ocg = blockIdx.x;
  for (int i=threadIdx.x; i<48*12; i+=256){
    int o = i%12, c = i/12;
    lw[i] = w[(ocg*12 + o)*48 + c];
  }
  __syncthreads();
  int p = blockIdx.y*256 + threadIdx.x;
  float acc[12];
  #pragma unroll
  for (int o=0;o<12;o++) acc[o] = bias[ocg*12+o];
  for (int c=0;c<48;c++){
    float v = b[(size_t)c*HW + p];
    const float* wp = lw + c*12;
    #pragma unroll
    for (int o=0;o<12;o++) acc[o] = fmaf(v, wp[o], acc[o]);
  }
  #pragma unroll
  for (int o=0;o<12;o++) g[(size_t)(ocg*12+o)*HW + p] = sigmoid_(acc[o]);
}

// ---------------- scpa: 3x3 conv 48->48, 12 oc per block, weights in LDS
// grid (4, 64); epilogue mode 0=lrelu, 1=mul aux
__global__ __launch_bounds__(256) void k_conv3(const float* __restrict__ in,
                        const float* __restrict__ w, const float* __restrict__ aux,
                        float* __restrict__ out, int mode){
  __shared__ float lw[48*9*12];        // [ic][j][o12]
  int ocg = blockIdx.x;
  for (int i=threadIdx.x; i<48*9*12; i+=256){
    int o = i%12, j = (i/12)%9, ic = i/108;
    lw[i] = w[((size_t)(ocg*12+o)*48 + ic)*9 + j];
  }
  __syncthreads();
  int p = blockIdx.y*256 + threadIdx.x;
  int hh = p>>7, ww = p&127;
  float acc[12];
  #pragma unroll
  for (int o=0;o<12;o++) acc[o]=0.f;
  for (int ic=0; ic<48; ic++){
    const float* ip = in + (size_t)ic*HW;
    float xv[9];
    #pragma unroll
    for (int di=0;di<3;di++){
      int y = hh+di-1;
      bool yok = (unsigned)y < 128u;
      #pragma unroll
      for (int dj=0;dj<3;dj++){
        int xx = ww+dj-1;
        bool ok = yok && ((unsigned)xx < 128u);
        xv[di*3+dj] = ok ? ip[y*128+xx] : 0.f;
      }
    }
    const float* lwp = lw + ic*108;
    #pragma unroll
    for (int j=0;j<9;j++){
      float xj = xv[j];
      const float* wj = lwp + j*12;
      #pragma unroll
      for (int o=0;o<12;o++) acc[o] = fmaf(xj, wj[o], acc[o]);
    }
  }
  #pragma unroll
  for (int o=0;o<12;o++){
    size_t oi = (size_t)(ocg*12+o)*HW + p;
    out[oi] = (mode==0) ? lrelu_(acc[o]) : acc[o]*aux[oi];
  }
}

// ---------------- final 1x1 conv (96 in -> 24 oc per block) + both residuals
__global__ __launch_bounds__(256) void k_c3(const float* __restrict__ ab,
                     const float* __restrict__ w, const float* __restrict__ h2,
                     const float* __restrict__ xsum, float* __restrict__ out){
  __shared__ float lw[96*24];          // [j][o24]
  int ocg = blockIdx.x;
  for (int i=threadIdx.x; i<96*24; i+=256){
    int o = i%24, j = i/24;
    lw[i] = w[(ocg*24 + o)*96 + j];
  }
  __syncthreads();
  int p = blockIdx.y*256 + threadIdx.x;
  float acc[24];
  #pragma unroll
  for (int o=0;o<24;o++) acc[o]=0.f;
  for (int j=0;j<96;j++){
    float v = ab[(size_t)j*HW + p];
    const float* wp = lw + j*24;
    #pragma unroll
    for (int o=0;o<24;o++) acc[o] = fmaf(v, wp[o], acc[o]);
  }
  #pragma unroll
  for (int o=0;o<24;o++){
    size_t oi = (size_t)(ocg*24+o)*HW + p;
    out[oi] = acc[o] + h2[oi] + xsum[oi];
  }
}

extern "C" void kernel_launch(void* const* d_in, const int* in_sizes, int n_in,
                              void* d_out, int out_size, void* d_ws, size_t ws_size,
                              hipStream_t stream){
  (void)in_sizes; (void)n_in; (void)out_size; (void)ws_size;
  const float* x    = (const float*)d_in[0];
  const float* bn1g = (const float*)d_in[1];
  const float* bn1b = (const float*)d_in[2];
  const float* bn1m = (const float*)d_in[3];
  const float* bn1v = (const float*)d_in[4];
  const float* caw1 = (const float*)d_in[5];
  const float* caw2 = (const float*)d_in[6];
  const float* peW  = (const float*)d_in[7];
  const float* peb  = (const float*)d_in[8];
  const float* puW  = (const float*)d_in[9];
  const float* pub  = (const float*)d_in[10];
  const float* lng  = (const float*)d_in[11];
  const float* lnb  = (const float*)d_in[12];
  const float* inW  = (const float*)d_in[13];
  const float* convw= (const float*)d_in[14];
  const float* convb= (const float*)d_in[15];
  const float* xprojw=(const float*)d_in[16];
  const float* dtw  = (const float*)d_in[17];
  const float* dtb  = (const float*)d_in[18];
  const float* Alog = (const float*)d_in[19];
  const float* Dsk  = (const float*)d_in[20];
  const float* ong  = (const float*)d_in[21];
  const float* onb  = (const float*)d_in[22];
  const float* outW = (const float*)d_in[23];
  const float* mw   = (const float*)d_in[24];
  const float* bn2g = (const float*)d_in[25];
  const float* bn2b = (const float*)d_in[26];
  const float* bn2m = (const float*)d_in[27];
  const float* bn2v = (const float*)d_in[28];
  const float* c1a  = (const float*)d_in[29];
  const float* c1b  = (const float*)d_in[30];
  const float* k1w  = (const float*)d_in[31];
  const float* k2w  = (const float*)d_in[32];
  const float* k2b  = (const float*)d_in[33];
  const float* k3w  = (const float*)d_in[34];
  const float* k4w  = (const float*)d_in[35];
  const float* c3w  = (const float*)d_in[36];
  float* out = (float*)d_out;

  float* ws = (float*)d_ws;
  size_t off = 0;
  auto alloc = [&](size_t n){ float* p = ws + off; off += n; return p; };
  float* peWT  = alloc((size_t)1536*192);
  float* puWT  = alloc((size_t)192*1536);
  float* inWT  = alloc((size_t)8*192*768);
  float* outWT = alloc((size_t)8*384*192);
  float* bufH  = alloc((size_t)96*HW);
  float* stats = alloc(256);
  float* attn  = alloc(128);
  float* bufP  = alloc((size_t)1024*1536);   // xp, later xu
  float* x2a   = alloc((size_t)1024*192);
  float* x2b   = alloc((size_t)1024*192);
  float* bufLN = alloc((size_t)1024*192);
  float* bufXZ = alloc((size_t)1024*768);
  float* bufXC = alloc((size_t)384*1024);
  float* bufXCS= alloc((size_t)384*1024);
  float* bufXST= alloc((size_t)4*1024*384);  // later ab (96ch)
  float* xdbl  = alloc((size_t)4*44*1024);
  float* dts   = alloc((size_t)4*1024*384);  // later scpa a|b
  float* bc    = alloc((size_t)4*1024*32);
  float* yst   = alloc((size_t)4*1024*384);  // later scpa g|t
  float* bufY  = alloc((size_t)1024*384);
  float* xsum  = alloc((size_t)96*HW);
  float* h2    = alloc((size_t)96*HW);
  float* Ech   = alloc((size_t)K_*NCH_*DI_*NS_);
  float* Hch   = alloc((size_t)K_*NCH_*DI_*NS_);
  float* carry = alloc((size_t)K_*NCH_*DI_*NS_);

  dim3 tb(32,8);
  // weight transposes
  k_transpose<<<dim3(48,6,1), tb, 0, stream>>>(peW, peWT, 192, 1536, 1536);
  k_transpose<<<dim3(6,48,1), tb, 0, stream>>>(puW, puWT, 1536, 192, 192);
  k_transpose<<<dim3(6,24,8), tb, 0, stream>>>(inW, inWT, 768, 192, 192);
  k_transpose<<<dim3(12,6,8), tb, 0, stream>>>(outW, outWT, 192, 384, 384);

  k_bn1<<<96,256,0,stream>>>(x, bn1g, bn1b, bn1m, bn1v, bufH, stats);
  k_attn<<<1,128,0,stream>>>(stats, caw1, caw2, attn);
  k_patchify<<<(1024*1536)/256,256,0,stream>>>(bufH, bufP);
  k_gemm<<<dim3(256,1),256,0,stream>>>(bufP, peWT, peb, nullptr, x2a, 1536, 192);

  float* cur = x2a; float* nxt = x2b;
  for (int b=0;b<8;b++){
    k_ln<<<256,256,0,stream>>>(cur, lng+(size_t)b*192, lnb+(size_t)b*192, bufLN);
    k_gemm<<<dim3(256,3),256,0,stream>>>(bufLN, inWT+(size_t)b*192*768, nullptr, nullptr, bufXZ, 192, 768);
    k_transpose<<<dim3(12,32,1),tb,0,stream>>>(bufXZ, bufXC, 1024, 384, 768);
    k_dwconv<<<384,256,0,stream>>>(bufXC, convw+(size_t)b*384*9, convb+(size_t)b*384, bufXCS);
    k_build_xst<<<dim3(32,12),tb,0,stream>>>(bufXCS, bufXST);
    k_xdbl<<<dim3(4,11,4),256,0,stream>>>(bufXCS, xprojw+(size_t)b*4*44*384, xdbl);
    k_dt<<<dim3(1024,4),384,0,stream>>>(xdbl, dtw+(size_t)b*4*384*12, dtb+(size_t)b*4*384, dts);
    k_bc<<<16,256,0,stream>>>(xdbl, bc);
    const float* Ab = Alog + (size_t)b*4*384*16;
    k_scanA<<<dim3(NCH_,DI_/16,4),256,0,stream>>>(bufXST, dts, bc, Ab, Ech, Hch);
    k_scanB<<<(K_*DI_*NS_)/256,256,0,stream>>>(Ech, Hch, carry);
    k_scanC<<<dim3(NCH_,DI_/16,4),256,0,stream>>>(bufXST, dts, bc, Ab, carry, yst);
    k_merge<<<1024,384,0,stream>>>(yst, bufXST, Dsk+(size_t)b*4*384, mw+(size_t)b*4,
                                   ong+(size_t)b*384, onb+(size_t)b*384, bufXZ, bufY);
    k_gemm<<<dim3(256,1),256,0,stream>>>(bufY, outWT+(size_t)b*384*192, nullptr, cur, nxt, 384, 192);
    float* t = cur; cur = nxt; nxt = t;
  }

  k_gemm<<<dim3(256,6),256,0,stream>>>(cur, puWT, pub, nullptr, bufP, 192, 1536);
  k_sum<<<(96*HW)/256,256,0,stream>>>(x, bufH, attn, bufP, bn2g, bn2b, bn2m, bn2v, xsum, h2);

  float* bufA = dts;
  float* bufB = dts + (size_t)48*HW;
  float* bufG = yst;
  float* bufT = yst + (size_t)48*HW;
  float* ab   = bufXST;
  k_1x1ab<<<dim3(4,64),256,0,stream>>>(h2, c1a, c1b, bufA, bufB);
  k_1x1g<<<dim3(4,64),256,0,stream>>>(bufB, k2w, k2b, bufG);
  k_conv3<<<dim3(4,64),256,0,stream>>>(bufA, k1w, nullptr, ab, 0);
  k_conv3<<<dim3(4,64),256,0,stream>>>(bufB, k3w, bufG, bufT, 1);
  k_conv3<<<dim3(4,64),256,0,stream>>>(bufT, k4w, nullptr, ab+(size_t)48*HW, 0);
  k_c3<<<dim3(4,64),256,0,stream>>>(ab, c3w, h2, xsum, out);
}

// Round 4
// 1379.238 us; speedup vs baseline: 3.7980x; 1.1461x over previous
//
#include <hip/hip_runtime.h>
#include <math.h>

#define HW 16384
constexpr int C_ = 96;
constexpr int E_ = 192, DI_ = 384, NS_ = 16, R_ = 12, K_ = 4, NBLK_ = 8, GW_ = 48;
constexpr int L_ = 1024, CXP_ = 44; // R + 2*NS
constexpr int TC_ = 64;             // scan chunk length
constexpr int NCH_ = L_ / TC_;      // 16 chunks

__device__ __forceinline__ float lrelu_(float x){ return x >= 0.f ? x : 0.2f*x; }
__device__ __forceinline__ float sigmoid_(float x){ return 1.f/(1.f+expf(-x)); }
__device__ __forceinline__ float silu_(float x){ return x/(1.f+expf(-x)); }
__device__ __forceinline__ float softplus_(float x){ return fmaxf(x,0.f)+log1pf(expf(-fabsf(x))); }

// ---------------- generic tiled transpose: out[b][c][r] = in[b][r*in_stride + c]
__global__ void k_transpose(const float* __restrict__ in, float* __restrict__ out,
                            int rows, int cols, int in_stride){
  __shared__ float t[32][33];
  const float* ib = in + (size_t)blockIdx.z*rows*in_stride;
  float* ob = out + (size_t)blockIdx.z*rows*cols;
  int r0 = blockIdx.y*32, c0 = blockIdx.x*32;
  int tx = threadIdx.x, ty = threadIdx.y;
  for (int i=0;i<32;i+=8){
    int r = r0+ty+i, c = c0+tx;
    if (r<rows && c<cols) t[ty+i][tx] = ib[(size_t)r*in_stride+c];
  }
  __syncthreads();
  for (int i=0;i<32;i+=8){
    int c = c0+ty+i, r = r0+tx;
    if (r<rows && c<cols) ob[(size_t)c*rows+r] = t[tx][ty+i];
  }
}

// ---------------- bn1 + per-channel mean/max stats
__global__ void k_bn1(const float* __restrict__ x, const float* g, const float* b,
                      const float* m, const float* v,
                      float* __restrict__ h, float* __restrict__ stats){
  int c = blockIdx.x, tid = threadIdx.x;
  float sc = g[c]*rsqrtf(v[c]+1e-5f), sh = b[c]-m[c]*sc;
  const float* xc = x + (size_t)c*HW;
  float* hc = h + (size_t)c*HW;
  float s = 0.f, mx = -1e30f;
  for (int i=tid;i<HW;i+=256){
    float val = fmaf(xc[i], sc, sh);
    hc[i] = val; s += val; mx = fmaxf(mx, val);
  }
  for (int o=32;o;o>>=1){ s += __shfl_xor(s,o); mx = fmaxf(mx, __shfl_xor(mx,o)); }
  __shared__ float ss[4], sm[4];
  int wid = tid>>6, lane = tid&63;
  if (!lane){ ss[wid]=s; sm[wid]=mx; }
  __syncthreads();
  if (!tid){
    stats[c] = (ss[0]+ss[1]+ss[2]+ss[3])*(1.f/HW);
    stats[96+c] = fmaxf(fmaxf(sm[0],sm[1]),fmaxf(sm[2],sm[3]));
  }
}

// ---------------- channel-attention MLP (1 block)
__global__ void k_attn(const float* __restrict__ stats, const float* __restrict__ w1,
                       const float* __restrict__ w2, float* __restrict__ attn){
  __shared__ float hid[12];
  int tid = threadIdx.x;
  if (tid < 12){
    int j = tid%6, which = tid/6;
    const float* vv = stats + which*96;
    float a = 0.f;
    for (int c=0;c<96;c++) a += vv[c]*w1[j*96+c];
    hid[tid] = fmaxf(a, 0.f);
  }
  __syncthreads();
  if (tid < 96){
    float a = 0.f;
    for (int j=0;j<6;j++) a += (hid[j]+hid[6+j])*w2[tid*6+j];
    attn[tid] = sigmoid_(a);
  }
}

// ---------------- patchify h -> xp[l][1536]
__global__ void k_patchify(const float* __restrict__ h, float* __restrict__ xp){
  int idx = blockIdx.x*256 + threadIdx.x;
  int l = idx/1536, kk = idx%1536;
  int c = kk>>4, i = (kk>>2)&3, j = kk&3;
  int hp = l>>5, wp = l&31;
  xp[idx] = h[((size_t)c<<14) + (size_t)(hp*4+i)*128 + (wp*4+j)];
}

// ---------------- tiled GEMM 64x64: out[m][n] = (res?) + Sum_k act[m][k]*wt[k][n] + (bias?)
// grid (M/64, N/64); K%16==0
__global__ __launch_bounds__(256) void k_gemm64(const float* __restrict__ act,
                      const float* __restrict__ wt, const float* __restrict__ bias,
                      const float* __restrict__ res, float* __restrict__ out,
                      int K, int N){
  __shared__ float As[16][64];
  __shared__ float Bs[16][64];
  int tid = threadIdx.x;
  int m0 = blockIdx.x*64, n0 = blockIdx.y*64;
  int tx = tid&15, ty = tid>>4;
  int arow = tid>>2, akq = tid&3;
  int brow = tid>>4, bnq = tid&15;
  float acc[4][4] = {{0}};
  for (int k0=0; k0<K; k0+=16){
    float4 a   = *(const float4*)&act[(size_t)(m0+arow)*K + k0 + akq*4];
    float4 bvg = *(const float4*)&wt [(size_t)(k0+brow)*N + n0 + bnq*4];
    __syncthreads();
    As[akq*4+0][arow]=a.x; As[akq*4+1][arow]=a.y;
    As[akq*4+2][arow]=a.z; As[akq*4+3][arow]=a.w;
    *(float4*)&Bs[brow][bnq*4] = bvg;
    __syncthreads();
    #pragma unroll
    for (int kk=0; kk<16; kk++){
      float4 av = *(const float4*)&As[kk][ty*4];
      float4 bv = *(const float4*)&Bs[kk][tx*4];
      float aa[4] = {av.x,av.y,av.z,av.w};
      float bb[4] = {bv.x,bv.y,bv.z,bv.w};
      #pragma unroll
      for (int i=0;i<4;i++)
        #pragma unroll
        for (int j=0;j<4;j++) acc[i][j] = fmaf(aa[i], bb[j], acc[i][j]);
    }
  }
  float4 bq = bias ? *(const float4*)&bias[n0+tx*4] : make_float4(0.f,0.f,0.f,0.f);
  #pragma unroll
  for (int i=0;i<4;i++){
    size_t o = (size_t)(m0+ty*4+i)*N + n0 + tx*4;
    float4 r = res ? *(const float4*)&res[o] : make_float4(0.f,0.f,0.f,0.f);
    float4 ov;
    ov.x = acc[i][0]+bq.x+r.x; ov.y = acc[i][1]+bq.y+r.y;
    ov.z = acc[i][2]+bq.z+r.z; ov.w = acc[i][3]+bq.w+r.w;
    *(float4*)&out[o] = ov;
  }
}

// ---------------- tiled GEMM 32x32 (for N=192 shapes): grid (M/32, N/32); K%16==0
__global__ __launch_bounds__(256) void k_gemm32(const float* __restrict__ act,
                      const float* __restrict__ wt, const float* __restrict__ bias,
                      const float* __restrict__ res, float* __restrict__ out,
                      int K, int N){
  __shared__ float As[16][32];
  __shared__ float Bs[16][32];
  int tid = threadIdx.x;
  int m0 = blockIdx.x*32, n0 = blockIdx.y*32;
  int tx = tid&15, ty = tid>>4;
  int arow = tid>>3, akd = tid&7;
  int brow = tid>>4, bnd = tid&15;
  float acc[2][2] = {{0}};
  for (int k0=0; k0<K; k0+=16){
    float2 a   = *(const float2*)&act[(size_t)(m0+arow)*K + k0 + akd*2];
    float2 bvg = *(const float2*)&wt [(size_t)(k0+brow)*N + n0 + bnd*2];
    __syncthreads();
    As[akd*2+0][arow]=a.x; As[akd*2+1][arow]=a.y;
    *(float2*)&Bs[brow][bnd*2] = bvg;
    __syncthreads();
    #pragma unroll
    for (int kk=0; kk<16; kk++){
      float2 av = *(const float2*)&As[kk][ty*2];
      float2 bv = *(const float2*)&Bs[kk][tx*2];
      acc[0][0] = fmaf(av.x, bv.x, acc[0][0]);
      acc[0][1] = fmaf(av.x, bv.y, acc[0][1]);
      acc[1][0] = fmaf(av.y, bv.x, acc[1][0]);
      acc[1][1] = fmaf(av.y, bv.y, acc[1][1]);
    }
  }
  float2 bq = bias ? *(const float2*)&bias[n0+tx*2] : make_float2(0.f,0.f);
  #pragma unroll
  for (int i=0;i<2;i++){
    size_t o = (size_t)(m0+ty*2+i)*N + n0 + tx*2;
    float2 r = res ? *(const float2*)&res[o] : make_float2(0.f,0.f);
    float2 ov;
    ov.x = acc[i][0]+bq.x+r.x; ov.y = acc[i][1]+bq.y+r.y;
    *(float2*)&out[o] = ov;
  }
}

// ---------------- layernorm over E_=192, one wave per row
__global__ void k_ln(const float* __restrict__ x, const float* __restrict__ g,
                     const float* __restrict__ b, float* __restrict__ out){
  int l = blockIdx.x*4 + (threadIdx.x>>6);
  int lane = threadIdx.x&63;
  const float* xr = x + (size_t)l*E_;
  float v0 = xr[lane], v1 = xr[lane+64], v2 = xr[lane+128];
  float s = v0+v1+v2, sq = v0*v0+v1*v1+v2*v2;
  for (int o=32;o;o>>=1){ s += __shfl_xor(s,o); sq += __shfl_xor(sq,o); }
  float mu = s*(1.f/192.f);
  float rs = rsqrtf(sq*(1.f/192.f) - mu*mu + 1e-5f);
  float* orow = out + (size_t)l*E_;
  orow[lane]     = (v0-mu)*rs*g[lane]     + b[lane];
  orow[lane+64]  = (v1-mu)*rs*g[lane+64]  + b[lane+64];
  orow[lane+128] = (v2-mu)*rs*g[lane+128] + b[lane+128];
}

// ---------------- depthwise 3x3 conv (SAME) + bias + silu; in/out [d][l], l=h*32+w
__global__ void k_dwconv(const float* __restrict__ xc, const float* __restrict__ w,
                         const float* __restrict__ bias, float* __restrict__ out){
  int d = blockIdx.x;
  const float* in = xc + (size_t)d*L_;
  float wk[9];
  #pragma unroll
  for (int i=0;i<9;i++) wk[i] = w[d*9+i];
  float bb = bias[d];
  for (int p=threadIdx.x; p<L_; p+=256){
    int hh = p>>5, ww = p&31;
    float acc = bb;
    #pragma unroll
    for (int di=0;di<3;di++){
      int y = hh+di-1;
      if ((unsigned)y >= 32u) continue;
      #pragma unroll
      for (int dj=0;dj<3;dj++){
        int xx = ww+dj-1;
        if ((unsigned)xx >= 32u) continue;
        acc = fmaf(in[y*32+xx], wk[di*3+dj], acc);
      }
    }
    out[(size_t)d*L_+p] = silu_(acc);
  }
}

// ---------------- build xs_t[k][t][d] (4 scan orders) from xcs[d][l]
__global__ void k_build_xst(const float* __restrict__ xcs, float* __restrict__ xst){
  __shared__ float t[32][33];
  int d0 = blockIdx.y*32;
  int h0 = blockIdx.x;          // l tile = h0*32 .. h0*32+31
  int l0 = h0*32;
  int tx = threadIdx.x, ty = threadIdx.y;
  for (int i=0;i<32;i+=8)
    t[ty+i][tx] = xcs[(size_t)(d0+ty+i)*L_ + l0+tx];
  __syncthreads();
  int d = d0+tx;
  for (int i=0;i<32;i+=8){
    int wq = ty+i;
    int l = l0+wq;
    float val = t[tx][wq];
    int t1 = wq*32 + h0;
    xst[(size_t)l*DI_ + d] = val;
    xst[(size_t)(L_ + t1)*DI_ + d] = val;
    xst[(size_t)(2*L_ + (1023-l))*DI_ + d] = val;
    xst[(size_t)(3*L_ + (1023-t1))*DI_ + d] = val;
  }
}

// ---------------- x_dbl[k][c][l] = Sum_d xs[k][d][l] * xw[k][c][d]
__global__ __launch_bounds__(256) void k_xdbl(const float* __restrict__ xcs,
                       const float* __restrict__ xw, float* __restrict__ xdbl){
  int k = blockIdx.z;
  int s = blockIdx.x*256 + threadIdx.x;   // source position in xcs row
  int Ts = ((s&31)<<5) | (s>>5);
  int lw;
  if (k==0) lw = s;
  else if (k==1) lw = Ts;
  else if (k==2) lw = 1023-s;
  else lw = 1023-Ts;
  int c0 = blockIdx.y*4;
  const float* w0 = xw + ((size_t)k*CXP_ + c0)*DI_;
  float a0=0,a1=0,a2=0,a3=0;
  const float* src = xcs + s;
  for (int d=0; d<DI_; d++){
    float v = src[(size_t)d*L_];
    a0 = fmaf(v, w0[d],        a0);
    a1 = fmaf(v, w0[DI_+d],    a1);
    a2 = fmaf(v, w0[2*DI_+d],  a2);
    a3 = fmaf(v, w0[3*DI_+d],  a3);
  }
  size_t base = ((size_t)k*CXP_ + c0)*L_ + lw;
  xdbl[base]       = a0;
  xdbl[base+L_]    = a1;
  xdbl[base+2*L_]  = a2;
  xdbl[base+3*L_]  = a3;
}

// ---------------- dt projection + softplus -> dts_t[k][l][d]
__global__ void k_dt(const float* __restrict__ xdbl, const float* __restrict__ dtw,
                     const float* __restrict__ dtb, float* __restrict__ dts_t){
  int k = blockIdx.y, l = blockIdx.x, d = threadIdx.x;
  float acc = dtb[(size_t)k*DI_ + d];
  const float* w = dtw + ((size_t)k*DI_ + d)*R_;
  const float* xr = xdbl + (size_t)k*CXP_*L_ + l;
  #pragma unroll
  for (int r=0;r<R_;r++) acc = fmaf(xr[(size_t)r*L_], w[r], acc);
  dts_t[((size_t)k*L_ + l)*DI_ + d] = softplus_(acc);
}

// ---------------- repack B,C -> bc[k][t][32]
__global__ void k_bc(const float* __restrict__ xdbl, float* __restrict__ bc){
  int idx = blockIdx.x*256 + threadIdx.x;
  int k = idx>>10, t = idx&1023;
  const float* src = xdbl + ((size_t)k*CXP_ + R_)*L_ + t;
  float* dst = bc + ((size_t)k*L_ + t)*32;
  #pragma unroll
  for (int c=0;c<32;c++) dst[c] = src[(size_t)c*L_];
}

// ---------------- chunked selective scan, phase A: per-chunk aggregates
__global__ __launch_bounds__(256) void k_scanA(const float* __restrict__ xst,
                      const float* __restrict__ dts_t, const float* __restrict__ bc,
                      const float* __restrict__ Alog,
                      float* __restrict__ Ech, float* __restrict__ Hch){
  int k = blockIdx.z;
  int d = blockIdx.y*16 + (threadIdx.x>>4);
  int n = threadIdx.x&15;
  int ch = blockIdx.x;
  float A = -expf(Alog[((size_t)k*DI_ + d)*NS_ + n]);
  float aL2 = A * 1.4426950408889634f;
  int t0 = ch*TC_;
  const float* dtp = dts_t + ((size_t)k*L_ + t0)*DI_ + d;
  const float* xp_ = xst   + ((size_t)k*L_ + t0)*DI_ + d;
  const float* bcp = bc    + ((size_t)k*L_ + t0)*32;
  float h = 0.f, Ep = 1.f;
  #pragma unroll 4
  for (int t=0;t<TC_;t++){
    float dt = dtp[(size_t)t*DI_];
    float xv = xp_[(size_t)t*DI_];
    float Bn = bcp[t*32+n];
    float e = exp2f(aL2*dt);
    h = fmaf(e, h, dt*xv*Bn);
    Ep *= e;
  }
  size_t idx = (((size_t)k*NCH_ + ch)*DI_ + d)*NS_ + n;
  Ech[idx] = Ep; Hch[idx] = h;
}

// ---------------- phase B: fold chunk aggregates -> carry-in per chunk
__global__ void k_scanB(const float* __restrict__ Ech, const float* __restrict__ Hch,
                        float* __restrict__ carry){
  int idx = blockIdx.x*256 + threadIdx.x;     // (k, d*16+n) flattened
  int k = idx / (DI_*NS_);
  int dn = idx % (DI_*NS_);
  float h = 0.f;
  #pragma unroll
  for (int c=0;c<NCH_;c++){
    size_t o = ((size_t)(k*NCH_+c)*DI_*NS_) + dn;
    carry[o] = h;
    h = fmaf(Ech[o], h, Hch[o]);
  }
}

// ---------------- phase C: recompute with carry-in, emit y
__global__ __launch_bounds__(256) void k_scanC(const float* __restrict__ xst,
                      const float* __restrict__ dts_t, const float* __restrict__ bc,
                      const float* __restrict__ Alog, const float* __restrict__ carry,
                      float* __restrict__ yst){
  int k = blockIdx.z;
  int d = blockIdx.y*16 + (threadIdx.x>>4);
  int n = threadIdx.x&15;
  int ch = blockIdx.x;
  float A = -expf(Alog[((size_t)k*DI_ + d)*NS_ + n]);
  float aL2 = A * 1.4426950408889634f;
  int t0 = ch*TC_;
  const float* dtp = dts_t + ((size_t)k*L_ + t0)*DI_ + d;
  const float* xp_ = xst   + ((size_t)k*L_ + t0)*DI_ + d;
  const float* bcp = bc    + ((size_t)k*L_ + t0)*32;
  float* yp = yst + ((size_t)k*L_ + t0)*DI_ + d;
  float h = carry[(((size_t)k*NCH_ + ch)*DI_ + d)*NS_ + n];
  #pragma unroll 4
  for (int t=0;t<TC_;t++){
    float dt = dtp[(size_t)t*DI_];
    float xv = xp_[(size_t)t*DI_];
    float Bn = bcp[t*32+n], Cn = bcp[t*32+16+n];
    float e = exp2f(aL2*dt);
    h = fmaf(e, h, dt*xv*Bn);
    float p = h*Cn;
    p += __shfl_xor(p,1); p += __shfl_xor(p,2);
    p += __shfl_xor(p,4); p += __shfl_xor(p,8);
    if (n==0) yp[(size_t)t*DI_] = p;
  }
}

// ---------------- merge 4 directions + Dskip + LN + silu(z) gate
__global__ void k_merge(const float* __restrict__ yst, const float* __restrict__ xst,
                        const float* __restrict__ Dsk, const float* __restrict__ mw,
                        const float* __restrict__ ong, const float* __restrict__ onb,
                        const float* __restrict__ xz, float* __restrict__ out){
  int l = blockIdx.x, d = threadIdx.x;
  int T = ((l&31)<<5) | (l>>5);
  int tt[4] = { l, T, 1023-l, 1023-T };
  float v = 0.f;
  #pragma unroll
  for (int k=0;k<4;k++){
    size_t idx = (size_t)(k*L_ + tt[k])*DI_ + d;
    v += mw[k]*(yst[idx] + xst[idx]*Dsk[k*DI_+d]);
  }
  float s = v, sq = v*v;
  for (int o=32;o;o>>=1){ s += __shfl_xor(s,o); sq += __shfl_xor(sq,o); }
  __shared__ float rs_[6], rq_[6];
  int lane = d&63, wid = d>>6;
  if (!lane){ rs_[wid]=s; rq_[wid]=sq; }
  __syncthreads();
  float ts=0.f, tq=0.f;
  #pragma unroll
  for (int i=0;i<6;i++){ ts += rs_[i]; tq += rq_[i]; }
  float mu = ts*(1.f/DI_);
  float rstd = rsqrtf(tq*(1.f/DI_) - mu*mu + 1e-5f);
  float y = (v-mu)*rstd*ong[d] + onb[d];
  float z = xz[(size_t)l*768 + DI_ + d];
  out[(size_t)l*DI_ + d] = y * silu_(z);
}

// ---------------- un-patchify + residual + attention + bn2
__global__ void k_sum(const float* __restrict__ x, const float* __restrict__ h,
                      const float* __restrict__ attn, const float* __restrict__ xu,
                      const float* g2, const float* b2, const float* m2, const float* v2,
                      float* __restrict__ xsum, float* __restrict__ h2){
  int idx = blockIdx.x*256 + threadIdx.x;
  int c = idx>>14, p = idx&16383;
  int hh = p>>7, ww = p&127;
  int l = (hh>>2)*32 + (ww>>2);
  int o = (c<<4) + ((hh&3)<<2) + (ww&3);
  float s = x[idx] + h[idx]*attn[c] + xu[(size_t)l*1536 + o];
  xsum[idx] = s;
  h2[idx] = (s - m2[c])*rsqrtf(v2[c]+1e-5f)*g2[c] + b2[c];
}

// ---------------- scpa: dual 1x1 conv + lrelu; 12 a-oc + 12 b-oc per block
__global__ __launch_bounds__(256) void k_1x1ab(const float* __restrict__ h2,
                        const float* __restrict__ wa, const float* __restrict__ wb,
                        float* __restrict__ a, float* __restrict__ b){
  __shared__ float lw[96*24];          // [c][o24]: 12 a then 12 b
  int ocg = blockIdx.x;
  for (int i=threadIdx.x; i<96*24; i+=256){
    int o = i%24, c = i/24;
    lw[i] = (o<12) ? wa[(ocg*12 + o)*96 + c] : wb[(ocg*12 + (o-12))*96 + c];
  }
  __syncthreads();
  int p = blockIdx.y*256 + threadIdx.x;
  float acc[24];
  #pragma unroll
  for (int o=0;o<24;o++) acc[o]=0.f;
  for (int c=0;c<96;c++){
    float v = h2[(size_t)c*HW + p];
    const float* w = lw + c*24;
    #pragma unroll
    for (int o=0;o<24;o++) acc[o] = fmaf(v, w[o], acc[o]);
  }
  #pragma unroll
  for (int o=0;o<12;o++){
    a[(size_t)(ocg*12+o)*HW + p] = lrelu_(acc[o]);
    b[(size_t)(ocg*12+o)*HW + p] = lrelu_(acc[12+o]);
  }
}

// ---------------- scpa: 1x1 conv + bias + sigmoid (gate); 12 oc per block
__global__ __launch_bounds__(256) void k_1x1g(const float* __restrict__ b,
                       const float* __restrict__ w, const float* __restrict__ bias,
                       float* __restrict__ g){
  __shared__ float lw[48*12];
  int ocg = blockIdx.x;
  for (int i=threadIdx.x; i<48*12; i+=256){
    int o = i%12, c = i/12;
    lw[i] = w[(ocg*12 + o)*48 + c];
  }
  __syncthreads();
  int p = blockIdx.y*256 + threadIdx.x;
  float acc[12];
  #pragma unroll
  for (int o=0;o<12;o++) acc[o] = bias[ocg*12+o];
  for (int c=0;c<48;c++){
    float v = b[(size_t)c*HW + p];
    const float* wp = lw + c*12;
    #pragma unroll
    for (int o=0;o<12;o++) acc[o] = fmaf(v, wp[o], acc[o]);
  }
  #pragma unroll
  for (int o=0;o<12;o++) g[(size_t)(ocg*12+o)*HW + p] = sigmoid_(acc[o]);
}

// ---------------- scpa: 3x3 conv 48->48, 12 oc per block, weights in LDS
__global__ __launch_bounds__(256) void k_conv3(const float* __restrict__ in,
                        const float* __restrict__ w, const float* __restrict__ aux,
                        float* __restrict__ out, int mode){
  __shared__ float lw[48*9*12];        // [ic][j][o12]
  int ocg = blockIdx.x;
  for (int i=threadIdx.x; i<48*9*12; i+=256){
    int o = i%12, j = (i/12)%9, ic = i/108;
    lw[i] = w[((size_t)(ocg*12+o)*48 + ic)*9 + j];
  }
  __syncthreads();
  int p = blockIdx.y*256 + threadIdx.x;
  int hh = p>>7, ww = p&127;
  float acc[12];
  #pragma unroll
  for (int o=0;o<12;o++) acc[o]=0.f;
  for (int ic=0; ic<48; ic++){
    const float* ip = in + (size_t)ic*HW;
    float xv[9];
    #pragma unroll
    for (int di=0;di<3;di++){
      int y = hh+di-1;
      bool yok = (unsigned)y < 128u;
      #pragma unroll
      for (int dj=0;dj<3;dj++){
        int xx = ww+dj-1;
        bool ok = yok && ((unsigned)xx < 128u);
        xv[di*3+dj] = ok ? ip[y*128+xx] : 0.f;
      }
    }
    const float* lwp = lw + ic*108;
    #pragma unroll
    for (int j=0;j<9;j++){
      float xj = xv[j];
      const float* wj = lwp + j*12;
      #pragma unroll
      for (int o=0;o<12;o++) acc[o] = fmaf(xj, wj[o], acc[o]);
    }
  }
  #pragma unroll
  for (int o=0;o<12;o++){
    size_t oi = (size_t)(ocg*12+o)*HW + p;
    out[oi] = (mode==0) ? lrelu_(acc[o]) : acc[o]*aux[oi];
  }
}

// ---------------- final 1x1 conv (96 in -> 24 oc per block) + both residuals
__global__ __launch_bounds__(256) void k_c3(const float* __restrict__ ab,
                     const float* __restrict__ w, const float* __restrict__ h2,
                     const float* __restrict__ xsum, float* __restrict__ out){
  __shared__ float lw[96*24];          // [j][o24]
  int ocg = blockIdx.x;
  for (int i=threadIdx.x; i<96*24; i+=256){
    int o = i%24, j = i/24;
    lw[i] = w[(ocg*24 + o)*96 + j];
  }
  __syncthreads();
  int p = blockIdx.y*256 + threadIdx.x;
  float acc[24];
  #pragma unroll
  for (int o=0;o<24;o++) acc[o]=0.f;
  for (int j=0;j<96;j++){
    float v = ab[(size_t)j*HW + p];
    const float* wp = lw + j*24;
    #pragma unroll
    for (int o=0;o<24;o++) acc[o] = fmaf(v, wp[o], acc[o]);
  }
  #pragma unroll
  for (int o=0;o<24;o++){
    size_t oi = (size_t)(ocg*24+o)*HW + p;
    out[oi] = acc[o] + h2[oi] + xsum[oi];
  }
}

extern "C" void kernel_launch(void* const* d_in, const int* in_sizes, int n_in,
                              void* d_out, int out_size, void* d_ws, size_t ws_size,
                              hipStream_t stream){
  (void)in_sizes; (void)n_in; (void)out_size; (void)ws_size;
  const float* x    = (const float*)d_in[0];
  const float* bn1g = (const float*)d_in[1];
  const float* bn1b = (const float*)d_in[2];
  const float* bn1m = (const float*)d_in[3];
  const float* bn1v = (const float*)d_in[4];
  const float* caw1 = (const float*)d_in[5];
  const float* caw2 = (const float*)d_in[6];
  const float* peW  = (const float*)d_in[7];
  const float* peb  = (const float*)d_in[8];
  const float* puW  = (const float*)d_in[9];
  const float* pub  = (const float*)d_in[10];
  const float* lng  = (const float*)d_in[11];
  const float* lnb  = (const float*)d_in[12];
  const float* inW  = (const float*)d_in[13];
  const float* convw= (const float*)d_in[14];
  const float* convb= (const float*)d_in[15];
  const float* xprojw=(const float*)d_in[16];
  const float* dtw  = (const float*)d_in[17];
  const float* dtb  = (const float*)d_in[18];
  const float* Alog = (const float*)d_in[19];
  const float* Dsk  = (const float*)d_in[20];
  const float* ong  = (const float*)d_in[21];
  const float* onb  = (const float*)d_in[22];
  const float* outW = (const float*)d_in[23];
  const float* mw   = (const float*)d_in[24];
  const float* bn2g = (const float*)d_in[25];
  const float* bn2b = (const float*)d_in[26];
  const float* bn2m = (const float*)d_in[27];
  const float* bn2v = (const float*)d_in[28];
  const float* c1a  = (const float*)d_in[29];
  const float* c1b  = (const float*)d_in[30];
  const float* k1w  = (const float*)d_in[31];
  const float* k2w  = (const float*)d_in[32];
  const float* k2b  = (const float*)d_in[33];
  const float* k3w  = (const float*)d_in[34];
  const float* k4w  = (const float*)d_in[35];
  const float* c3w  = (const float*)d_in[36];
  float* out = (float*)d_out;

  float* ws = (float*)d_ws;
  size_t off = 0;
  auto alloc = [&](size_t n){ float* p = ws + off; off += n; return p; };
  float* peWT  = alloc((size_t)1536*192);
  float* puWT  = alloc((size_t)192*1536);
  float* inWT  = alloc((size_t)8*192*768);
  float* outWT = alloc((size_t)8*384*192);
  float* bufH  = alloc((size_t)96*HW);
  float* stats = alloc(256);
  float* attn  = alloc(128);
  float* bufP  = alloc((size_t)1024*1536);   // xp, later xu
  float* x2a   = alloc((size_t)1024*192);
  float* x2b   = alloc((size_t)1024*192);
  float* bufLN = alloc((size_t)1024*192);
  float* bufXZ = alloc((size_t)1024*768);
  float* bufXC = alloc((size_t)384*1024);
  float* bufXCS= alloc((size_t)384*1024);
  float* bufXST= alloc((size_t)4*1024*384);  // later ab (96ch)
  float* xdbl  = alloc((size_t)4*44*1024);
  float* dts   = alloc((size_t)4*1024*384);  // later scpa a|b
  float* bc    = alloc((size_t)4*1024*32);
  float* yst   = alloc((size_t)4*1024*384);  // later scpa g|t
  float* bufY  = alloc((size_t)1024*384);
  float* xsum  = alloc((size_t)96*HW);
  float* h2    = alloc((size_t)96*HW);
  float* Ech   = alloc((size_t)K_*NCH_*DI_*NS_);
  float* Hch   = alloc((size_t)K_*NCH_*DI_*NS_);
  float* carry = alloc((size_t)K_*NCH_*DI_*NS_);

  dim3 tb(32,8);
  // weight transposes
  k_transpose<<<dim3(48,6,1), tb, 0, stream>>>(peW, peWT, 192, 1536, 1536);
  k_transpose<<<dim3(6,48,1), tb, 0, stream>>>(puW, puWT, 1536, 192, 192);
  k_transpose<<<dim3(6,24,8), tb, 0, stream>>>(inW, inWT, 768, 192, 192);
  k_transpose<<<dim3(12,6,8), tb, 0, stream>>>(outW, outWT, 192, 384, 384);

  k_bn1<<<96,256,0,stream>>>(x, bn1g, bn1b, bn1m, bn1v, bufH, stats);
  k_attn<<<1,128,0,stream>>>(stats, caw1, caw2, attn);
  k_patchify<<<(1024*1536)/256,256,0,stream>>>(bufH, bufP);
  k_gemm32<<<dim3(32,6),256,0,stream>>>(bufP, peWT, peb, nullptr, x2a, 1536, 192);

  float* cur = x2a; float* nxt = x2b;
  for (int b=0;b<8;b++){
    k_ln<<<256,256,0,stream>>>(cur, lng+(size_t)b*192, lnb+(size_t)b*192, bufLN);
    k_gemm64<<<dim3(16,12),256,0,stream>>>(bufLN, inWT+(size_t)b*192*768, nullptr, nullptr, bufXZ, 192, 768);
    k_transpose<<<dim3(12,32,1),tb,0,stream>>>(bufXZ, bufXC, 1024, 384, 768);
    k_dwconv<<<384,256,0,stream>>>(bufXC, convw+(size_t)b*384*9, convb+(size_t)b*384, bufXCS);
    k_build_xst<<<dim3(32,12),tb,0,stream>>>(bufXCS, bufXST);
    k_xdbl<<<dim3(4,11,4),256,0,stream>>>(bufXCS, xprojw+(size_t)b*4*44*384, xdbl);
    k_dt<<<dim3(1024,4),384,0,stream>>>(xdbl, dtw+(size_t)b*4*384*12, dtb+(size_t)b*4*384, dts);
    k_bc<<<16,256,0,stream>>>(xdbl, bc);
    const float* Ab = Alog + (size_t)b*4*384*16;
    k_scanA<<<dim3(NCH_,DI_/16,4),256,0,stream>>>(bufXST, dts, bc, Ab, Ech, Hch);
    k_scanB<<<(K_*DI_*NS_)/256,256,0,stream>>>(Ech, Hch, carry);
    k_scanC<<<dim3(NCH_,DI_/16,4),256,0,stream>>>(bufXST, dts, bc, Ab, carry, yst);
    k_merge<<<1024,384,0,stream>>>(yst, bufXST, Dsk+(size_t)b*4*384, mw+(size_t)b*4,
                                   ong+(size_t)b*384, onb+(size_t)b*384, bufXZ, bufY);
    k_gemm32<<<dim3(32,6),256,0,stream>>>(bufY, outWT+(size_t)b*384*192, nullptr, cur, nxt, 384, 192);
    float* t = cur; cur = nxt; nxt = t;
  }

  k_gemm64<<<dim3(16,24),256,0,stream>>>(cur, puWT, pub, nullptr, bufP, 192, 1536);
  k_sum<<<(96*HW)/256,256,0,stream>>>(x, bufH, attn, bufP, bn2g, bn2b, bn2m, bn2v, xsum, h2);

  float* bufA = dts;
  float* bufB = dts + (size_t)48*HW;
  float* bufG = yst;
  float* bufT = yst + (size_t)48*HW;
  float* ab   = bufXST;
  k_1x1ab<<<dim3(4,64),256,0,stream>>>(h2, c1a, c1b, bufA, bufB);
  k_1x1g<<<dim3(4,64),256,0,stream>>>(bufB, k2w, k2b, bufG);
  k_conv3<<<dim3(4,64),256,0,stream>>>(bufA, k1w, nullptr, ab, 0);
  k_conv3<<<dim3(4,64),256,0,stream>>>(bufB, k3w, bufG, bufT, 1);
  k_conv3<<<dim3(4,64),256,0,stream>>>(bufT, k4w, nullptr, ab+(size_t)48*HW, 0);
  k_c3<<<dim3(4,64),256,0,stream>>>(ab, c3w, h2, xsum, out);
}

// Round 5
// 1268.370 us; speedup vs baseline: 4.1300x; 1.0874x over previous
//
#include <hip/hip_runtime.h>
#include <math.h>

#define HW 16384
constexpr int C_ = 96;
constexpr int E_ = 192, DI_ = 384, NS_ = 16, R_ = 12, K_ = 4, NBLK_ = 8, GW_ = 48;
constexpr int L_ = 1024, CXP_ = 44; // R + 2*NS
constexpr int TC_ = 64;             // scan chunk length
constexpr int NCH_ = L_ / TC_;      // 16 chunks

__device__ __forceinline__ float lrelu_(float x){ return x >= 0.f ? x : 0.2f*x; }
__device__ __forceinline__ float sigmoid_(float x){ return 1.f/(1.f+expf(-x)); }
__device__ __forceinline__ float silu_(float x){ return x/(1.f+expf(-x)); }
__device__ __forceinline__ float softplus_(float x){ return fmaxf(x,0.f)+log1pf(expf(-fabsf(x))); }

// ---------------- generic tiled transpose: out[b][c][r] = in[b][r*in_stride + c]
__global__ void k_transpose(const float* __restrict__ in, float* __restrict__ out,
                            int rows, int cols, int in_stride){
  __shared__ float t[32][33];
  const float* ib = in + (size_t)blockIdx.z*rows*in_stride;
  float* ob = out + (size_t)blockIdx.z*rows*cols;
  int r0 = blockIdx.y*32, c0 = blockIdx.x*32;
  int tx = threadIdx.x, ty = threadIdx.y;
  for (int i=0;i<32;i+=8){
    int r = r0+ty+i, c = c0+tx;
    if (r<rows && c<cols) t[ty+i][tx] = ib[(size_t)r*in_stride+c];
  }
  __syncthreads();
  for (int i=0;i<32;i+=8){
    int c = c0+ty+i, r = r0+tx;
    if (r<rows && c<cols) ob[(size_t)c*rows+r] = t[tx][ty+i];
  }
}

// ---------------- bn1 + per-channel mean/max stats
__global__ void k_bn1(const float* __restrict__ x, const float* g, const float* b,
                      const float* m, const float* v,
                      float* __restrict__ h, float* __restrict__ stats){
  int c = blockIdx.x, tid = threadIdx.x;
  float sc = g[c]*rsqrtf(v[c]+1e-5f), sh = b[c]-m[c]*sc;
  const float* xc = x + (size_t)c*HW;
  float* hc = h + (size_t)c*HW;
  float s = 0.f, mx = -1e30f;
  for (int i=tid;i<HW;i+=256){
    float val = fmaf(xc[i], sc, sh);
    hc[i] = val; s += val; mx = fmaxf(mx, val);
  }
  for (int o=32;o;o>>=1){ s += __shfl_xor(s,o); mx = fmaxf(mx, __shfl_xor(mx,o)); }
  __shared__ float ss[4], sm[4];
  int wid = tid>>6, lane = tid&63;
  if (!lane){ ss[wid]=s; sm[wid]=mx; }
  __syncthreads();
  if (!tid){
    stats[c] = (ss[0]+ss[1]+ss[2]+ss[3])*(1.f/HW);
    stats[96+c] = fmaxf(fmaxf(sm[0],sm[1]),fmaxf(sm[2],sm[3]));
  }
}

// ---------------- channel-attention MLP (1 block)
__global__ void k_attn(const float* __restrict__ stats, const float* __restrict__ w1,
                       const float* __restrict__ w2, float* __restrict__ attn){
  __shared__ float hid[12];
  int tid = threadIdx.x;
  if (tid < 12){
    int j = tid%6, which = tid/6;
    const float* vv = stats + which*96;
    float a = 0.f;
    for (int c=0;c<96;c++) a += vv[c]*w1[j*96+c];
    hid[tid] = fmaxf(a, 0.f);
  }
  __syncthreads();
  if (tid < 96){
    float a = 0.f;
    for (int j=0;j<6;j++) a += (hid[j]+hid[6+j])*w2[tid*6+j];
    attn[tid] = sigmoid_(a);
  }
}

// ---------------- patchify h -> xp[l][1536]
__global__ void k_patchify(const float* __restrict__ h, float* __restrict__ xp){
  int idx = blockIdx.x*256 + threadIdx.x;
  int l = idx/1536, kk = idx%1536;
  int c = kk>>4, i = (kk>>2)&3, j = kk&3;
  int hp = l>>5, wp = l&31;
  xp[idx] = h[((size_t)c<<14) + (size_t)(hp*4+i)*128 + (wp*4+j)];
}

// ---------------- pipelined tiled GEMM 64x64, BK=16: grid (M/64, N/64); K%16==0
__global__ __launch_bounds__(256) void k_gemm64(const float* __restrict__ act,
                      const float* __restrict__ wt, const float* __restrict__ bias,
                      const float* __restrict__ res, float* __restrict__ out,
                      int K, int N){
  __shared__ float As[16][68];   // pad+4: conflict-free transposed stores, 16B-aligned reads
  __shared__ float Bs[16][64];
  int tid = threadIdx.x;
  int m0 = blockIdx.x*64, n0 = blockIdx.y*64;
  int tx = tid&15, ty = tid>>4;
  int arow = tid>>2, akq = tid&3;
  int brow = tid>>4, bnq = tid&15;
  float4 aR = *(const float4*)&act[(size_t)(m0+arow)*K + akq*4];
  float4 bR = *(const float4*)&wt [(size_t)brow*N + n0 + bnq*4];
  float acc[4][4] = {{0}};
  for (int k0=0; k0<K; k0+=16){
    __syncthreads();
    As[akq*4+0][arow]=aR.x; As[akq*4+1][arow]=aR.y;
    As[akq*4+2][arow]=aR.z; As[akq*4+3][arow]=aR.w;
    *(float4*)&Bs[brow][bnq*4] = bR;
    __syncthreads();
    if (k0+16 < K){
      aR = *(const float4*)&act[(size_t)(m0+arow)*K + k0+16 + akq*4];
      bR = *(const float4*)&wt [(size_t)(k0+16+brow)*N + n0 + bnq*4];
    }
    #pragma unroll
    for (int kk=0; kk<16; kk++){
      float4 av = *(const float4*)&As[kk][ty*4];
      float4 bv = *(const float4*)&Bs[kk][tx*4];
      float aa[4] = {av.x,av.y,av.z,av.w};
      float bb[4] = {bv.x,bv.y,bv.z,bv.w};
      #pragma unroll
      for (int i=0;i<4;i++)
        #pragma unroll
        for (int j=0;j<4;j++) acc[i][j] = fmaf(aa[i], bb[j], acc[i][j]);
    }
  }
  float4 bq = bias ? *(const float4*)&bias[n0+tx*4] : make_float4(0.f,0.f,0.f,0.f);
  #pragma unroll
  for (int i=0;i<4;i++){
    size_t o = (size_t)(m0+ty*4+i)*N + n0 + tx*4;
    float4 r = res ? *(const float4*)&res[o] : make_float4(0.f,0.f,0.f,0.f);
    float4 ov;
    ov.x = acc[i][0]+bq.x+r.x; ov.y = acc[i][1]+bq.y+r.y;
    ov.z = acc[i][2]+bq.z+r.z; ov.w = acc[i][3]+bq.w+r.w;
    *(float4*)&out[o] = ov;
  }
}

// ---------------- pipelined tiled GEMM 32x32, BK=32: grid (M/32, N/32); K%32==0
__global__ __launch_bounds__(256) void k_gemm32(const float* __restrict__ act,
                      const float* __restrict__ wt, const float* __restrict__ bias,
                      const float* __restrict__ res, float* __restrict__ out,
                      int K, int N){
  __shared__ float As[32][34];   // pad+2: conflict-free transposed stores, 8B-aligned reads
  __shared__ float Bs[32][32];
  int tid = threadIdx.x;
  int m0 = blockIdx.x*32, n0 = blockIdx.y*32;
  int tx = tid&15, ty = tid>>4;
  int arow = tid>>3, akq = tid&7;
  int brow = tid>>3, bn4 = tid&7;
  float4 aR = *(const float4*)&act[(size_t)(m0+arow)*K + akq*4];
  float4 bR = *(const float4*)&wt [(size_t)brow*N + n0 + bn4*4];
  float acc[2][2] = {{0}};
  for (int k0=0; k0<K; k0+=32){
    __syncthreads();
    As[akq*4+0][arow]=aR.x; As[akq*4+1][arow]=aR.y;
    As[akq*4+2][arow]=aR.z; As[akq*4+3][arow]=aR.w;
    *(float4*)&Bs[brow][bn4*4] = bR;
    __syncthreads();
    if (k0+32 < K){
      aR = *(const float4*)&act[(size_t)(m0+arow)*K + k0+32 + akq*4];
      bR = *(const float4*)&wt [(size_t)(k0+32+brow)*N + n0 + bn4*4];
    }
    #pragma unroll
    for (int kk=0; kk<32; kk++){
      float2 av = *(const float2*)&As[kk][ty*2];
      float2 bv = *(const float2*)&Bs[kk][tx*2];
      acc[0][0] = fmaf(av.x, bv.x, acc[0][0]);
      acc[0][1] = fmaf(av.x, bv.y, acc[0][1]);
      acc[1][0] = fmaf(av.y, bv.x, acc[1][0]);
      acc[1][1] = fmaf(av.y, bv.y, acc[1][1]);
    }
  }
  float2 bq = bias ? *(const float2*)&bias[n0+tx*2] : make_float2(0.f,0.f);
  #pragma unroll
  for (int i=0;i<2;i++){
    size_t o = (size_t)(m0+ty*2+i)*N + n0 + tx*2;
    float2 r = res ? *(const float2*)&res[o] : make_float2(0.f,0.f);
    float2 ov;
    ov.x = acc[i][0]+bq.x+r.x; ov.y = acc[i][1]+bq.y+r.y;
    *(float2*)&out[o] = ov;
  }
}

// ---------------- layernorm over E_=192, one wave per row
__global__ void k_ln(const float* __restrict__ x, const float* __restrict__ g,
                     const float* __restrict__ b, float* __restrict__ out){
  int l = blockIdx.x*4 + (threadIdx.x>>6);
  int lane = threadIdx.x&63;
  const float* xr = x + (size_t)l*E_;
  float v0 = xr[lane], v1 = xr[lane+64], v2 = xr[lane+128];
  float s = v0+v1+v2, sq = v0*v0+v1*v1+v2*v2;
  for (int o=32;o;o>>=1){ s += __shfl_xor(s,o); sq += __shfl_xor(sq,o); }
  float mu = s*(1.f/192.f);
  float rs = rsqrtf(sq*(1.f/192.f) - mu*mu + 1e-5f);
  float* orow = out + (size_t)l*E_;
  orow[lane]     = (v0-mu)*rs*g[lane]     + b[lane];
  orow[lane+64]  = (v1-mu)*rs*g[lane+64]  + b[lane+64];
  orow[lane+128] = (v2-mu)*rs*g[lane+128] + b[lane+128];
}

// ---------------- depthwise 3x3 conv (SAME) + bias + silu; in/out [d][l], l=h*32+w
__global__ void k_dwconv(const float* __restrict__ xc, const float* __restrict__ w,
                         const float* __restrict__ bias, float* __restrict__ out){
  int d = blockIdx.x;
  const float* in = xc + (size_t)d*L_;
  float wk[9];
  #pragma unroll
  for (int i=0;i<9;i++) wk[i] = w[d*9+i];
  float bb = bias[d];
  for (int p=threadIdx.x; p<L_; p+=256){
    int hh = p>>5, ww = p&31;
    float acc = bb;
    #pragma unroll
    for (int di=0;di<3;di++){
      int y = hh+di-1;
      if ((unsigned)y >= 32u) continue;
      #pragma unroll
      for (int dj=0;dj<3;dj++){
        int xx = ww+dj-1;
        if ((unsigned)xx >= 32u) continue;
        acc = fmaf(in[y*32+xx], wk[di*3+dj], acc);
      }
    }
    out[(size_t)d*L_+p] = silu_(acc);
  }
}

// ---------------- build xs_t[k][t][d] (4 scan orders) from xcs[d][l]
__global__ void k_build_xst(const float* __restrict__ xcs, float* __restrict__ xst){
  __shared__ float t[32][33];
  int d0 = blockIdx.y*32;
  int h0 = blockIdx.x;          // l tile = h0*32 .. h0*32+31
  int l0 = h0*32;
  int tx = threadIdx.x, ty = threadIdx.y;
  for (int i=0;i<32;i+=8)
    t[ty+i][tx] = xcs[(size_t)(d0+ty+i)*L_ + l0+tx];
  __syncthreads();
  int d = d0+tx;
  for (int i=0;i<32;i+=8){
    int wq = ty+i;
    int l = l0+wq;
    float val = t[tx][wq];
    int t1 = wq*32 + h0;
    xst[(size_t)l*DI_ + d] = val;
    xst[(size_t)(L_ + t1)*DI_ + d] = val;
    xst[(size_t)(2*L_ + (1023-l))*DI_ + d] = val;
    xst[(size_t)(3*L_ + (1023-t1))*DI_ + d] = val;
  }
}

// ---------------- x_dbl[k][c][l] = Sum_d xs[k][d][l] * xw[k][c][d]
__global__ __launch_bounds__(256) void k_xdbl(const float* __restrict__ xcs,
                       const float* __restrict__ xw, float* __restrict__ xdbl){
  int k = blockIdx.z;
  int s = blockIdx.x*256 + threadIdx.x;   // source position in xcs row
  int Ts = ((s&31)<<5) | (s>>5);
  int lw;
  if (k==0) lw = s;
  else if (k==1) lw = Ts;
  else if (k==2) lw = 1023-s;
  else lw = 1023-Ts;
  int c0 = blockIdx.y*4;
  const float* w0 = xw + ((size_t)k*CXP_ + c0)*DI_;
  float a0=0,a1=0,a2=0,a3=0;
  const float* src = xcs + s;
  for (int d=0; d<DI_; d++){
    float v = src[(size_t)d*L_];
    a0 = fmaf(v, w0[d],        a0);
    a1 = fmaf(v, w0[DI_+d],    a1);
    a2 = fmaf(v, w0[2*DI_+d],  a2);
    a3 = fmaf(v, w0[3*DI_+d],  a3);
  }
  size_t base = ((size_t)k*CXP_ + c0)*L_ + lw;
  xdbl[base]       = a0;
  xdbl[base+L_]    = a1;
  xdbl[base+2*L_]  = a2;
  xdbl[base+3*L_]  = a3;
}

// ---------------- dt projection + softplus -> dts_t[k][l][d]
__global__ void k_dt(const float* __restrict__ xdbl, const float* __restrict__ dtw,
                     const float* __restrict__ dtb, float* __restrict__ dts_t){
  int k = blockIdx.y, l = blockIdx.x, d = threadIdx.x;
  float acc = dtb[(size_t)k*DI_ + d];
  const float* w = dtw + ((size_t)k*DI_ + d)*R_;
  const float* xr = xdbl + (size_t)k*CXP_*L_ + l;
  #pragma unroll
  for (int r=0;r<R_;r++) acc = fmaf(xr[(size_t)r*L_], w[r], acc);
  dts_t[((size_t)k*L_ + l)*DI_ + d] = softplus_(acc);
}

// ---------------- repack B,C -> bc[k][t][32]
__global__ void k_bc(const float* __restrict__ xdbl, float* __restrict__ bc){
  int idx = blockIdx.x*256 + threadIdx.x;
  int k = idx>>10, t = idx&1023;
  const float* src = xdbl + ((size_t)k*CXP_ + R_)*L_ + t;
  float* dst = bc + ((size_t)k*L_ + t)*32;
  #pragma unroll
  for (int c=0;c<32;c++) dst[c] = src[(size_t)c*L_];
}

// ---------------- chunked selective scan, phase A: per-chunk aggregates
__global__ __launch_bounds__(256) void k_scanA(const float* __restrict__ xst,
                      const float* __restrict__ dts_t, const float* __restrict__ bc,
                      const float* __restrict__ Alog,
                      float* __restrict__ Ech, float* __restrict__ Hch){
  int k = blockIdx.z;
  int d = blockIdx.y*16 + (threadIdx.x>>4);
  int n = threadIdx.x&15;
  int ch = blockIdx.x;
  float A = -expf(Alog[((size_t)k*DI_ + d)*NS_ + n]);
  float aL2 = A * 1.4426950408889634f;
  int t0 = ch*TC_;
  const float* dtp = dts_t + ((size_t)k*L_ + t0)*DI_ + d;
  const float* xp_ = xst   + ((size_t)k*L_ + t0)*DI_ + d;
  const float* bcp = bc    + ((size_t)k*L_ + t0)*32;
  float h = 0.f, Ep = 1.f;
  #pragma unroll 4
  for (int t=0;t<TC_;t++){
    float dt = dtp[(size_t)t*DI_];
    float xv = xp_[(size_t)t*DI_];
    float Bn = bcp[t*32+n];
    float e = exp2f(aL2*dt);
    h = fmaf(e, h, dt*xv*Bn);
    Ep *= e;
  }
  size_t idx = (((size_t)k*NCH_ + ch)*DI_ + d)*NS_ + n;
  Ech[idx] = Ep; Hch[idx] = h;
}

// ---------------- phase B: fold chunk aggregates -> carry-in per chunk
__global__ void k_scanB(const float* __restrict__ Ech, const float* __restrict__ Hch,
                        float* __restrict__ carry){
  int idx = blockIdx.x*256 + threadIdx.x;     // (k, d*16+n) flattened
  int k = idx / (DI_*NS_);
  int dn = idx % (DI_*NS_);
  float h = 0.f;
  #pragma unroll
  for (int c=0;c<NCH_;c++){
    size_t o = ((size_t)(k*NCH_+c)*DI_*NS_) + dn;
    carry[o] = h;
    h = fmaf(Ech[o], h, Hch[o]);
  }
}

// ---------------- phase C: recompute with carry-in, emit y
__global__ __launch_bounds__(256) void k_scanC(const float* __restrict__ xst,
                      const float* __restrict__ dts_t, const float* __restrict__ bc,
                      const float* __restrict__ Alog, const float* __restrict__ carry,
                      float* __restrict__ yst){
  int k = blockIdx.z;
  int d = blockIdx.y*16 + (threadIdx.x>>4);
  int n = threadIdx.x&15;
  int ch = blockIdx.x;
  float A = -expf(Alog[((size_t)k*DI_ + d)*NS_ + n]);
  float aL2 = A * 1.4426950408889634f;
  int t0 = ch*TC_;
  const float* dtp = dts_t + ((size_t)k*L_ + t0)*DI_ + d;
  const float* xp_ = xst   + ((size_t)k*L_ + t0)*DI_ + d;
  const float* bcp = bc    + ((size_t)k*L_ + t0)*32;
  float* yp = yst + ((size_t)k*L_ + t0)*DI_ + d;
  float h = carry[(((size_t)k*NCH_ + ch)*DI_ + d)*NS_ + n];
  #pragma unroll 4
  for (int t=0;t<TC_;t++){
    float dt = dtp[(size_t)t*DI_];
    float xv = xp_[(size_t)t*DI_];
    float Bn = bcp[t*32+n], Cn = bcp[t*32+16+n];
    float e = exp2f(aL2*dt);
    h = fmaf(e, h, dt*xv*Bn);
    float p = h*Cn;
    p += __shfl_xor(p,1); p += __shfl_xor(p,2);
    p += __shfl_xor(p,4); p += __shfl_xor(p,8);
    if (n==0) yp[(size_t)t*DI_] = p;
  }
}

// ---------------- merge 4 directions + Dskip + LN + silu(z) gate
__global__ void k_merge(const float* __restrict__ yst, const float* __restrict__ xst,
                        const float* __restrict__ Dsk, const float* __restrict__ mw,
                        const float* __restrict__ ong, const float* __restrict__ onb,
                        const float* __restrict__ xz, float* __restrict__ out){
  int l = blockIdx.x, d = threadIdx.x;
  int T = ((l&31)<<5) | (l>>5);
  int tt[4] = { l, T, 1023-l, 1023-T };
  float v = 0.f;
  #pragma unroll
  for (int k=0;k<4;k++){
    size_t idx = (size_t)(k*L_ + tt[k])*DI_ + d;
    v += mw[k]*(yst[idx] + xst[idx]*Dsk[k*DI_+d]);
  }
  float s = v, sq = v*v;
  for (int o=32;o;o>>=1){ s += __shfl_xor(s,o); sq += __shfl_xor(sq,o); }
  __shared__ float rs_[6], rq_[6];
  int lane = d&63, wid = d>>6;
  if (!lane){ rs_[wid]=s; rq_[wid]=sq; }
  __syncthreads();
  float ts=0.f, tq=0.f;
  #pragma unroll
  for (int i=0;i<6;i++){ ts += rs_[i]; tq += rq_[i]; }
  float mu = ts*(1.f/DI_);
  float rstd = rsqrtf(tq*(1.f/DI_) - mu*mu + 1e-5f);
  float y = (v-mu)*rstd*ong[d] + onb[d];
  float z = xz[(size_t)l*768 + DI_ + d];
  out[(size_t)l*DI_ + d] = y * silu_(z);
}

// ---------------- un-patchify + residual + attention + bn2
__global__ void k_sum(const float* __restrict__ x, const float* __restrict__ h,
                      const float* __restrict__ attn, const float* __restrict__ xu,
                      const float* g2, const float* b2, const float* m2, const float* v2,
                      float* __restrict__ xsum, float* __restrict__ h2){
  int idx = blockIdx.x*256 + threadIdx.x;
  int c = idx>>14, p = idx&16383;
  int hh = p>>7, ww = p&127;
  int l = (hh>>2)*32 + (ww>>2);
  int o = (c<<4) + ((hh&3)<<2) + (ww&3);
  float s = x[idx] + h[idx]*attn[c] + xu[(size_t)l*1536 + o];
  xsum[idx] = s;
  h2[idx] = (s - m2[c])*rsqrtf(v2[c]+1e-5f)*g2[c] + b2[c];
}

// ---------------- scpa: dual 1x1 conv + lrelu; 12 a-oc + 12 b-oc per block
__global__ __launch_bounds__(256) void k_1x1ab(const float* __restrict__ h2,
                        const float* __restrict__ wa, const float* __restrict__ wb,
                        float* __restrict__ a, float* __restrict__ b){
  __shared__ float lw[96*24];          // [c][o24]: 12 a then 12 b
  int ocg = blockIdx.x;
  for (int i=threadIdx.x; i<96*24; i+=256){
    int o = i%24, c = i/24;
    lw[i] = (o<12) ? wa[(ocg*12 + o)*96 + c] : wb[(ocg*12 + (o-12))*96 + c];
  }
  __syncthreads();
  int p = blockIdx.y*256 + threadIdx.x;
  float acc[24];
  #pragma unroll
  for (int o=0;o<24;o++) acc[o]=0.f;
  for (int c=0;c<96;c++){
    float v = h2[(size_t)c*HW + p];
    const float* w = lw + c*24;
    #pragma unroll
    for (int o=0;o<24;o++) acc[o] = fmaf(v, w[o], acc[o]);
  }
  #pragma unroll
  for (int o=0;o<12;o++){
    a[(size_t)(ocg*12+o)*HW + p] = lrelu_(acc[o]);
    b[(size_t)(ocg*12+o)*HW + p] = lrelu_(acc[12+o]);
  }
}

// ---------------- scpa: 1x1 conv + bias + sigmoid (gate); 12 oc per block
__global__ __launch_bounds__(256) void k_1x1g(const float* __restrict__ b,
                       const float* __restrict__ w, const float* __restrict__ bias,
                       float* __restrict__ g){
  __shared__ float lw[48*12];
  int ocg = blockIdx.x;
  for (int i=threadIdx.x; i<48*12; i+=256){
    int o = i%12, c = i/12;
    lw[i] = w[(ocg*12 + o)*48 + c];
  }
  __syncthreads();
  int p = blockIdx.y*256 + threadIdx.x;
  float acc[12];
  #pragma unroll
  for (int o=0;o<12;o++) acc[o] = bias[ocg*12+o];
  for (int c=0;c<48;c++){
    float v = b[(size_t)c*HW + p];
    const float* wp = lw + c*12;
    #pragma unroll
    for (int o=0;o<12;o++) acc[o] = fmaf(v, wp[o], acc[o]);
  }
  #pragma unroll
  for (int o=0;o<12;o++) g[(size_t)(ocg*12+o)*HW + p] = sigmoid_(acc[o]);
}

// ---------------- scpa: 3x3 conv 48->48, 12 oc per block, weights in LDS
__global__ __launch_bounds__(256) void k_conv3(const float* __restrict__ in,
                        const float* __restrict__ w, const float* __restrict__ aux,
                        float* __restrict__ out, int mode){
  __shared__ float lw[48*9*12];        // [ic][j][o12]
  int ocg = blockIdx.x;
  for (int i=threadIdx.x; i<48*9*12; i+=256){
    int o = i%12, j = (i/12)%9, ic = i/108;
    lw[i] = w[((size_t)(ocg*12+o)*48 + ic)*9 + j];
  }
  __syncthreads();
  int p = blockIdx.y*256 + threadIdx.x;
  int hh = p>>7, ww = p&127;
  float acc[12];
  #pragma unroll
  for (int o=0;o<12;o++) acc[o]=0.f;
  for (int ic=0; ic<48; ic++){
    const float* ip = in + (size_t)ic*HW;
    float xv[9];
    #pragma unroll
    for (int di=0;di<3;di++){
      int y = hh+di-1;
      bool yok = (unsigned)y < 128u;
      #pragma unroll
      for (int dj=0;dj<3;dj++){
        int xx = ww+dj-1;
        bool ok = yok && ((unsigned)xx < 128u);
        xv[di*3+dj] = ok ? ip[y*128+xx] : 0.f;
      }
    }
    const float* lwp = lw + ic*108;
    #pragma unroll
    for (int j=0;j<9;j++){
      float xj = xv[j];
      const float* wj = lwp + j*12;
      #pragma unroll
      for (int o=0;o<12;o++) acc[o] = fmaf(xj, wj[o], acc[o]);
    }
  }
  #pragma unroll
  for (int o=0;o<12;o++){
    size_t oi = (size_t)(ocg*12+o)*HW + p;
    out[oi] = (mode==0) ? lrelu_(acc[o]) : acc[o]*aux[oi];
  }
}

// ---------------- final 1x1 conv (96 in -> 24 oc per block) + both residuals
__global__ __launch_bounds__(256) void k_c3(const float* __restrict__ ab,
                     const float* __restrict__ w, const float* __restrict__ h2,
                     const float* __restrict__ xsum, float* __restrict__ out){
  __shared__ float lw[96*24];          // [j][o24]
  int ocg = blockIdx.x;
  for (int i=threadIdx.x; i<96*24; i+=256){
    int o = i%24, j = i/24;
    lw[i] = w[(ocg*24 + o)*96 + j];
  }
  __syncthreads();
  int p = blockIdx.y*256 + threadIdx.x;
  float acc[24];
  #pragma unroll
  for (int o=0;o<24;o++) acc[o]=0.f;
  for (int j=0;j<96;j++){
    float v = ab[(size_t)j*HW + p];
    const float* wp = lw + j*24;
    #pragma unroll
    for (int o=0;o<24;o++) acc[o] = fmaf(v, wp[o], acc[o]);
  }
  #pragma unroll
  for (int o=0;o<24;o++){
    size_t oi = (size_t)(ocg*24+o)*HW + p;
    out[oi] = acc[o] + h2[oi] + xsum[oi];
  }
}

extern "C" void kernel_launch(void* const* d_in, const int* in_sizes, int n_in,
                              void* d_out, int out_size, void* d_ws, size_t ws_size,
                              hipStream_t stream){
  (void)in_sizes; (void)n_in; (void)out_size; (void)ws_size;
  const float* x    = (const float*)d_in[0];
  const float* bn1g = (const float*)d_in[1];
  const float* bn1b = (const float*)d_in[2];
  const float* bn1m = (const float*)d_in[3];
  const float* bn1v = (const float*)d_in[4];
  const float* caw1 = (const float*)d_in[5];
  const float* caw2 = (const float*)d_in[6];
  const float* peW  = (const float*)d_in[7];
  const float* peb  = (const float*)d_in[8];
  const float* puW  = (const float*)d_in[9];
  const float* pub  = (const float*)d_in[10];
  const float* lng  = (const float*)d_in[11];
  const float* lnb  = (const float*)d_in[12];
  const float* inW  = (const float*)d_in[13];
  const float* convw= (const float*)d_in[14];
  const float* convb= (const float*)d_in[15];
  const float* xprojw=(const float*)d_in[16];
  const float* dtw  = (const float*)d_in[17];
  const float* dtb  = (const float*)d_in[18];
  const float* Alog = (const float*)d_in[19];
  const float* Dsk  = (const float*)d_in[20];
  const float* ong  = (const float*)d_in[21];
  const float* onb  = (const float*)d_in[22];
  const float* outW = (const float*)d_in[23];
  const float* mw   = (const float*)d_in[24];
  const float* bn2g = (const float*)d_in[25];
  const float* bn2b = (const float*)d_in[26];
  const float* bn2m = (const float*)d_in[27];
  const float* bn2v = (const float*)d_in[28];
  const float* c1a  = (const float*)d_in[29];
  const float* c1b  = (const float*)d_in[30];
  const float* k1w  = (const float*)d_in[31];
  const float* k2w  = (const float*)d_in[32];
  const float* k2b  = (const float*)d_in[33];
  const float* k3w  = (const float*)d_in[34];
  const float* k4w  = (const float*)d_in[35];
  const float* c3w  = (const float*)d_in[36];
  float* out = (float*)d_out;

  float* ws = (float*)d_ws;
  size_t off = 0;
  auto alloc = [&](size_t n){ float* p = ws + off; off += n; return p; };
  float* peWT  = alloc((size_t)1536*192);
  float* puWT  = alloc((size_t)192*1536);
  float* inWT  = alloc((size_t)8*192*768);
  float* outWT = alloc((size_t)8*384*192);
  float* bufH  = alloc((size_t)96*HW);
  float* stats = alloc(256);
  float* attn  = alloc(128);
  float* bufP  = alloc((size_t)1024*1536);   // xp, later xu
  float* x2a   = alloc((size_t)1024*192);
  float* x2b   = alloc((size_t)1024*192);
  float* bufLN = alloc((size_t)1024*192);
  float* bufXZ = alloc((size_t)1024*768);
  float* bufXC = alloc((size_t)384*1024);
  float* bufXCS= alloc((size_t)384*1024);
  float* bufXST= alloc((size_t)4*1024*384);  // later ab (96ch)
  float* xdbl  = alloc((size_t)4*44*1024);
  float* dts   = alloc((size_t)4*1024*384);  // later scpa a|b
  float* bc    = alloc((size_t)4*1024*32);
  float* yst   = alloc((size_t)4*1024*384);  // later scpa g|t
  float* bufY  = alloc((size_t)1024*384);
  float* xsum  = alloc((size_t)96*HW);
  float* h2    = alloc((size_t)96*HW);
  float* Ech   = alloc((size_t)K_*NCH_*DI_*NS_);
  float* Hch   = alloc((size_t)K_*NCH_*DI_*NS_);
  float* carry = alloc((size_t)K_*NCH_*DI_*NS_);

  dim3 tb(32,8);
  // weight transposes
  k_transpose<<<dim3(48,6,1), tb, 0, stream>>>(peW, peWT, 192, 1536, 1536);
  k_transpose<<<dim3(6,48,1), tb, 0, stream>>>(puW, puWT, 1536, 192, 192);
  k_transpose<<<dim3(6,24,8), tb, 0, stream>>>(inW, inWT, 768, 192, 192);
  k_transpose<<<dim3(12,6,8), tb, 0, stream>>>(outW, outWT, 192, 384, 384);

  k_bn1<<<96,256,0,stream>>>(x, bn1g, bn1b, bn1m, bn1v, bufH, stats);
  k_attn<<<1,128,0,stream>>>(stats, caw1, caw2, attn);
  k_patchify<<<(1024*1536)/256,256,0,stream>>>(bufH, bufP);
  k_gemm32<<<dim3(32,6),256,0,stream>>>(bufP, peWT, peb, nullptr, x2a, 1536, 192);

  float* cur = x2a; float* nxt = x2b;
  for (int b=0;b<8;b++){
    k_ln<<<256,256,0,stream>>>(cur, lng+(size_t)b*192, lnb+(size_t)b*192, bufLN);
    k_gemm64<<<dim3(16,12),256,0,stream>>>(bufLN, inWT+(size_t)b*192*768, nullptr, nullptr, bufXZ, 192, 768);
    k_transpose<<<dim3(12,32,1),tb,0,stream>>>(bufXZ, bufXC, 1024, 384, 768);
    k_dwconv<<<384,256,0,stream>>>(bufXC, convw+(size_t)b*384*9, convb+(size_t)b*384, bufXCS);
    k_build_xst<<<dim3(32,12),tb,0,stream>>>(bufXCS, bufXST);
    k_xdbl<<<dim3(4,11,4),256,0,stream>>>(bufXCS, xprojw+(size_t)b*4*44*384, xdbl);
    k_dt<<<dim3(1024,4),384,0,stream>>>(xdbl, dtw+(size_t)b*4*384*12, dtb+(size_t)b*4*384, dts);
    k_bc<<<16,256,0,stream>>>(xdbl, bc);
    const float* Ab = Alog + (size_t)b*4*384*16;
    k_scanA<<<dim3(NCH_,DI_/16,4),256,0,stream>>>(bufXST, dts, bc, Ab, Ech, Hch);
    k_scanB<<<(K_*DI_*NS_)/256,256,0,stream>>>(Ech, Hch, carry);
    k_scanC<<<dim3(NCH_,DI_/16,4),256,0,stream>>>(bufXST, dts, bc, Ab, carry, yst);
    k_merge<<<1024,384,0,stream>>>(yst, bufXST, Dsk+(size_t)b*4*384, mw+(size_t)b*4,
                                   ong+(size_t)b*384, onb+(size_t)b*384, bufXZ, bufY);
    k_gemm32<<<dim3(32,6),256,0,stream>>>(bufY, outWT+(size_t)b*384*192, nullptr, cur, nxt, 384, 192);
    float* t = cur; cur = nxt; nxt = t;
  }

  k_gemm64<<<dim3(16,24),256,0,stream>>>(cur, puWT, pub, nullptr, bufP, 192, 1536);
  k_sum<<<(96*HW)/256,256,0,stream>>>(x, bufH, attn, bufP, bn2g, bn2b, bn2m, bn2v, xsum, h2);

  float* bufA = dts;
  float* bufB = dts + (size_t)48*HW;
  float* bufG = yst;
  float* bufT = yst + (size_t)48*HW;
  float* ab   = bufXST;
  k_1x1ab<<<dim3(4,64),256,0,stream>>>(h2, c1a, c1b, bufA, bufB);
  k_1x1g<<<dim3(4,64),256,0,stream>>>(bufB, k2w, k2b, bufG);
  k_conv3<<<dim3(4,64),256,0,stream>>>(bufA, k1w, nullptr, ab, 0);
  k_conv3<<<dim3(4,64),256,0,stream>>>(bufB, k3w, bufG, bufT, 1);
  k_conv3<<<dim3(4,64),256,0,stream>>>(bufT, k4w, nullptr, ab+(size_t)48*HW, 0);
  k_c3<<<dim3(4,64),256,0,stream>>>(ab, c3w, h2, xsum, out);
}

// Round 6
// 1234.139 us; speedup vs baseline: 4.2445x; 1.0277x over previous
//
#include <hip/hip_runtime.h>
#include <math.h>

#define HW 16384
constexpr int C_ = 96;
constexpr int E_ = 192, DI_ = 384, NS_ = 16, R_ = 12, K_ = 4, NBLK_ = 8, GW_ = 48;
constexpr int L_ = 1024, CXP_ = 44; // R + 2*NS
constexpr int TC_ = 64;             // scan chunk length
constexpr int NCH_ = L_ / TC_;      // 16 chunks

__device__ __forceinline__ float lrelu_(float x){ return x >= 0.f ? x : 0.2f*x; }
__device__ __forceinline__ float sigmoid_(float x){ return 1.f/(1.f+expf(-x)); }
__device__ __forceinline__ float silu_(float x){ return x/(1.f+expf(-x)); }
__device__ __forceinline__ float softplus_(float x){ return fmaxf(x,0.f)+log1pf(expf(-fabsf(x))); }

// ---------------- generic tiled transpose: out[b][c][r] = in[b][r*in_stride + c]
__global__ void k_transpose(const float* __restrict__ in, float* __restrict__ out,
                            int rows, int cols, int in_stride){
  __shared__ float t[32][33];
  const float* ib = in + (size_t)blockIdx.z*rows*in_stride;
  float* ob = out + (size_t)blockIdx.z*rows*cols;
  int r0 = blockIdx.y*32, c0 = blockIdx.x*32;
  int tx = threadIdx.x, ty = threadIdx.y;
  for (int i=0;i<32;i+=8){
    int r = r0+ty+i, c = c0+tx;
    if (r<rows && c<cols) t[ty+i][tx] = ib[(size_t)r*in_stride+c];
  }
  __syncthreads();
  for (int i=0;i<32;i+=8){
    int c = c0+ty+i, r = r0+tx;
    if (r<rows && c<cols) ob[(size_t)c*rows+r] = t[tx][ty+i];
  }
}

// ---------------- bn1 + per-channel mean/max stats
__global__ void k_bn1(const float* __restrict__ x, const float* g, const float* b,
                      const float* m, const float* v,
                      float* __restrict__ h, float* __restrict__ stats){
  int c = blockIdx.x, tid = threadIdx.x;
  float sc = g[c]*rsqrtf(v[c]+1e-5f), sh = b[c]-m[c]*sc;
  const float* xc = x + (size_t)c*HW;
  float* hc = h + (size_t)c*HW;
  float s = 0.f, mx = -1e30f;
  for (int i=tid;i<HW;i+=256){
    float val = fmaf(xc[i], sc, sh);
    hc[i] = val; s += val; mx = fmaxf(mx, val);
  }
  for (int o=32;o;o>>=1){ s += __shfl_xor(s,o); mx = fmaxf(mx, __shfl_xor(mx,o)); }
  __shared__ float ss[4], sm[4];
  int wid = tid>>6, lane = tid&63;
  if (!lane){ ss[wid]=s; sm[wid]=mx; }
  __syncthreads();
  if (!tid){
    stats[c] = (ss[0]+ss[1]+ss[2]+ss[3])*(1.f/HW);
    stats[96+c] = fmaxf(fmaxf(sm[0],sm[1]),fmaxf(sm[2],sm[3]));
  }
}

// ---------------- channel-attention MLP (1 block)
__global__ void k_attn(const float* __restrict__ stats, const float* __restrict__ w1,
                       const float* __restrict__ w2, float* __restrict__ attn){
  __shared__ float hid[12];
  int tid = threadIdx.x;
  if (tid < 12){
    int j = tid%6, which = tid/6;
    const float* vv = stats + which*96;
    float a = 0.f;
    for (int c=0;c<96;c++) a += vv[c]*w1[j*96+c];
    hid[tid] = fmaxf(a, 0.f);
  }
  __syncthreads();
  if (tid < 96){
    float a = 0.f;
    for (int j=0;j<6;j++) a += (hid[j]+hid[6+j])*w2[tid*6+j];
    attn[tid] = sigmoid_(a);
  }
}

// ---------------- patchify h -> xp[l][1536]
__global__ void k_patchify(const float* __restrict__ h, float* __restrict__ xp){
  int idx = blockIdx.x*256 + threadIdx.x;
  int l = idx/1536, kk = idx%1536;
  int c = kk>>4, i = (kk>>2)&3, j = kk&3;
  int hp = l>>5, wp = l&31;
  xp[idx] = h[((size_t)c<<14) + (size_t)(hp*4+i)*128 + (wp*4+j)];
}

// ---------------- pipelined tiled GEMM 64x64, BK=16: grid (M/64, N/64); K%16==0
__global__ __launch_bounds__(256) void k_gemm64(const float* __restrict__ act,
                      const float* __restrict__ wt, const float* __restrict__ bias,
                      const float* __restrict__ res, float* __restrict__ out,
                      int K, int N){
  __shared__ float As[16][68];
  __shared__ float Bs[16][64];
  int tid = threadIdx.x;
  int m0 = blockIdx.x*64, n0 = blockIdx.y*64;
  int tx = tid&15, ty = tid>>4;
  int arow = tid>>2, akq = tid&3;
  int brow = tid>>4, bnq = tid&15;
  float4 aR = *(const float4*)&act[(size_t)(m0+arow)*K + akq*4];
  float4 bR = *(const float4*)&wt [(size_t)brow*N + n0 + bnq*4];
  float acc[4][4] = {{0}};
  for (int k0=0; k0<K; k0+=16){
    __syncthreads();
    As[akq*4+0][arow]=aR.x; As[akq*4+1][arow]=aR.y;
    As[akq*4+2][arow]=aR.z; As[akq*4+3][arow]=aR.w;
    *(float4*)&Bs[brow][bnq*4] = bR;
    __syncthreads();
    if (k0+16 < K){
      aR = *(const float4*)&act[(size_t)(m0+arow)*K + k0+16 + akq*4];
      bR = *(const float4*)&wt [(size_t)(k0+16+brow)*N + n0 + bnq*4];
    }
    #pragma unroll
    for (int kk=0; kk<16; kk++){
      float4 av = *(const float4*)&As[kk][ty*4];
      float4 bv = *(const float4*)&Bs[kk][tx*4];
      float aa[4] = {av.x,av.y,av.z,av.w};
      float bb[4] = {bv.x,bv.y,bv.z,bv.w};
      #pragma unroll
      for (int i=0;i<4;i++)
        #pragma unroll
        for (int j=0;j<4;j++) acc[i][j] = fmaf(aa[i], bb[j], acc[i][j]);
    }
  }
  float4 bq = bias ? *(const float4*)&bias[n0+tx*4] : make_float4(0.f,0.f,0.f,0.f);
  #pragma unroll
  for (int i=0;i<4;i++){
    size_t o = (size_t)(m0+ty*4+i)*N + n0 + tx*4;
    float4 r = res ? *(const float4*)&res[o] : make_float4(0.f,0.f,0.f,0.f);
    float4 ov;
    ov.x = acc[i][0]+bq.x+r.x; ov.y = acc[i][1]+bq.y+r.y;
    ov.z = acc[i][2]+bq.z+r.z; ov.w = acc[i][3]+bq.w+r.w;
    *(float4*)&out[o] = ov;
  }
}

// ---------------- pipelined tiled GEMM 32x32, BK=32: grid (M/32, N/32); K%32==0
__global__ __launch_bounds__(256) void k_gemm32(const float* __restrict__ act,
                      const float* __restrict__ wt, const float* __restrict__ bias,
                      const float* __restrict__ res, float* __restrict__ out,
                      int K, int N){
  __shared__ float As[32][34];
  __shared__ float Bs[32][32];
  int tid = threadIdx.x;
  int m0 = blockIdx.x*32, n0 = blockIdx.y*32;
  int tx = tid&15, ty = tid>>4;
  int arow = tid>>3, akq = tid&7;
  int brow = tid>>3, bn4 = tid&7;
  float4 aR = *(const float4*)&act[(size_t)(m0+arow)*K + akq*4];
  float4 bR = *(const float4*)&wt [(size_t)brow*N + n0 + bn4*4];
  float acc[2][2] = {{0}};
  for (int k0=0; k0<K; k0+=32){
    __syncthreads();
    As[akq*4+0][arow]=aR.x; As[akq*4+1][arow]=aR.y;
    As[akq*4+2][arow]=aR.z; As[akq*4+3][arow]=aR.w;
    *(float4*)&Bs[brow][bn4*4] = bR;
    __syncthreads();
    if (k0+32 < K){
      aR = *(const float4*)&act[(size_t)(m0+arow)*K + k0+32 + akq*4];
      bR = *(const float4*)&wt [(size_t)(k0+32+brow)*N + n0 + bn4*4];
    }
    #pragma unroll
    for (int kk=0; kk<32; kk++){
      float2 av = *(const float2*)&As[kk][ty*2];
      float2 bv = *(const float2*)&Bs[kk][tx*2];
      acc[0][0] = fmaf(av.x, bv.x, acc[0][0]);
      acc[0][1] = fmaf(av.x, bv.y, acc[0][1]);
      acc[1][0] = fmaf(av.y, bv.x, acc[1][0]);
      acc[1][1] = fmaf(av.y, bv.y, acc[1][1]);
    }
  }
  float2 bq = bias ? *(const float2*)&bias[n0+tx*2] : make_float2(0.f,0.f);
  #pragma unroll
  for (int i=0;i<2;i++){
    size_t o = (size_t)(m0+ty*2+i)*N + n0 + tx*2;
    float2 r = res ? *(const float2*)&res[o] : make_float2(0.f,0.f);
    float2 ov;
    ov.x = acc[i][0]+bq.x+r.x; ov.y = acc[i][1]+bq.y+r.y;
    *(float2*)&out[o] = ov;
  }
}

// ---------------- layernorm over E_=192, one wave per row
__global__ void k_ln(const float* __restrict__ x, const float* __restrict__ g,
                     const float* __restrict__ b, float* __restrict__ out){
  int l = blockIdx.x*4 + (threadIdx.x>>6);
  int lane = threadIdx.x&63;
  const float* xr = x + (size_t)l*E_;
  float v0 = xr[lane], v1 = xr[lane+64], v2 = xr[lane+128];
  float s = v0+v1+v2, sq = v0*v0+v1*v1+v2*v2;
  for (int o=32;o;o>>=1){ s += __shfl_xor(s,o); sq += __shfl_xor(sq,o); }
  float mu = s*(1.f/192.f);
  float rs = rsqrtf(sq*(1.f/192.f) - mu*mu + 1e-5f);
  float* orow = out + (size_t)l*E_;
  orow[lane]     = (v0-mu)*rs*g[lane]     + b[lane];
  orow[lane+64]  = (v1-mu)*rs*g[lane+64]  + b[lane+64];
  orow[lane+128] = (v2-mu)*rs*g[lane+128] + b[lane+128];
}

// ---------------- depthwise 3x3 conv (SAME) + bias + silu; in/out [d][l], l=h*32+w
__global__ void k_dwconv(const float* __restrict__ xc, const float* __restrict__ w,
                         const float* __restrict__ bias, float* __restrict__ out){
  int d = blockIdx.x;
  const float* in = xc + (size_t)d*L_;
  float wk[9];
  #pragma unroll
  for (int i=0;i<9;i++) wk[i] = w[d*9+i];
  float bb = bias[d];
  for (int p=threadIdx.x; p<L_; p+=256){
    int hh = p>>5, ww = p&31;
    float acc = bb;
    #pragma unroll
    for (int di=0;di<3;di++){
      int y = hh+di-1;
      if ((unsigned)y >= 32u) continue;
      #pragma unroll
      for (int dj=0;dj<3;dj++){
        int xx = ww+dj-1;
        if ((unsigned)xx >= 32u) continue;
        acc = fmaf(in[y*32+xx], wk[di*3+dj], acc);
      }
    }
    out[(size_t)d*L_+p] = silu_(acc);
  }
}

// ---------------- build xs_t[k][t][d] (4 scan orders) from xcs[d][l]
__global__ void k_build_xst(const float* __restrict__ xcs, float* __restrict__ xst){
  __shared__ float t[32][33];
  int d0 = blockIdx.y*32;
  int h0 = blockIdx.x;          // l tile = h0*32 .. h0*32+31
  int l0 = h0*32;
  int tx = threadIdx.x, ty = threadIdx.y;
  for (int i=0;i<32;i+=8)
    t[ty+i][tx] = xcs[(size_t)(d0+ty+i)*L_ + l0+tx];
  __syncthreads();
  int d = d0+tx;
  for (int i=0;i<32;i+=8){
    int wq = ty+i;
    int l = l0+wq;
    float val = t[tx][wq];
    int t1 = wq*32 + h0;
    xst[(size_t)l*DI_ + d] = val;
    xst[(size_t)(L_ + t1)*DI_ + d] = val;
    xst[(size_t)(2*L_ + (1023-l))*DI_ + d] = val;
    xst[(size_t)(3*L_ + (1023-t1))*DI_ + d] = val;
  }
}

// ---------------- x_dbl[k][c][l] = Sum_d xs[k][d][l] * xw[k][c][d]
__global__ __launch_bounds__(256) void k_xdbl(const float* __restrict__ xcs,
                       const float* __restrict__ xw, float* __restrict__ xdbl){
  int k = blockIdx.z;
  int s = blockIdx.x*256 + threadIdx.x;   // source position in xcs row
  int Ts = ((s&31)<<5) | (s>>5);
  int lw;
  if (k==0) lw = s;
  else if (k==1) lw = Ts;
  else if (k==2) lw = 1023-s;
  else lw = 1023-Ts;
  int c0 = blockIdx.y*4;
  const float* w0 = xw + ((size_t)k*CXP_ + c0)*DI_;
  float a0=0,a1=0,a2=0,a3=0;
  const float* src = xcs + s;
  for (int d=0; d<DI_; d++){
    float v = src[(size_t)d*L_];
    a0 = fmaf(v, w0[d],        a0);
    a1 = fmaf(v, w0[DI_+d],    a1);
    a2 = fmaf(v, w0[2*DI_+d],  a2);
    a3 = fmaf(v, w0[3*DI_+d],  a3);
  }
  size_t base = ((size_t)k*CXP_ + c0)*L_ + lw;
  xdbl[base]       = a0;
  xdbl[base+L_]    = a1;
  xdbl[base+2*L_]  = a2;
  xdbl[base+3*L_]  = a3;
}

// ---------------- dt projection + softplus -> dts_t[k][l][d]; also repack B,C -> bc[k][t][32]
__global__ void k_dtbc(const float* __restrict__ xdbl, const float* __restrict__ dtw,
                       const float* __restrict__ dtb, float* __restrict__ dts_t,
                       float* __restrict__ bc){
  int k = blockIdx.y, l = blockIdx.x, d = threadIdx.x;
  float acc = dtb[(size_t)k*DI_ + d];
  const float* w = dtw + ((size_t)k*DI_ + d)*R_;
  const float* xr = xdbl + (size_t)k*CXP_*L_ + l;
  #pragma unroll
  for (int r=0;r<R_;r++) acc = fmaf(xr[(size_t)r*L_], w[r], acc);
  dts_t[((size_t)k*L_ + l)*DI_ + d] = softplus_(acc);
  if (d < 32)
    bc[((size_t)k*L_ + l)*32 + d] = xdbl[((size_t)k*CXP_ + R_ + d)*L_ + l];
}

// ---------------- chunked selective scan, phase A: per-chunk aggregates
__global__ __launch_bounds__(256) void k_scanA(const float* __restrict__ xst,
                      const float* __restrict__ dts_t, const float* __restrict__ bc,
                      const float* __restrict__ Alog,
                      float* __restrict__ Ech, float* __restrict__ Hch){
  int k = blockIdx.z;
  int d = blockIdx.y*16 + (threadIdx.x>>4);
  int n = threadIdx.x&15;
  int ch = blockIdx.x;
  float A = -expf(Alog[((size_t)k*DI_ + d)*NS_ + n]);
  float aL2 = A * 1.4426950408889634f;
  int t0 = ch*TC_;
  const float* dtp = dts_t + ((size_t)k*L_ + t0)*DI_ + d;
  const float* xp_ = xst   + ((size_t)k*L_ + t0)*DI_ + d;
  const float* bcp = bc    + ((size_t)k*L_ + t0)*32;
  float h = 0.f, Ep = 1.f;
  #pragma unroll 4
  for (int t=0;t<TC_;t++){
    float dt = dtp[(size_t)t*DI_];
    float xv = xp_[(size_t)t*DI_];
    float Bn = bcp[t*32+n];
    float e = exp2f(aL2*dt);
    h = fmaf(e, h, dt*xv*Bn);
    Ep *= e;
  }
  size_t idx = (((size_t)k*NCH_ + ch)*DI_ + d)*NS_ + n;
  Ech[idx] = Ep; Hch[idx] = h;
}

// ---------------- phase B: fold chunk aggregates -> carry-in per chunk
__global__ void k_scanB(const float* __restrict__ Ech, const float* __restrict__ Hch,
                        float* __restrict__ carry){
  int idx = blockIdx.x*256 + threadIdx.x;     // (k, d*16+n) flattened
  int k = idx / (DI_*NS_);
  int dn = idx % (DI_*NS_);
  float h = 0.f;
  #pragma unroll
  for (int c=0;c<NCH_;c++){
    size_t o = ((size_t)(k*NCH_+c)*DI_*NS_) + dn;
    carry[o] = h;
    h = fmaf(Ech[o], h, Hch[o]);
  }
}

// ---------------- phase C: recompute with carry-in, emit y
__global__ __launch_bounds__(256) void k_scanC(const float* __restrict__ xst,
                      const float* __restrict__ dts_t, const float* __restrict__ bc,
                      const float* __restrict__ Alog, const float* __restrict__ carry,
                      float* __restrict__ yst){
  int k = blockIdx.z;
  int d = blockIdx.y*16 + (threadIdx.x>>4);
  int n = threadIdx.x&15;
  int ch = blockIdx.x;
  float A = -expf(Alog[((size_t)k*DI_ + d)*NS_ + n]);
  float aL2 = A * 1.4426950408889634f;
  int t0 = ch*TC_;
  const float* dtp = dts_t + ((size_t)k*L_ + t0)*DI_ + d;
  const float* xp_ = xst   + ((size_t)k*L_ + t0)*DI_ + d;
  const float* bcp = bc    + ((size_t)k*L_ + t0)*32;
  float* yp = yst + ((size_t)k*L_ + t0)*DI_ + d;
  float h = carry[(((size_t)k*NCH_ + ch)*DI_ + d)*NS_ + n];
  #pragma unroll 4
  for (int t=0;t<TC_;t++){
    float dt = dtp[(size_t)t*DI_];
    float xv = xp_[(size_t)t*DI_];
    float Bn = bcp[t*32+n], Cn = bcp[t*32+16+n];
    float e = exp2f(aL2*dt);
    h = fmaf(e, h, dt*xv*Bn);
    float p = h*Cn;
    p += __shfl_xor(p,1); p += __shfl_xor(p,2);
    p += __shfl_xor(p,4); p += __shfl_xor(p,8);
    if (n==0) yp[(size_t)t*DI_] = p;
  }
}

// ---------------- merge 4 directions + Dskip + LN + silu(z) gate
__global__ void k_merge(const float* __restrict__ yst, const float* __restrict__ xst,
                        const float* __restrict__ Dsk, const float* __restrict__ mw,
                        const float* __restrict__ ong, const float* __restrict__ onb,
                        const float* __restrict__ xz, float* __restrict__ out){
  int l = blockIdx.x, d = threadIdx.x;
  int T = ((l&31)<<5) | (l>>5);
  int tt[4] = { l, T, 1023-l, 1023-T };
  float v = 0.f;
  #pragma unroll
  for (int k=0;k<4;k++){
    size_t idx = (size_t)(k*L_ + tt[k])*DI_ + d;
    v += mw[k]*(yst[idx] + xst[idx]*Dsk[k*DI_+d]);
  }
  float s = v, sq = v*v;
  for (int o=32;o;o>>=1){ s += __shfl_xor(s,o); sq += __shfl_xor(sq,o); }
  __shared__ float rs_[6], rq_[6];
  int lane = d&63, wid = d>>6;
  if (!lane){ rs_[wid]=s; rq_[wid]=sq; }
  __syncthreads();
  float ts=0.f, tq=0.f;
  #pragma unroll
  for (int i=0;i<6;i++){ ts += rs_[i]; tq += rq_[i]; }
  float mu = ts*(1.f/DI_);
  float rstd = rsqrtf(tq*(1.f/DI_) - mu*mu + 1e-5f);
  float y = (v-mu)*rstd*ong[d] + onb[d];
  float z = xz[(size_t)l*768 + DI_ + d];
  out[(size_t)l*DI_ + d] = y * silu_(z);
}

// ---------------- un-patchify + residual + attention + bn2
__global__ void k_sum(const float* __restrict__ x, const float* __restrict__ h,
                      const float* __restrict__ attn, const float* __restrict__ xu,
                      const float* g2, const float* b2, const float* m2, const float* v2,
                      float* __restrict__ xsum, float* __restrict__ h2){
  int idx = blockIdx.x*256 + threadIdx.x;
  int c = idx>>14, p = idx&16383;
  int hh = p>>7, ww = p&127;
  int l = (hh>>2)*32 + (ww>>2);
  int o = (c<<4) + ((hh&3)<<2) + (ww&3);
  float s = x[idx] + h[idx]*attn[c] + xu[(size_t)l*1536 + o];
  xsum[idx] = s;
  h2[idx] = (s - m2[c])*rsqrtf(v2[c]+1e-5f)*g2[c] + b2[c];
}

// ---------------- scpa: dual 1x1 conv + lrelu; 6 a-oc + 6 b-oc per block; grid (8,64)
__global__ __launch_bounds__(256) void k_1x1ab(const float* __restrict__ h2,
                        const float* __restrict__ wa, const float* __restrict__ wb,
                        float* __restrict__ a, float* __restrict__ b){
  __shared__ float lw[96*12];          // [c][o12]: 6 a then 6 b
  int ocg = blockIdx.x;
  for (int i=threadIdx.x; i<96*12; i+=256){
    int o = i%12, c = i/12;
    lw[i] = (o<6) ? wa[(ocg*6 + o)*96 + c] : wb[(ocg*6 + (o-6))*96 + c];
  }
  __syncthreads();
  int p = blockIdx.y*256 + threadIdx.x;
  float acc[12];
  #pragma unroll
  for (int o=0;o<12;o++) acc[o]=0.f;
  for (int c=0;c<96;c++){
    float v = h2[(size_t)c*HW + p];
    const float* w = lw + c*12;
    #pragma unroll
    for (int o=0;o<12;o++) acc[o] = fmaf(v, w[o], acc[o]);
  }
  #pragma unroll
  for (int o=0;o<6;o++){
    a[(size_t)(ocg*6+o)*HW + p] = lrelu_(acc[o]);
    b[(size_t)(ocg*6+o)*HW + p] = lrelu_(acc[6+o]);
  }
}

// ---------------- scpa: 1x1 conv + bias + sigmoid (gate); 6 oc per block; grid (8,64)
__global__ __launch_bounds__(256) void k_1x1g(const float* __restrict__ b,
                       const float* __restrict__ w, const float* __restrict__ bias,
                       float* __restrict__ g){
  __shared__ float lw[48*6];
  int ocg = blockIdx.x;
  for (int i=threadIdx.x; i<48*6; i+=256){
    int o = i%6, c = i/6;
    lw[i] = w[(ocg*6 + o)*48 + c];
  }
  __syncthreads();
  int p = blockIdx.y*256 + threadIdx.x;
  float acc[6];
  #pragma unroll
  for (int o=0;o<6;o++) acc[o] = bias[ocg*6+o];
  for (int c=0;c<48;c++){
    float v = b[(size_t)c*HW + p];
    const float* wp = lw + c*6;
    #pragma unroll
    for (int o=0;o<6;o++) acc[o] = fmaf(v, wp[o], acc[o]);
  }
  #pragma unroll
  for (int o=0;o<6;o++) g[(size_t)(ocg*6+o)*HW + p] = sigmoid_(acc[o]);
}

// ---------------- scpa: 3x3 conv 48->48, 6 oc per block, weights in LDS; grid (8,64)
__global__ __launch_bounds__(256) void k_conv3(const float* __restrict__ in,
                        const float* __restrict__ w, const float* __restrict__ aux,
                        float* __restrict__ out, int mode){
  __shared__ float lw[48*9*6];         // [ic][j][o6]
  int ocg = blockIdx.x;
  for (int i=threadIdx.x; i<48*9*6; i+=256){
    int o = i%6, j = (i/6)%9, ic = i/54;
    lw[i] = w[((size_t)(ocg*6+o)*48 + ic)*9 + j];
  }
  __syncthreads();
  int p = blockIdx.y*256 + threadIdx.x;
  int hh = p>>7, ww = p&127;
  float acc[6];
  #pragma unroll
  for (int o=0;o<6;o++) acc[o]=0.f;
  for (int ic=0; ic<48; ic++){
    const float* ip = in + (size_t)ic*HW;
    float xv[9];
    #pragma unroll
    for (int di=0;di<3;di++){
      int y = hh+di-1;
      bool yok = (unsigned)y < 128u;
      #pragma unroll
      for (int dj=0;dj<3;dj++){
        int xx = ww+dj-1;
        bool ok = yok && ((unsigned)xx < 128u);
        xv[di*3+dj] = ok ? ip[y*128+xx] : 0.f;
      }
    }
    const float* lwp = lw + ic*54;
    #pragma unroll
    for (int j=0;j<9;j++){
      float xj = xv[j];
      const float* wj = lwp + j*6;
      #pragma unroll
      for (int o=0;o<6;o++) acc[o] = fmaf(xj, wj[o], acc[o]);
    }
  }
  #pragma unroll
  for (int o=0;o<6;o++){
    size_t oi = (size_t)(ocg*6+o)*HW + p;
    out[oi] = (mode==0) ? lrelu_(acc[o]) : acc[o]*aux[oi];
  }
}

// ---------------- final 1x1 conv (96 in -> 12 oc per block) + both residuals; grid (8,64)
__global__ __launch_bounds__(256) void k_c3(const float* __restrict__ ab,
                     const float* __restrict__ w, const float* __restrict__ h2,
                     const float* __restrict__ xsum, float* __restrict__ out){
  __shared__ float lw[96*12];          // [j][o12]
  int ocg = blockIdx.x;
  for (int i=threadIdx.x; i<96*12; i+=256){
    int o = i%12, j = i/12;
    lw[i] = w[(ocg*12 + o)*96 + j];
  }
  __syncthreads();
  int p = blockIdx.y*256 + threadIdx.x;
  float acc[12];
  #pragma unroll
  for (int o=0;o<12;o++) acc[o]=0.f;
  for (int j=0;j<96;j++){
    float v = ab[(size_t)j*HW + p];
    const float* wp = lw + j*12;
    #pragma unroll
    for (int o=0;o<12;o++) acc[o] = fmaf(v, wp[o], acc[o]);
  }
  #pragma unroll
  for (int o=0;o<12;o++){
    size_t oi = (size_t)(ocg*12+o)*HW + p;
    out[oi] = acc[o] + h2[oi] + xsum[oi];
  }
}

extern "C" void kernel_launch(void* const* d_in, const int* in_sizes, int n_in,
                              void* d_out, int out_size, void* d_ws, size_t ws_size,
                              hipStream_t stream){
  (void)in_sizes; (void)n_in; (void)out_size; (void)ws_size;
  const float* x    = (const float*)d_in[0];
  const float* bn1g = (const float*)d_in[1];
  const float* bn1b = (const float*)d_in[2];
  const float* bn1m = (const float*)d_in[3];
  const float* bn1v = (const float*)d_in[4];
  const float* caw1 = (const float*)d_in[5];
  const float* caw2 = (const float*)d_in[6];
  const float* peW  = (const float*)d_in[7];
  const float* peb  = (const float*)d_in[8];
  const float* puW  = (const float*)d_in[9];
  const float* pub  = (const float*)d_in[10];
  const float* lng  = (const float*)d_in[11];
  const float* lnb  = (const float*)d_in[12];
  const float* inW  = (const float*)d_in[13];
  const float* convw= (const float*)d_in[14];
  const float* convb= (const float*)d_in[15];
  const float* xprojw=(const float*)d_in[16];
  const float* dtw  = (const float*)d_in[17];
  const float* dtb  = (const float*)d_in[18];
  const float* Alog = (const float*)d_in[19];
  const float* Dsk  = (const float*)d_in[20];
  const float* ong  = (const float*)d_in[21];
  const float* onb  = (const float*)d_in[22];
  const float* outW = (const float*)d_in[23];
  const float* mw   = (const float*)d_in[24];
  const float* bn2g = (const float*)d_in[25];
  const float* bn2b = (const float*)d_in[26];
  const float* bn2m = (const float*)d_in[27];
  const float* bn2v = (const float*)d_in[28];
  const float* c1a  = (const float*)d_in[29];
  const float* c1b  = (const float*)d_in[30];
  const float* k1w  = (const float*)d_in[31];
  const float* k2w  = (const float*)d_in[32];
  const float* k2b  = (const float*)d_in[33];
  const float* k3w  = (const float*)d_in[34];
  const float* k4w  = (const float*)d_in[35];
  const float* c3w  = (const float*)d_in[36];
  float* out = (float*)d_out;

  float* ws = (float*)d_ws;
  size_t off = 0;
  auto alloc = [&](size_t n){ float* p = ws + off; off += n; return p; };
  float* peWT  = alloc((size_t)1536*192);
  float* puWT  = alloc((size_t)192*1536);
  float* inWT  = alloc((size_t)8*192*768);
  float* outWT = alloc((size_t)8*384*192);
  float* bufH  = alloc((size_t)96*HW);
  float* stats = alloc(256);
  float* attn  = alloc(128);
  float* bufP  = alloc((size_t)1024*1536);   // xp, later xu
  float* x2a   = alloc((size_t)1024*192);
  float* x2b   = alloc((size_t)1024*192);
  float* bufLN = alloc((size_t)1024*192);
  float* bufXZ = alloc((size_t)1024*768);
  float* bufXC = alloc((size_t)384*1024);
  float* bufXCS= alloc((size_t)384*1024);
  float* bufXST= alloc((size_t)4*1024*384);  // later ab (96ch)
  float* xdbl  = alloc((size_t)4*44*1024);
  float* dts   = alloc((size_t)4*1024*384);  // later scpa a|b
  float* bc    = alloc((size_t)4*1024*32);
  float* yst   = alloc((size_t)4*1024*384);  // later scpa g|t
  float* bufY  = alloc((size_t)1024*384);
  float* xsum  = alloc((size_t)96*HW);
  float* h2    = alloc((size_t)96*HW);
  float* Ech   = alloc((size_t)K_*NCH_*DI_*NS_);
  float* Hch   = alloc((size_t)K_*NCH_*DI_*NS_);
  float* carry = alloc((size_t)K_*NCH_*DI_*NS_);

  dim3 tb(32,8);
  // weight transposes
  k_transpose<<<dim3(48,6,1), tb, 0, stream>>>(peW, peWT, 192, 1536, 1536);
  k_transpose<<<dim3(6,48,1), tb, 0, stream>>>(puW, puWT, 1536, 192, 192);
  k_transpose<<<dim3(6,24,8), tb, 0, stream>>>(inW, inWT, 768, 192, 192);
  k_transpose<<<dim3(12,6,8), tb, 0, stream>>>(outW, outWT, 192, 384, 384);

  k_bn1<<<96,256,0,stream>>>(x, bn1g, bn1b, bn1m, bn1v, bufH, stats);
  k_attn<<<1,128,0,stream>>>(stats, caw1, caw2, attn);
  k_patchify<<<(1024*1536)/256,256,0,stream>>>(bufH, bufP);
  k_gemm32<<<dim3(32,6),256,0,stream>>>(bufP, peWT, peb, nullptr, x2a, 1536, 192);

  float* cur = x2a; float* nxt = x2b;
  for (int b=0;b<8;b++){
    k_ln<<<256,256,0,stream>>>(cur, lng+(size_t)b*192, lnb+(size_t)b*192, bufLN);
    k_gemm64<<<dim3(16,12),256,0,stream>>>(bufLN, inWT+(size_t)b*192*768, nullptr, nullptr, bufXZ, 192, 768);
    k_transpose<<<dim3(12,32,1),tb,0,stream>>>(bufXZ, bufXC, 1024, 384, 768);
    k_dwconv<<<384,256,0,stream>>>(bufXC, convw+(size_t)b*384*9, convb+(size_t)b*384, bufXCS);
    k_build_xst<<<dim3(32,12),tb,0,stream>>>(bufXCS, bufXST);
    k_xdbl<<<dim3(4,11,4),256,0,stream>>>(bufXCS, xprojw+(size_t)b*4*44*384, xdbl);
    k_dtbc<<<dim3(1024,4),384,0,stream>>>(xdbl, dtw+(size_t)b*4*384*12, dtb+(size_t)b*4*384, dts, bc);
    const float* Ab = Alog + (size_t)b*4*384*16;
    k_scanA<<<dim3(NCH_,DI_/16,4),256,0,stream>>>(bufXST, dts, bc, Ab, Ech, Hch);
    k_scanB<<<(K_*DI_*NS_)/256,256,0,stream>>>(Ech, Hch, carry);
    k_scanC<<<dim3(NCH_,DI_/16,4),256,0,stream>>>(bufXST, dts, bc, Ab, carry, yst);
    k_merge<<<1024,384,0,stream>>>(yst, bufXST, Dsk+(size_t)b*4*384, mw+(size_t)b*4,
                                   ong+(size_t)b*384, onb+(size_t)b*384, bufXZ, bufY);
    k_gemm32<<<dim3(32,6),256,0,stream>>>(bufY, outWT+(size_t)b*384*192, nullptr, cur, nxt, 384, 192);
    float* t = cur; cur = nxt; nxt = t;
  }

  k_gemm64<<<dim3(16,24),256,0,stream>>>(cur, puWT, pub, nullptr, bufP, 192, 1536);
  k_sum<<<(96*HW)/256,256,0,stream>>>(x, bufH, attn, bufP, bn2g, bn2b, bn2m, bn2v, xsum, h2);

  float* bufA = dts;
  float* bufB = dts + (size_t)48*HW;
  float* bufG = yst;
  float* bufT = yst + (size_t)48*HW;
  float* ab   = bufXST;
  k_1x1ab<<<dim3(8,64),256,0,stream>>>(h2, c1a, c1b, bufA, bufB);
  k_1x1g<<<dim3(8,64),256,0,stream>>>(bufB, k2w, k2b, bufG);
  k_conv3<<<dim3(8,64),256,0,stream>>>(bufA, k1w, nullptr, ab, 0);
  k_conv3<<<dim3(8,64),256,0,stream>>>(bufB, k3w, bufG, bufT, 1);
  k_conv3<<<dim3(8,64),256,0,stream>>>(bufT, k4w, nullptr, ab+(size_t)48*HW, 0);
  k_c3<<<dim3(8,64),256,0,stream>>>(ab, c3w, h2, xsum, out);
}

// Round 7
// 1160.923 us; speedup vs baseline: 4.5122x; 1.0631x over previous
//
#include <hip/hip_runtime.h>
#include <math.h>

#define HW 16384
constexpr int C_ = 96;
constexpr int E_ = 192, DI_ = 384, NS_ = 16, R_ = 12, K_ = 4, NBLK_ = 8, GW_ = 48;
constexpr int L_ = 1024, CXP_ = 44; // R + 2*NS
constexpr int TC_ = 64;             // scan chunk length
constexpr int NCH_ = L_ / TC_;      // 16 chunks

__device__ __forceinline__ float lrelu_(float x){ return x >= 0.f ? x : 0.2f*x; }
__device__ __forceinline__ float sigmoid_(float x){ return 1.f/(1.f+expf(-x)); }
__device__ __forceinline__ float silu_(float x){ return x/(1.f+expf(-x)); }
__device__ __forceinline__ float softplus_(float x){ return fmaxf(x,0.f)+log1pf(expf(-fabsf(x))); }

// ---------------- generic tiled transpose: out[b][c][r] = in[b][r*in_stride + c]
__global__ void k_transpose(const float* __restrict__ in, float* __restrict__ out,
                            int rows, int cols, int in_stride){
  __shared__ float t[32][33];
  const float* ib = in + (size_t)blockIdx.z*rows*in_stride;
  float* ob = out + (size_t)blockIdx.z*rows*cols;
  int r0 = blockIdx.y*32, c0 = blockIdx.x*32;
  int tx = threadIdx.x, ty = threadIdx.y;
  for (int i=0;i<32;i+=8){
    int r = r0+ty+i, c = c0+tx;
    if (r<rows && c<cols) t[ty+i][tx] = ib[(size_t)r*in_stride+c];
  }
  __syncthreads();
  for (int i=0;i<32;i+=8){
    int c = c0+ty+i, r = r0+tx;
    if (r<rows && c<cols) ob[(size_t)c*rows+r] = t[tx][ty+i];
  }
}

// ---------------- bn1 + per-channel mean/max stats
__global__ void k_bn1(const float* __restrict__ x, const float* g, const float* b,
                      const float* m, const float* v,
                      float* __restrict__ h, float* __restrict__ stats){
  int c = blockIdx.x, tid = threadIdx.x;
  float sc = g[c]*rsqrtf(v[c]+1e-5f), sh = b[c]-m[c]*sc;
  const float* xc = x + (size_t)c*HW;
  float* hc = h + (size_t)c*HW;
  float s = 0.f, mx = -1e30f;
  for (int i=tid;i<HW;i+=256){
    float val = fmaf(xc[i], sc, sh);
    hc[i] = val; s += val; mx = fmaxf(mx, val);
  }
  for (int o=32;o;o>>=1){ s += __shfl_xor(s,o); mx = fmaxf(mx, __shfl_xor(mx,o)); }
  __shared__ float ss[4], sm[4];
  int wid = tid>>6, lane = tid&63;
  if (!lane){ ss[wid]=s; sm[wid]=mx; }
  __syncthreads();
  if (!tid){
    stats[c] = (ss[0]+ss[1]+ss[2]+ss[3])*(1.f/HW);
    stats[96+c] = fmaxf(fmaxf(sm[0],sm[1]),fmaxf(sm[2],sm[3]));
  }
}

// ---------------- channel-attention MLP (1 block)
__global__ void k_attn(const float* __restrict__ stats, const float* __restrict__ w1,
                       const float* __restrict__ w2, float* __restrict__ attn){
  __shared__ float hid[12];
  int tid = threadIdx.x;
  if (tid < 12){
    int j = tid%6, which = tid/6;
    const float* vv = stats + which*96;
    float a = 0.f;
    for (int c=0;c<96;c++) a += vv[c]*w1[j*96+c];
    hid[tid] = fmaxf(a, 0.f);
  }
  __syncthreads();
  if (tid < 96){
    float a = 0.f;
    for (int j=0;j<6;j++) a += (hid[j]+hid[6+j])*w2[tid*6+j];
    attn[tid] = sigmoid_(a);
  }
}

// ---------------- patchify h -> xp[l][1536]
__global__ void k_patchify(const float* __restrict__ h, float* __restrict__ xp){
  int idx = blockIdx.x*256 + threadIdx.x;
  int l = idx/1536, kk = idx%1536;
  int c = kk>>4, i = (kk>>2)&3, j = kk&3;
  int hp = l>>5, wp = l&31;
  xp[idx] = h[((size_t)c<<14) + (size_t)(hp*4+i)*128 + (wp*4+j)];
}

// ---------------- pipelined tiled GEMM 32x32, BK=32: grid (M/32, N/32); K%32==0
__global__ __launch_bounds__(256) void k_gemm32(const float* __restrict__ act,
                      const float* __restrict__ wt, const float* __restrict__ bias,
                      const float* __restrict__ res, float* __restrict__ out,
                      int K, int N){
  __shared__ float As[32][34];
  __shared__ float Bs[32][32];
  int tid = threadIdx.x;
  int m0 = blockIdx.x*32, n0 = blockIdx.y*32;
  int tx = tid&15, ty = tid>>4;
  int arow = tid>>3, akq = tid&7;
  int brow = tid>>3, bn4 = tid&7;
  float4 aR = *(const float4*)&act[(size_t)(m0+arow)*K + akq*4];
  float4 bR = *(const float4*)&wt [(size_t)brow*N + n0 + bn4*4];
  float acc[2][2] = {{0}};
  for (int k0=0; k0<K; k0+=32){
    __syncthreads();
    As[akq*4+0][arow]=aR.x; As[akq*4+1][arow]=aR.y;
    As[akq*4+2][arow]=aR.z; As[akq*4+3][arow]=aR.w;
    *(float4*)&Bs[brow][bn4*4] = bR;
    __syncthreads();
    if (k0+32 < K){
      aR = *(const float4*)&act[(size_t)(m0+arow)*K + k0+32 + akq*4];
      bR = *(const float4*)&wt [(size_t)(k0+32+brow)*N + n0 + bn4*4];
    }
    #pragma unroll
    for (int kk=0; kk<32; kk++){
      float2 av = *(const float2*)&As[kk][ty*2];
      float2 bv = *(const float2*)&Bs[kk][tx*2];
      acc[0][0] = fmaf(av.x, bv.x, acc[0][0]);
      acc[0][1] = fmaf(av.x, bv.y, acc[0][1]);
      acc[1][0] = fmaf(av.y, bv.x, acc[1][0]);
      acc[1][1] = fmaf(av.y, bv.y, acc[1][1]);
    }
  }
  float2 bq = bias ? *(const float2*)&bias[n0+tx*2] : make_float2(0.f,0.f);
  #pragma unroll
  for (int i=0;i<2;i++){
    size_t o = (size_t)(m0+ty*2+i)*N + n0 + tx*2;
    float2 r = res ? *(const float2*)&res[o] : make_float2(0.f,0.f);
    float2 ov;
    ov.x = acc[i][0]+bq.x+r.x; ov.y = acc[i][1]+bq.y+r.y;
    *(float2*)&out[o] = ov;
  }
}

// ---------------- LN row-stats (mean, rstd) over E_=192
__global__ void k_lnstats(const float* __restrict__ x, float* __restrict__ mu,
                          float* __restrict__ rs){
  int l = blockIdx.x*4 + (threadIdx.x>>6);
  int lane = threadIdx.x&63;
  const float* xr = x + (size_t)l*E_;
  float v0 = xr[lane], v1 = xr[lane+64], v2 = xr[lane+128];
  float s = v0+v1+v2, sq = v0*v0+v1*v1+v2*v2;
  for (int o=32;o;o>>=1){ s += __shfl_xor(s,o); sq += __shfl_xor(sq,o); }
  if (!lane){
    float m = s*(1.f/192.f);
    mu[l] = m;
    rs[l] = rsqrtf(sq*(1.f/192.f) - m*m + 1e-5f);
  }
}

// ---------------- gemm32 with layernorm fused on the A operand (K%32==0)
__global__ __launch_bounds__(256) void k_gemm32ln(const float* __restrict__ act,
                      const float* __restrict__ wt, const float* __restrict__ lg,
                      const float* __restrict__ lb, const float* __restrict__ mu,
                      const float* __restrict__ rs, float* __restrict__ out,
                      int K, int N){
  __shared__ float As[32][34];
  __shared__ float Bs[32][32];
  int tid = threadIdx.x;
  int m0 = blockIdx.x*32, n0 = blockIdx.y*32;
  int tx = tid&15, ty = tid>>4;
  int arow = tid>>3, akq = tid&7;
  int brow = tid>>3, bn4 = tid&7;
  float m = mu[m0+arow], r = rs[m0+arow];
  float4 aR = *(const float4*)&act[(size_t)(m0+arow)*K + akq*4];
  float4 gR = *(const float4*)&lg[akq*4];
  float4 hR = *(const float4*)&lb[akq*4];
  float4 bR = *(const float4*)&wt[(size_t)brow*N + n0 + bn4*4];
  float acc[2][2] = {{0}};
  for (int k0=0; k0<K; k0+=32){
    __syncthreads();
    As[akq*4+0][arow] = (aR.x-m)*r*gR.x + hR.x;
    As[akq*4+1][arow] = (aR.y-m)*r*gR.y + hR.y;
    As[akq*4+2][arow] = (aR.z-m)*r*gR.z + hR.z;
    As[akq*4+3][arow] = (aR.w-m)*r*gR.w + hR.w;
    *(float4*)&Bs[brow][bn4*4] = bR;
    __syncthreads();
    if (k0+32 < K){
      aR = *(const float4*)&act[(size_t)(m0+arow)*K + k0+32 + akq*4];
      gR = *(const float4*)&lg[k0+32+akq*4];
      hR = *(const float4*)&lb[k0+32+akq*4];
      bR = *(const float4*)&wt[(size_t)(k0+32+brow)*N + n0 + bn4*4];
    }
    #pragma unroll
    for (int kk=0; kk<32; kk++){
      float2 av = *(const float2*)&As[kk][ty*2];
      float2 bv = *(const float2*)&Bs[kk][tx*2];
      acc[0][0] = fmaf(av.x, bv.x, acc[0][0]);
      acc[0][1] = fmaf(av.x, bv.y, acc[0][1]);
      acc[1][0] = fmaf(av.y, bv.x, acc[1][0]);
      acc[1][1] = fmaf(av.y, bv.y, acc[1][1]);
    }
  }
  #pragma unroll
  for (int i=0;i<2;i++){
    size_t o = (size_t)(m0+ty*2+i)*N + n0 + tx*2;
    float2 ov; ov.x = acc[i][0]; ov.y = acc[i][1];
    *(float2*)&out[o] = ov;
  }
}

// ---------------- fused depthwise conv + silu + 4-dir xst build; grid (32 h0, 12 d0), tb (32,8)
__global__ __launch_bounds__(256) void k_dwxst(const float* __restrict__ xz,
                        const float* __restrict__ w, const float* __restrict__ bias,
                        float* __restrict__ xcs, float* __restrict__ xst){
  __shared__ float ld[96][33];   // 3 h-rows x 32 w  by 32 d
  __shared__ float t[32][33];    // conv result [d_local][w]
  int h0 = blockIdx.x;
  int d0 = blockIdx.y*32;
  int tx = threadIdx.x, ty = threadIdx.y;
  #pragma unroll
  for (int i=0;i<12;i++){
    int ll = i*8 + ty;
    int h = h0 - 1 + (ll>>5);
    int wv = ll & 31;
    float v = 0.f;
    if ((unsigned)h < 32u) v = xz[(size_t)(h*32+wv)*768 + d0 + tx];
    ld[ll][tx] = v;
  }
  __syncthreads();
  #pragma unroll
  for (int i=0;i<4;i++){
    int dl = ty + 8*i;
    int d = d0 + dl;
    float acc = bias[d];
    const float* wp = w + d*9;
    #pragma unroll
    for (int di=0;di<3;di++){
      #pragma unroll
      for (int dj=0;dj<3;dj++){
        int wq = tx + dj - 1;
        if ((unsigned)wq < 32u)
          acc = fmaf(ld[di*32 + wq][dl], wp[di*3+dj], acc);
      }
    }
    float val = silu_(acc);
    xcs[(size_t)d*L_ + h0*32 + tx] = val;
    t[dl][tx] = val;
  }
  __syncthreads();
  int d = d0 + tx;
  #pragma unroll
  for (int i=0;i<4;i++){
    int wq = ty + 8*i;
    int l = h0*32 + wq;
    float val = t[tx][wq];
    int t1 = wq*32 + h0;
    xst[(size_t)l*DI_ + d] = val;
    xst[(size_t)(L_ + t1)*DI_ + d] = val;
    xst[(size_t)(2*L_ + (1023-l))*DI_ + d] = val;
    xst[(size_t)(3*L_ + (1023-t1))*DI_ + d] = val;
  }
}

// ---------------- x_dbl partial (split-K over d, 3 x 128): grid (4, 11, 12)
__global__ __launch_bounds__(256) void k_xdblP(const float* __restrict__ xcs,
                       const float* __restrict__ xw, float* __restrict__ xdblP){
  int kz = blockIdx.z;
  int k = kz & 3, sp = kz >> 2;
  int s = blockIdx.x*256 + threadIdx.x;
  int Ts = ((s&31)<<5) | (s>>5);
  int lw;
  if (k==0) lw = s;
  else if (k==1) lw = Ts;
  else if (k==2) lw = 1023-s;
  else lw = 1023-Ts;
  int c0 = blockIdx.y*4;
  const float* wp = xw + ((size_t)k*CXP_ + c0)*DI_ + sp*128;
  const float* src = xcs + s + (size_t)sp*128*L_;
  float a0=0,a1=0,a2=0,a3=0;
  for (int d=0; d<128; d++){
    float v = src[(size_t)d*L_];
    a0 = fmaf(v, wp[d],        a0);
    a1 = fmaf(v, wp[DI_+d],    a1);
    a2 = fmaf(v, wp[2*DI_+d],  a2);
    a3 = fmaf(v, wp[3*DI_+d],  a3);
  }
  size_t base = (((size_t)sp*4 + k)*CXP_ + c0)*L_ + lw;
  xdblP[base]       = a0;
  xdblP[base+L_]    = a1;
  xdblP[base+2*L_]  = a2;
  xdblP[base+3*L_]  = a3;
}

// ---------------- combine partials + dt proj + softplus -> dts_t; repack B,C -> bc
__global__ void k_dtbc(const float* __restrict__ xdblP, const float* __restrict__ dtw,
                       const float* __restrict__ dtb, float* __restrict__ dts_t,
                       float* __restrict__ bc){
  int k = blockIdx.y, l = blockIdx.x, d = threadIdx.x;
  const float* p0 = xdblP + ((size_t)(0+k)*CXP_)*L_ + l;
  const float* p1 = xdblP + ((size_t)(4+k)*CXP_)*L_ + l;
  const float* p2 = xdblP + ((size_t)(8+k)*CXP_)*L_ + l;
  float acc = dtb[(size_t)k*DI_ + d];
  const float* w = dtw + ((size_t)k*DI_ + d)*R_;
  #pragma unroll
  for (int r=0;r<R_;r++){
    size_t o = (size_t)r*L_;
    acc = fmaf(p0[o]+p1[o]+p2[o], w[r], acc);
  }
  dts_t[((size_t)k*L_ + l)*DI_ + d] = softplus_(acc);
  if (d < 32){
    size_t o = (size_t)(R_+d)*L_;
    bc[((size_t)k*L_ + l)*32 + d] = p0[o]+p1[o]+p2[o];
  }
}

// ---------------- chunked selective scan, phase A: per-chunk aggregates
__global__ __launch_bounds__(256) void k_scanA(const float* __restrict__ xst,
                      const float* __restrict__ dts_t, const float* __restrict__ bc,
                      const float* __restrict__ Alog,
                      float* __restrict__ Ech, float* __restrict__ Hch){
  int k = blockIdx.z;
  int d = blockIdx.y*16 + (threadIdx.x>>4);
  int n = threadIdx.x&15;
  int ch = blockIdx.x;
  float A = -expf(Alog[((size_t)k*DI_ + d)*NS_ + n]);
  float aL2 = A * 1.4426950408889634f;
  int t0 = ch*TC_;
  const float* dtp = dts_t + ((size_t)k*L_ + t0)*DI_ + d;
  const float* xp_ = xst   + ((size_t)k*L_ + t0)*DI_ + d;
  const float* bcp = bc    + ((size_t)k*L_ + t0)*32;
  float h = 0.f, Ep = 1.f;
  #pragma unroll 4
  for (int t=0;t<TC_;t++){
    float dt = dtp[(size_t)t*DI_];
    float xv = xp_[(size_t)t*DI_];
    float Bn = bcp[t*32+n];
    float e = exp2f(aL2*dt);
    h = fmaf(e, h, dt*xv*Bn);
    Ep *= e;
  }
  size_t idx = (((size_t)k*NCH_ + ch)*DI_ + d)*NS_ + n;
  Ech[idx] = Ep; Hch[idx] = h;
}

// ---------------- phase B: fold chunk aggregates -> carry-in per chunk
__global__ void k_scanB(const float* __restrict__ Ech, const float* __restrict__ Hch,
                        float* __restrict__ carry){
  int idx = blockIdx.x*256 + threadIdx.x;
  int k = idx / (DI_*NS_);
  int dn = idx % (DI_*NS_);
  float h = 0.f;
  #pragma unroll
  for (int c=0;c<NCH_;c++){
    size_t o = ((size_t)(k*NCH_+c)*DI_*NS_) + dn;
    carry[o] = h;
    h = fmaf(Ech[o], h, Hch[o]);
  }
}

// ---------------- phase C: recompute with carry-in, emit y
__global__ __launch_bounds__(256) void k_scanC(const float* __restrict__ xst,
                      const float* __restrict__ dts_t, const float* __restrict__ bc,
                      const float* __restrict__ Alog, const float* __restrict__ carry,
                      float* __restrict__ yst){
  int k = blockIdx.z;
  int d = blockIdx.y*16 + (threadIdx.x>>4);
  int n = threadIdx.x&15;
  int ch = blockIdx.x;
  float A = -expf(Alog[((size_t)k*DI_ + d)*NS_ + n]);
  float aL2 = A * 1.4426950408889634f;
  int t0 = ch*TC_;
  const float* dtp = dts_t + ((size_t)k*L_ + t0)*DI_ + d;
  const float* xp_ = xst   + ((size_t)k*L_ + t0)*DI_ + d;
  const float* bcp = bc    + ((size_t)k*L_ + t0)*32;
  float* yp = yst + ((size_t)k*L_ + t0)*DI_ + d;
  float h = carry[(((size_t)k*NCH_ + ch)*DI_ + d)*NS_ + n];
  #pragma unroll 4
  for (int t=0;t<TC_;t++){
    float dt = dtp[(size_t)t*DI_];
    float xv = xp_[(size_t)t*DI_];
    float Bn = bcp[t*32+n], Cn = bcp[t*32+16+n];
    float e = exp2f(aL2*dt);
    h = fmaf(e, h, dt*xv*Bn);
    float p = h*Cn;
    p += __shfl_xor(p,1); p += __shfl_xor(p,2);
    p += __shfl_xor(p,4); p += __shfl_xor(p,8);
    if (n==0) yp[(size_t)t*DI_] = p;
  }
}

// ---------------- merge 4 directions + Dskip + LN + silu(z) gate
__global__ void k_merge(const float* __restrict__ yst, const float* __restrict__ xst,
                        const float* __restrict__ Dsk, const float* __restrict__ mw,
                        const float* __restrict__ ong, const float* __restrict__ onb,
                        const float* __restrict__ xz, float* __restrict__ out){
  int l = blockIdx.x, d = threadIdx.x;
  int T = ((l&31)<<5) | (l>>5);
  int tt[4] = { l, T, 1023-l, 1023-T };
  float v = 0.f;
  #pragma unroll
  for (int k=0;k<4;k++){
    size_t idx = (size_t)(k*L_ + tt[k])*DI_ + d;
    v += mw[k]*(yst[idx] + xst[idx]*Dsk[k*DI_+d]);
  }
  float s = v, sq = v*v;
  for (int o=32;o;o>>=1){ s += __shfl_xor(s,o); sq += __shfl_xor(sq,o); }
  __shared__ float rs_[6], rq_[6];
  int lane = d&63, wid = d>>6;
  if (!lane){ rs_[wid]=s; rq_[wid]=sq; }
  __syncthreads();
  float ts=0.f, tq=0.f;
  #pragma unroll
  for (int i=0;i<6;i++){ ts += rs_[i]; tq += rq_[i]; }
  float mu = ts*(1.f/DI_);
  float rstd = rsqrtf(tq*(1.f/DI_) - mu*mu + 1e-5f);
  float y = (v-mu)*rstd*ong[d] + onb[d];
  float z = xz[(size_t)l*768 + DI_ + d];
  out[(size_t)l*DI_ + d] = y * silu_(z);
}

// ---------------- un-patchify + residual + attention + bn2
__global__ void k_sum(const float* __restrict__ x, const float* __restrict__ h,
                      const float* __restrict__ attn, const float* __restrict__ xu,
                      const float* g2, const float* b2, const float* m2, const float* v2,
                      float* __restrict__ xsum, float* __restrict__ h2){
  int idx = blockIdx.x*256 + threadIdx.x;
  int c = idx>>14, p = idx&16383;
  int hh = p>>7, ww = p&127;
  int l = (hh>>2)*32 + (ww>>2);
  int o = (c<<4) + ((hh&3)<<2) + (ww&3);
  float s = x[idx] + h[idx]*attn[c] + xu[(size_t)l*1536 + o];
  xsum[idx] = s;
  h2[idx] = (s - m2[c])*rsqrtf(v2[c]+1e-5f)*g2[c] + b2[c];
}

// ---------------- scpa: dual 1x1 conv + lrelu; 6 a-oc + 6 b-oc per block; grid (8,64)
__global__ __launch_bounds__(256) void k_1x1ab(const float* __restrict__ h2,
                        const float* __restrict__ wa, const float* __restrict__ wb,
                        float* __restrict__ a, float* __restrict__ b){
  __shared__ float lw[96*12];
  int ocg = blockIdx.x;
  for (int i=threadIdx.x; i<96*12; i+=256){
    int o = i%12, c = i/12;
    lw[i] = (o<6) ? wa[(ocg*6 + o)*96 + c] : wb[(ocg*6 + (o-6))*96 + c];
  }
  __syncthreads();
  int p = blockIdx.y*256 + threadIdx.x;
  float acc[12];
  #pragma unroll
  for (int o=0;o<12;o++) acc[o]=0.f;
  for (int c=0;c<96;c++){
    float v = h2[(size_t)c*HW + p];
    const float* w = lw + c*12;
    #pragma unroll
    for (int o=0;o<12;o++) acc[o] = fmaf(v, w[o], acc[o]);
  }
  #pragma unroll
  for (int o=0;o<6;o++){
    a[(size_t)(ocg*6+o)*HW + p] = lrelu_(acc[o]);
    b[(size_t)(ocg*6+o)*HW + p] = lrelu_(acc[6+o]);
  }
}

// ---------------- scpa: 1x1 conv + bias + sigmoid (gate); 6 oc per block; grid (8,64)
__global__ __launch_bounds__(256) void k_1x1g(const float* __restrict__ b,
                       const float* __restrict__ w, const float* __restrict__ bias,
                       float* __restrict__ g){
  __shared__ float lw[48*6];
  int ocg = blockIdx.x;
  for (int i=threadIdx.x; i<48*6; i+=256){
    int o = i%6, c = i/6;
    lw[i] = w[(ocg*6 + o)*48 + c];
  }
  __syncthreads();
  int p = blockIdx.y*256 + threadIdx.x;
  float acc[6];
  #pragma unroll
  for (int o=0;o<6;o++) acc[o] = bias[ocg*6+o];
  for (int c=0;c<48;c++){
    float v = b[(size_t)c*HW + p];
    const float* wp = lw + c*6;
    #pragma unroll
    for (int o=0;o<6;o++) acc[o] = fmaf(v, wp[o], acc[o]);
  }
  #pragma unroll
  for (int o=0;o<6;o++) g[(size_t)(ocg*6+o)*HW + p] = sigmoid_(acc[o]);
}

// ---------------- scpa: 3x3 conv 48->48, 6 oc per block, weights in LDS; grid (8,64)
__global__ __launch_bounds__(256) void k_conv3(const float* __restrict__ in,
                        const float* __restrict__ w, const float* __restrict__ aux,
                        float* __restrict__ out, int mode){
  __shared__ float lw[48*9*6];
  int ocg = blockIdx.x;
  for (int i=threadIdx.x; i<48*9*6; i+=256){
    int o = i%6, j = (i/6)%9, ic = i/54;
    lw[i] = w[((size_t)(ocg*6+o)*48 + ic)*9 + j];
  }
  __syncthreads();
  int p = blockIdx.y*256 + threadIdx.x;
  int hh = p>>7, ww = p&127;
  float acc[6];
  #pragma unroll
  for (int o=0;o<6;o++) acc[o]=0.f;
  for (int ic=0; ic<48; ic++){
    const float* ip = in + (size_t)ic*HW;
    float xv[9];
    #pragma unroll
    for (int di=0;di<3;di++){
      int y = hh+di-1;
      bool yok = (unsigned)y < 128u;
      #pragma unroll
      for (int dj=0;dj<3;dj++){
        int xx = ww+dj-1;
        bool ok = yok && ((unsigned)xx < 128u);
        xv[di*3+dj] = ok ? ip[y*128+xx] : 0.f;
      }
    }
    const float* lwp = lw + ic*54;
    #pragma unroll
    for (int j=0;j<9;j++){
      float xj = xv[j];
      const float* wj = lwp + j*6;
      #pragma unroll
      for (int o=0;o<6;o++) acc[o] = fmaf(xj, wj[o], acc[o]);
    }
  }
  #pragma unroll
  for (int o=0;o<6;o++){
    size_t oi = (size_t)(ocg*6+o)*HW + p;
    out[oi] = (mode==0) ? lrelu_(acc[o]) : acc[o]*aux[oi];
  }
}

// ---------------- final 1x1 conv (96 in -> 12 oc per block) + both residuals; grid (8,64)
__global__ __launch_bounds__(256) void k_c3(const float* __restrict__ ab,
                     const float* __restrict__ w, const float* __restrict__ h2,
                     const float* __restrict__ xsum, float* __restrict__ out){
  __shared__ float lw[96*12];
  int ocg = blockIdx.x;
  for (int i=threadIdx.x; i<96*12; i+=256){
    int o = i%12, j = i/12;
    lw[i] = w[(ocg*12 + o)*96 + j];
  }
  __syncthreads();
  int p = blockIdx.y*256 + threadIdx.x;
  float acc[12];
  #pragma unroll
  for (int o=0;o<12;o++) acc[o]=0.f;
  for (int j=0;j<96;j++){
    float v = ab[(size_t)j*HW + p];
    const float* wp = lw + j*12;
    #pragma unroll
    for (int o=0;o<12;o++) acc[o] = fmaf(v, wp[o], acc[o]);
  }
  #pragma unroll
  for (int o=0;o<12;o++){
    size_t oi = (size_t)(ocg*12+o)*HW + p;
    out[oi] = acc[o] + h2[oi] + xsum[oi];
  }
}

extern "C" void kernel_launch(void* const* d_in, const int* in_sizes, int n_in,
                              void* d_out, int out_size, void* d_ws, size_t ws_size,
                              hipStream_t stream){
  (void)in_sizes; (void)n_in; (void)out_size; (void)ws_size;
  const float* x    = (const float*)d_in[0];
  const float* bn1g = (const float*)d_in[1];
  const float* bn1b = (const float*)d_in[2];
  const float* bn1m = (const float*)d_in[3];
  const float* bn1v = (const float*)d_in[4];
  const float* caw1 = (const float*)d_in[5];
  const float* caw2 = (const float*)d_in[6];
  const float* peW  = (const float*)d_in[7];
  const float* peb  = (const float*)d_in[8];
  const float* puW  = (const float*)d_in[9];
  const float* pub  = (const float*)d_in[10];
  const float* lng  = (const float*)d_in[11];
  const float* lnb  = (const float*)d_in[12];
  const float* inW  = (const float*)d_in[13];
  const float* convw= (const float*)d_in[14];
  const float* convb= (const float*)d_in[15];
  const float* xprojw=(const float*)d_in[16];
  const float* dtw  = (const float*)d_in[17];
  const float* dtb  = (const float*)d_in[18];
  const float* Alog = (const float*)d_in[19];
  const float* Dsk  = (const float*)d_in[20];
  const float* ong  = (const float*)d_in[21];
  const float* onb  = (const float*)d_in[22];
  const float* outW = (const float*)d_in[23];
  const float* mw   = (const float*)d_in[24];
  const float* bn2g = (const float*)d_in[25];
  const float* bn2b = (const float*)d_in[26];
  const float* bn2m = (const float*)d_in[27];
  const float* bn2v = (const float*)d_in[28];
  const float* c1a  = (const float*)d_in[29];
  const float* c1b  = (const float*)d_in[30];
  const float* k1w  = (const float*)d_in[31];
  const float* k2w  = (const float*)d_in[32];
  const float* k2b  = (const float*)d_in[33];
  const float* k3w  = (const float*)d_in[34];
  const float* k4w  = (const float*)d_in[35];
  const float* c3w  = (const float*)d_in[36];
  float* out = (float*)d_out;

  float* ws = (float*)d_ws;
  size_t off = 0;
  auto alloc = [&](size_t n){ float* p = ws + off; off += n; return p; };
  float* peWT  = alloc((size_t)1536*192);
  float* puWT  = alloc((size_t)192*1536);
  float* inWT  = alloc((size_t)8*192*768);
  float* outWT = alloc((size_t)8*384*192);
  float* bufH  = alloc((size_t)96*HW);
  float* stats = alloc(256);
  float* attn  = alloc(128);
  float* bufP  = alloc((size_t)1024*1536);   // xp, later xu
  float* x2a   = alloc((size_t)1024*192);
  float* x2b   = alloc((size_t)1024*192);
  float* bufXZ = alloc((size_t)1024*768);
  float* bufXCS= alloc((size_t)384*1024);
  float* bufXST= alloc((size_t)4*1024*384);  // later ab (96ch)
  float* xdblP = alloc((size_t)12*44*1024);
  float* dts   = alloc((size_t)4*1024*384);  // later scpa a|b
  float* bc    = alloc((size_t)4*1024*32);
  float* yst   = alloc((size_t)4*1024*384);  // later scpa g|t
  float* bufY  = alloc((size_t)1024*384);
  float* xsum  = alloc((size_t)96*HW);
  float* h2    = alloc((size_t)96*HW);
  float* Ech   = alloc((size_t)K_*NCH_*DI_*NS_);
  float* Hch   = alloc((size_t)K_*NCH_*DI_*NS_);
  float* carry = alloc((size_t)K_*NCH_*DI_*NS_);
  float* muB   = alloc(1024);
  float* rsB   = alloc(1024);

  dim3 tb(32,8);
  // weight transposes
  k_transpose<<<dim3(48,6,1), tb, 0, stream>>>(peW, peWT, 192, 1536, 1536);
  k_transpose<<<dim3(6,48,1), tb, 0, stream>>>(puW, puWT, 1536, 192, 192);
  k_transpose<<<dim3(6,24,8), tb, 0, stream>>>(inW, inWT, 768, 192, 192);
  k_transpose<<<dim3(12,6,8), tb, 0, stream>>>(outW, outWT, 192, 384, 384);

  k_bn1<<<96,256,0,stream>>>(x, bn1g, bn1b, bn1m, bn1v, bufH, stats);
  k_attn<<<1,128,0,stream>>>(stats, caw1, caw2, attn);
  k_patchify<<<(1024*1536)/256,256,0,stream>>>(bufH, bufP);
  k_gemm32<<<dim3(32,6),256,0,stream>>>(bufP, peWT, peb, nullptr, x2a, 1536, 192);

  float* cur = x2a; float* nxt = x2b;
  for (int b=0;b<8;b++){
    k_lnstats<<<256,256,0,stream>>>(cur, muB, rsB);
    k_gemm32ln<<<dim3(32,24),256,0,stream>>>(cur, inWT+(size_t)b*192*768,
                        lng+(size_t)b*192, lnb+(size_t)b*192, muB, rsB, bufXZ, 192, 768);
    k_dwxst<<<dim3(32,12),tb,0,stream>>>(bufXZ, convw+(size_t)b*384*9,
                        convb+(size_t)b*384, bufXCS, bufXST);
    k_xdblP<<<dim3(4,11,12),256,0,stream>>>(bufXCS, xprojw+(size_t)b*4*44*384, xdblP);
    k_dtbc<<<dim3(1024,4),384,0,stream>>>(xdblP, dtw+(size_t)b*4*384*12, dtb+(size_t)b*4*384, dts, bc);
    const float* Ab = Alog + (size_t)b*4*384*16;
    k_scanA<<<dim3(NCH_,DI_/16,4),256,0,stream>>>(bufXST, dts, bc, Ab, Ech, Hch);
    k_scanB<<<(K_*DI_*NS_)/256,256,0,stream>>>(Ech, Hch, carry);
    k_scanC<<<dim3(NCH_,DI_/16,4),256,0,stream>>>(bufXST, dts, bc, Ab, carry, yst);
    k_merge<<<1024,384,0,stream>>>(yst, bufXST, Dsk+(size_t)b*4*384, mw+(size_t)b*4,
                                   ong+(size_t)b*384, onb+(size_t)b*384, bufXZ, bufY);
    k_gemm32<<<dim3(32,6),256,0,stream>>>(bufY, outWT+(size_t)b*384*192, nullptr, cur, nxt, 384, 192);
    float* t = cur; cur = nxt; nxt = t;
  }

  k_gemm32<<<dim3(32,48),256,0,stream>>>(cur, puWT, pub, nullptr, bufP, 192, 1536);
  k_sum<<<(96*HW)/256,256,0,stream>>>(x, bufH, attn, bufP, bn2g, bn2b, bn2m, bn2v, xsum, h2);

  float* bufA = dts;
  float* bufB = dts + (size_t)48*HW;
  float* bufG = yst;
  float* bufT = yst + (size_t)48*HW;
  float* ab   = bufXST;
  k_1x1ab<<<dim3(8,64),256,0,stream>>>(h2, c1a, c1b, bufA, bufB);
  k_1x1g<<<dim3(8,64),256,0,stream>>>(bufB, k2w, k2b, bufG);
  k_conv3<<<dim3(8,64),256,0,stream>>>(bufA, k1w, nullptr, ab, 0);
  k_conv3<<<dim3(8,64),256,0,stream>>>(bufB, k3w, bufG, bufT, 1);
  k_conv3<<<dim3(8,64),256,0,stream>>>(bufT, k4w, nullptr, ab+(size_t)48*HW, 0);
  k_c3<<<dim3(8,64),256,0,stream>>>(ab, c3w, h2, xsum, out);
}